// Round 1
// baseline (7572.855 us; speedup 1.0000x reference)
//
#include <hip/hip_runtime.h>
#include <hip/hip_bf16.h>

typedef long long ll;

#define B_ 8
#define SEG_ 16
#define T_ 257
#define H_ 1024
#define NH_ 16
#define DH_ 64
#define L_ 4113
#define SCALE 0.125f

__device__ __forceinline__ float bf2f(unsigned short u) {
  union { unsigned int i; float f; } w; w.i = ((unsigned int)u) << 16; return w.f;
}

__device__ __forceinline__ void store_ct(float* p, float v) { *p = v; }
__device__ __forceinline__ void store_ct(__hip_bfloat16* p, float v) { *p = __float2bfloat16(v); }

// C[m,n] = sum_k X[m,k] * W[n,k]  (+ bias[n]) (+ res[m*1024+n])
// X row m address: Xb + z*xzs + (m/xT)*xbs + (m%xT)*xrs
// C row m address: Cb + z*czs + (m/cT)*cbs + (m%cT)*crs
template<typename CT>
__global__ __launch_bounds__(256) void gemm_bt(
    const float* __restrict__ Xb, ll xzs, int xT, ll xbs, ll xrs,
    const float* __restrict__ Wb, ll wzs,
    const float* __restrict__ bias,
    CT* __restrict__ Cb, ll czs, int cT, ll cbs, ll crs,
    const float* __restrict__ res,
    int M, int K)
{
  const float* X = Xb + (ll)blockIdx.z * xzs;
  const float* W = Wb + (ll)blockIdx.z * wzs;
  CT* C = Cb + (ll)blockIdx.z * czs;

  const int tid = threadIdx.x;
  const int m0 = blockIdx.y * 64;
  const int n0 = blockIdx.x * 64;

  __shared__ float Xt[16][68];
  __shared__ float Wt[16][68];

  const int lr = tid >> 2;          // 0..63
  const int lc = (tid & 3) << 2;    // 0,4,8,12
  const int mload = m0 + lr;
  const bool mok = (mload < M);
  const ll xoff = mok ? ((ll)(mload / xT) * xbs + (ll)(mload % xT) * xrs) : 0;
  const ll woff = (ll)(n0 + lr) * K;

  const int tr = tid >> 4;          // 0..15
  const int tc = tid & 15;          // 0..15

  float acc[4][4];
#pragma unroll
  for (int i = 0; i < 4; ++i)
#pragma unroll
    for (int j = 0; j < 4; ++j) acc[i][j] = 0.f;

  for (int k0 = 0; k0 < K; k0 += 16) {
    float4 xv = make_float4(0.f, 0.f, 0.f, 0.f);
    if (mok) xv = *(const float4*)(X + xoff + k0 + lc);
    float4 wv = *(const float4*)(W + woff + k0 + lc);
    __syncthreads();
    Xt[lc + 0][lr] = xv.x; Xt[lc + 1][lr] = xv.y; Xt[lc + 2][lr] = xv.z; Xt[lc + 3][lr] = xv.w;
    Wt[lc + 0][lr] = wv.x; Wt[lc + 1][lr] = wv.y; Wt[lc + 2][lr] = wv.z; Wt[lc + 3][lr] = wv.w;
    __syncthreads();
#pragma unroll
    for (int kk = 0; kk < 16; ++kk) {
      float4 xa = *(const float4*)&Xt[kk][tr << 2];
      float4 wb = *(const float4*)&Wt[kk][tc << 2];
      float xa_[4] = {xa.x, xa.y, xa.z, xa.w};
      float wb_[4] = {wb.x, wb.y, wb.z, wb.w};
#pragma unroll
      for (int i = 0; i < 4; ++i)
#pragma unroll
        for (int j = 0; j < 4; ++j)
          acc[i][j] = fmaf(xa_[i], wb_[j], acc[i][j]);
    }
  }

#pragma unroll
  for (int i = 0; i < 4; ++i) {
    int m = m0 + (tr << 2) + i;
    if (m >= M) continue;
    ll co = (ll)(m / cT) * cbs + (ll)(m % cT) * crs;
#pragma unroll
    for (int j = 0; j < 4; ++j) {
      int n = n0 + (tc << 2) + j;
      float v = acc[i][j];
      if (bias) v += bias[n];
      if (res)  v += res[(ll)m * H_ + n];
      store_ct(C + co + n, v);
    }
  }
}

// one block per (head, segment, batch); thread t = query t (t < 257)
__global__ __launch_bounds__(320) void seg_attn(
    const __hip_bfloat16* __restrict__ Qb,
    const __hip_bfloat16* __restrict__ Kb,
    const __hip_bfloat16* __restrict__ Vb,
    float* __restrict__ so)
{
  const int h = blockIdx.x, s = blockIdx.y, b = blockIdx.z;
  const int tid = threadIdx.x;
  const ll base = ((ll)(b * SEG_ + s)) * T_ * H_ + h * DH_;

  __shared__ float Ks[64][64];
  __shared__ float Vs[64][64];

  float q[64];
  if (tid < T_) {
    const unsigned short* qp = (const unsigned short*)(Qb + base + (ll)tid * H_);
#pragma unroll
    for (int d4 = 0; d4 < 16; ++d4) {
      ushort4 u = *(const ushort4*)(qp + d4 * 4);
      q[d4 * 4 + 0] = bf2f(u.x); q[d4 * 4 + 1] = bf2f(u.y);
      q[d4 * 4 + 2] = bf2f(u.z); q[d4 * 4 + 3] = bf2f(u.w);
    }
  }

  // pass A: running max + sum of exp (scalar online update only)
  float m_ = -1e30f, l_ = 0.f;
  for (int k0 = 0; k0 < T_; k0 += 64) {
    const int kt = min(64, T_ - k0);
    __syncthreads();
    for (int lin = tid * 4; lin < kt * 64; lin += 320 * 4) {
      int kr = lin >> 6, kc = lin & 63;
      ushort4 u = *(const ushort4*)((const unsigned short*)(Kb + base + (ll)(k0 + kr) * H_ + kc));
      Ks[kr][kc + 0] = bf2f(u.x); Ks[kr][kc + 1] = bf2f(u.y);
      Ks[kr][kc + 2] = bf2f(u.z); Ks[kr][kc + 3] = bf2f(u.w);
    }
    __syncthreads();
    if (tid < T_) {
      for (int j = 0; j < kt; ++j) {
        float sc = 0.f;
#pragma unroll
        for (int d = 0; d < 64; ++d) sc = fmaf(q[d], Ks[j][d], sc);
        sc *= SCALE;
        float mn = fmaxf(m_, sc);
        l_ = l_ * __expf(m_ - mn) + __expf(sc - mn);
        m_ = mn;
      }
    }
  }

  // pass B: PV with known (m,l)
  float acc[64];
#pragma unroll
  for (int d = 0; d < 64; ++d) acc[d] = 0.f;

  for (int k0 = 0; k0 < T_; k0 += 64) {
    const int kt = min(64, T_ - k0);
    __syncthreads();
    for (int lin = tid * 4; lin < kt * 64; lin += 320 * 4) {
      int kr = lin >> 6, kc = lin & 63;
      ushort4 u = *(const ushort4*)((const unsigned short*)(Kb + base + (ll)(k0 + kr) * H_ + kc));
      Ks[kr][kc + 0] = bf2f(u.x); Ks[kr][kc + 1] = bf2f(u.y);
      Ks[kr][kc + 2] = bf2f(u.z); Ks[kr][kc + 3] = bf2f(u.w);
      ushort4 uv = *(const ushort4*)((const unsigned short*)(Vb + base + (ll)(k0 + kr) * H_ + kc));
      Vs[kr][kc + 0] = bf2f(uv.x); Vs[kr][kc + 1] = bf2f(uv.y);
      Vs[kr][kc + 2] = bf2f(uv.z); Vs[kr][kc + 3] = bf2f(uv.w);
    }
    __syncthreads();
    if (tid < T_) {
      for (int j = 0; j < kt; ++j) {
        float sc = 0.f;
#pragma unroll
        for (int d = 0; d < 64; ++d) sc = fmaf(q[d], Ks[j][d], sc);
        float p = __expf(sc * SCALE - m_);
#pragma unroll
        for (int d = 0; d < 64; ++d) acc[d] = fmaf(p, Vs[j][d], acc[d]);
      }
    }
  }

  if (tid < T_) {
    float invl = 1.f / l_;
    float* op = so + ((ll)b * L_ + 1 + (ll)s * T_ + tid) * H_ + h * DH_;
#pragma unroll
    for (int d4 = 0; d4 < 16; ++d4) {
      float4 o;
      o.x = acc[d4 * 4 + 0] * invl; o.y = acc[d4 * 4 + 1] * invl;
      o.z = acc[d4 * 4 + 2] * invl; o.w = acc[d4 * 4 + 3] * invl;
      *(float4*)(op + d4 * 4) = o;
    }
  }
}

__global__ __launch_bounds__(256) void copy_lords_in(
    const float* __restrict__ so, float* __restrict__ lin)
{
  int b = blockIdx.x / SEG_, s = blockIdx.x % SEG_;
  int i = threadIdx.x * 4;
  *(float4*)(lin + ((ll)(b * 17 + 1 + s)) * H_ + i) =
      *(const float4*)(so + ((ll)b * L_ + 1 + (ll)s * T_) * H_ + i);
}

__global__ __launch_bounds__(320) void lord_attn(
    const float* __restrict__ lq, const float* __restrict__ lk,
    const float* __restrict__ lv, float* __restrict__ so)
{
  int b = blockIdx.x;
  int tid = threadIdx.x;
  if (tid >= NH_ * 17) return;
  int h = tid / 17, qi = tid % 17;
  const float* qp = lq + ((ll)(b * 17 + qi)) * H_ + h * DH_;
  float q[64];
#pragma unroll
  for (int d = 0; d < 64; ++d) q[d] = qp[d];
  float sc[17];
#pragma unroll
  for (int k = 0; k < 17; ++k) {
    const float* kp = lk + ((ll)(b * 17 + k)) * H_ + h * DH_;
    float s_ = 0.f;
#pragma unroll
    for (int d = 0; d < 64; ++d) s_ = fmaf(q[d], kp[d], s_);
    sc[k] = s_ * SCALE;
  }
  float mx = sc[0];
#pragma unroll
  for (int k = 1; k < 17; ++k) mx = fmaxf(mx, sc[k]);
  float l = 0.f;
#pragma unroll
  for (int k = 0; k < 17; ++k) { sc[k] = __expf(sc[k] - mx); l += sc[k]; }
  float invl = 1.f / l;
  float out[64];
#pragma unroll
  for (int d = 0; d < 64; ++d) out[d] = 0.f;
#pragma unroll
  for (int k = 0; k < 17; ++k) {
    const float* vp = lv + ((ll)(b * 17 + k)) * H_ + h * DH_;
    float p = sc[k];
#pragma unroll
    for (int d = 0; d < 64; ++d) out[d] = fmaf(p, vp[d], out[d]);
  }
  ll row = (qi == 0) ? (ll)b * L_ : ((ll)b * L_ + 1 + (ll)(qi - 1) * T_);
  float* op = so + row * H_ + h * DH_;
#pragma unroll
  for (int d = 0; d < 64; ++d) op[d] = out[d] * invl;
}

__global__ __launch_bounds__(256) void ln_inplace(
    float* __restrict__ hbuf, const float* __restrict__ w, const float* __restrict__ bgain)
{
  const ll row = blockIdx.x;
  const int tid = threadIdx.x;
  float4 x = *(float4*)(hbuf + row * H_ + tid * 4);
  float s = x.x + x.y + x.z + x.w;
  float s2 = x.x * x.x + x.y * x.y + x.z * x.z + x.w * x.w;
#pragma unroll
  for (int off = 32; off >= 1; off >>= 1) {
    s  += __shfl_down(s, off, 64);
    s2 += __shfl_down(s2, off, 64);
  }
  __shared__ float red[2][4];
  int wid = tid >> 6;
  if ((tid & 63) == 0) { red[0][wid] = s; red[1][wid] = s2; }
  __syncthreads();
  s  = red[0][0] + red[0][1] + red[0][2] + red[0][3];
  s2 = red[1][0] + red[1][1] + red[1][2] + red[1][3];
  const float mean = s * (1.f / H_);
  float var = s2 * (1.f / H_) - mean * mean;
  var = fmaxf(var, 0.f);
  const float inv = rsqrtf(var + 1e-12f);
  float4 g = *(const float4*)(w + tid * 4);
  float4 bb = *(const float4*)(bgain + tid * 4);
  float4 y;
  y.x = (x.x - mean) * inv * g.x + bb.x;
  y.y = (x.y - mean) * inv * g.y + bb.y;
  y.z = (x.z - mean) * inv * g.z + bb.z;
  y.w = (x.w - mean) * inv * g.w + bb.w;
  *(float4*)(hbuf + row * H_ + tid * 4) = y;
}

extern "C" void kernel_launch(void* const* d_in, const int* in_sizes, int n_in,
                              void* d_out, int out_size, void* d_ws, size_t ws_size,
                              hipStream_t stream)
{
  const float* hidden  = (const float*)d_in[0];
  const float* Blord_w = (const float*)d_in[1];
  const float* Blord_b = (const float*)d_in[2];
  const float* seg_qw  = (const float*)d_in[3];
  const float* seg_kw  = (const float*)d_in[4];
  const float* seg_vw  = (const float*)d_in[5];
  const float* lord_qw = (const float*)d_in[6];
  const float* lord_kw = (const float*)d_in[7];
  const float* lord_vw = (const float*)d_in[8];
  const float* out_w   = (const float*)d_in[9];
  const float* out_b   = (const float*)d_in[10];
  const float* ln_w    = (const float*)d_in[11];
  const float* ln_b    = (const float*)d_in[12];

  float* attn_out = (float*)d_out;                          // output 0 [B,L,H]
  float* self_out = (float*)d_out + (ll)B_ * L_ * H_;       // output 1 [B,L,H]

  const ll QKV = (ll)B_ * SEG_ * T_ * H_;
  __hip_bfloat16* qb = (__hip_bfloat16*)d_ws;
  __hip_bfloat16* kb = qb + QKV;
  __hip_bfloat16* vb = kb + QKV;
  float* lords_in = (float*)(vb + QKV);
  float* lqw_ = lords_in + 136 * 1024;
  float* lkw_ = lqw_ + 136 * 1024;
  float* lvw_ = lkw_ + 136 * 1024;

  dim3 blk(256);

  // 1. segment QKV projections (bf16 out): grid z = segment
  {
    dim3 grid(16, 33, 16);
    gemm_bt<__hip_bfloat16><<<grid, blk, 0, stream>>>(
        hidden + H_, (ll)T_ * H_, T_, (ll)L_ * H_, (ll)H_,
        seg_qw, (ll)H_ * H_, nullptr,
        qb, (ll)T_ * H_, T_, (ll)SEG_ * T_ * H_, (ll)H_,
        nullptr, B_ * T_, H_);
    gemm_bt<__hip_bfloat16><<<grid, blk, 0, stream>>>(
        hidden + H_, (ll)T_ * H_, T_, (ll)L_ * H_, (ll)H_,
        seg_kw, (ll)H_ * H_, nullptr,
        kb, (ll)T_ * H_, T_, (ll)SEG_ * T_ * H_, (ll)H_,
        nullptr, B_ * T_, H_);
    gemm_bt<__hip_bfloat16><<<grid, blk, 0, stream>>>(
        hidden + H_, (ll)T_ * H_, T_, (ll)L_ * H_, (ll)H_,
        seg_vw, (ll)H_ * H_, nullptr,
        vb, (ll)T_ * H_, T_, (ll)SEG_ * T_ * H_, (ll)H_,
        nullptr, B_ * T_, H_);
  }

  // 2. Blord = hidden[:,0] @ Blord_w.T + b  -> lords_in rows b*17
  gemm_bt<float><<<dim3(16, 1, 1), blk, 0, stream>>>(
      hidden, 0, 1, (ll)L_ * H_, 0,
      Blord_w, 0, Blord_b,
      lords_in, 0, 1, (ll)17 * H_, 0,
      nullptr, B_, H_);

  // 3. per-segment attention -> self_out segment rows
  seg_attn<<<dim3(NH_, SEG_, B_), dim3(320), 0, stream>>>(qb, kb, vb, self_out);

  // 4. gather lord inputs (pre-update seg_out[:,:,0])
  copy_lords_in<<<dim3(B_ * SEG_), dim3(256), 0, stream>>>(self_out, lords_in);

  // 5. lord q/k/v projections (M=136)
  gemm_bt<float><<<dim3(16, 3, 1), blk, 0, stream>>>(
      lords_in, 0, 136, 0, (ll)H_, lord_qw, 0, nullptr,
      lqw_, 0, 136, 0, (ll)H_, nullptr, 136, H_);
  gemm_bt<float><<<dim3(16, 3, 1), blk, 0, stream>>>(
      lords_in, 0, 136, 0, (ll)H_, lord_kw, 0, nullptr,
      lkw_, 0, 136, 0, (ll)H_, nullptr, 136, H_);
  gemm_bt<float><<<dim3(16, 3, 1), blk, 0, stream>>>(
      lords_in, 0, 136, 0, (ll)H_, lord_vw, 0, nullptr,
      lvw_, 0, 136, 0, (ll)H_, nullptr, 136, H_);

  // 6. lord attention -> overwrites lord rows of self_out
  lord_attn<<<dim3(B_), dim3(272), 0, stream>>>(lqw_, lkw_, lvw_, self_out);

  // 7. output dense + bias + residual -> attn_out (pre-LN)
  gemm_bt<float><<<dim3(16, 515, 1), blk, 0, stream>>>(
      self_out, 0, B_ * L_, 0, (ll)H_, out_w, 0, out_b,
      attn_out, 0, B_ * L_, 0, (ll)H_, hidden, B_ * L_, H_);

  // 8. LayerNorm in place
  ln_inplace<<<dim3(B_ * L_), dim3(256), 0, stream>>>(attn_out, ln_w, ln_b);
}

// Round 3
// 1712.434 us; speedup vs baseline: 4.4223x; 4.4223x over previous
//
#include <hip/hip_runtime.h>
#include <hip/hip_bf16.h>

typedef long long ll;
typedef __attribute__((ext_vector_type(8))) short bf16x8;
typedef __attribute__((ext_vector_type(4))) float fx4;

#define B_ 8
#define SEG_ 16
#define T_ 257
#define H_ 1024
#define NH_ 16
#define L_ 4113
#define SCALE 0.125f

__device__ __forceinline__ float bf2f(unsigned short u) {
  union { unsigned int i; float f; } w; w.i = ((unsigned int)u) << 16; return w.f;
}
__device__ __forceinline__ unsigned short f2bfu(float x) {
  __hip_bfloat16 h = __float2bfloat16(x);
  return *(unsigned short*)&h;
}
__device__ __forceinline__ void store_ct(float* p, float v) { *p = v; }
__device__ __forceinline__ void store_ct(__hip_bfloat16* p, float v) { *p = __float2bfloat16(v); }

__device__ __forceinline__ void gl_lds16(const void* g, void* l) {
  __builtin_amdgcn_global_load_lds((const __attribute__((address_space(1))) void*)g,
                                   (__attribute__((address_space(3))) void*)l, 16, 0, 0);
}

// ---------------- fp32 -> bf16 convert (n multiple of 8) ----------------
__global__ __launch_bounds__(256) void f2bf(const float* __restrict__ src,
                                            __hip_bfloat16* __restrict__ dst, int n8) {
  for (int i = blockIdx.x * 256 + threadIdx.x; i < n8; i += gridDim.x * 256) {
    float4 a = ((const float4*)src)[i * 2];
    float4 b = ((const float4*)src)[i * 2 + 1];
    union { bf16x8 v; unsigned short u[8]; } o;
    o.u[0] = f2bfu(a.x); o.u[1] = f2bfu(a.y); o.u[2] = f2bfu(a.z); o.u[3] = f2bfu(a.w);
    o.u[4] = f2bfu(b.x); o.u[5] = f2bfu(b.y); o.u[6] = f2bfu(b.z); o.u[7] = f2bfu(b.w);
    ((bf16x8*)dst)[i] = o.v;
  }
}

// ---------------- bf16 MFMA GEMM: C[m,n] = sum_k A[m,k]*W[n,k] ----------------
template<typename CT, int XT>
__global__ __launch_bounds__(256) void gemm_mfma(
    const __hip_bfloat16* __restrict__ Ab, ll axz, ll axb, ll axr,
    const __hip_bfloat16* __restrict__ Bb, ll bwz,
    const float* __restrict__ bias,
    CT* __restrict__ Cb, ll czs, ll cbs, ll crs,
    const float* __restrict__ res,
    int M)
{
  const __hip_bfloat16* A = Ab + (ll)blockIdx.z * axz;
  const __hip_bfloat16* W = Bb + (ll)blockIdx.z * bwz;
  CT* C = Cb + (ll)blockIdx.z * czs;

  __shared__ __hip_bfloat16 At[128 * 32];
  __shared__ __hip_bfloat16 Bt[128 * 32];

  const int tid = threadIdx.x;
  const int lane = tid & 63;
  const int wid = tid >> 6;
  const int m0 = blockIdx.y * 128;
  const int n0 = blockIdx.x * 128;
  const int wm = (wid >> 1) * 64;
  const int wn = (wid & 1) * 64;

  const int r0 = tid >> 2;            // staging row within 64-row half
  const int kc = (tid & 3) * 8;       // staging k-col (elements)
  int am0 = m0 + r0;      if (am0 > M - 1) am0 = M - 1;
  int am1 = m0 + 64 + r0; if (am1 > M - 1) am1 = M - 1;
  ll aoff0, aoff1;
  if (XT) {
    aoff0 = (ll)(am0 / XT) * axb + (ll)(am0 % XT) * axr;
    aoff1 = (ll)(am1 / XT) * axb + (ll)(am1 % XT) * axr;
  } else {
    aoff0 = (ll)am0 * 1024; aoff1 = (ll)am1 * 1024;
  }
  const ll boff0 = (ll)(n0 + r0) * 1024;
  const ll boff1 = (ll)(n0 + 64 + r0) * 1024;

  fx4 acc[4][4];
#pragma unroll
  for (int i = 0; i < 4; ++i)
#pragma unroll
    for (int j = 0; j < 4; ++j) acc[i][j] = fx4{0.f, 0.f, 0.f, 0.f};

  const __hip_bfloat16* ap = At + (ll)(wm + (lane & 15)) * 32 + ((lane >> 4) << 3);
  const __hip_bfloat16* bp = Bt + (ll)(wn + (lane & 15)) * 32 + ((lane >> 4) << 3);

  for (int k0 = 0; k0 < 1024; k0 += 32) {
    __syncthreads();
    gl_lds16(A + aoff0 + k0 + kc, (void*)(At + r0 * 32 + kc));
    gl_lds16(A + aoff1 + k0 + kc, (void*)(At + 2048 + r0 * 32 + kc));
    gl_lds16(W + boff0 + k0 + kc, (void*)(Bt + r0 * 32 + kc));
    gl_lds16(W + boff1 + k0 + kc, (void*)(Bt + 2048 + r0 * 32 + kc));
    __syncthreads();

    bf16x8 af[4], bfr[4];
#pragma unroll
    for (int f = 0; f < 4; ++f) {
      af[f]  = *(const bf16x8*)(ap + f * 16 * 32);
      bfr[f] = *(const bf16x8*)(bp + f * 16 * 32);
    }
#pragma unroll
    for (int mf = 0; mf < 4; ++mf)
#pragma unroll
      for (int nf = 0; nf < 4; ++nf)
        acc[mf][nf] = __builtin_amdgcn_mfma_f32_16x16x32_bf16(af[mf], bfr[nf], acc[mf][nf], 0, 0, 0);
  }

  const int cn = n0 + wn + (lane & 15);
#pragma unroll
  for (int mf = 0; mf < 4; ++mf) {
    int mloc = m0 + wm + mf * 16 + ((lane >> 4) << 2);
#pragma unroll
    for (int r = 0; r < 4; ++r) {
      int m = mloc + r;
      if (m >= M) continue;
      ll co;
      if (XT) co = (ll)(m / XT) * cbs + (ll)(m % XT) * crs;
      else    co = (ll)m * 1024;
#pragma unroll
      for (int nf = 0; nf < 4; ++nf) {
        int n = cn + nf * 16;
        float v = acc[mf][nf][r];
        if (bias) v += bias[n];
        if (res)  v += res[(ll)m * 1024 + n];
        store_ct(C + co + n, v);
      }
    }
  }
}

// ---------------- MFMA flash attention over one segment ----------------
__global__ __launch_bounds__(256) void seg_attn_mfma(
    const __hip_bfloat16* __restrict__ Qb,
    const __hip_bfloat16* __restrict__ Kb,
    const __hip_bfloat16* __restrict__ Vb,
    float* __restrict__ so, __hip_bfloat16* __restrict__ sob)
{
  __shared__ __align__(16) char smem[8192 + 9216 + 4 * 4096];
  char* KsB = smem;                 // K tile [64][64] bf16, XOR-swizzled 16B slots
  char* VTB = smem + 8192;          // V^T [64 d][72 kk] bf16 (uint-packed writes)
  const int tid = threadIdx.x, lane = tid & 63, wid = tid >> 6;
  char* PB = smem + 8192 + 9216 + wid * 4096;  // per-wave P [32][64] bf16, swizzled

  const int h = blockIdx.y, bs = blockIdx.z;
  const int b = bs >> 4, s = bs & 15;
  const int q0 = blockIdx.x * 128 + wid * 32;
  const bool qvalid = (q0 <= 256);
  const ll base = (ll)bs * (T_ * H_) + h * 64;

  // Q fragments (rows clamped)
  bf16x8 qf[2][2];
#pragma unroll
  for (int mf = 0; mf < 2; ++mf) {
    int qr = q0 + mf * 16 + (lane & 15); if (qr > 256) qr = 256;
#pragma unroll
    for (int ks = 0; ks < 2; ++ks)
      qf[mf][ks] = *(const bf16x8*)(Qb + base + (ll)qr * H_ + ks * 32 + ((lane >> 4) << 3));
  }

  float m_[2][4], l_[2][4];
  fx4 of[2][4];
#pragma unroll
  for (int mf = 0; mf < 2; ++mf) {
#pragma unroll
    for (int r = 0; r < 4; ++r) { m_[mf][r] = -1e30f; l_[mf][r] = 0.f; }
#pragma unroll
    for (int df = 0; df < 4; ++df) of[mf][df] = fx4{0.f, 0.f, 0.f, 0.f};
  }

  const int krow = tid >> 3;          // K staging row (issue 0), +32 for issue 1
  const int kc8 = tid & 7;            // 16B slot within row
  const int kkp = tid & 31;           // VT: kk pair index
  const int vd0 = (tid >> 5) * 8;     // VT: d block

  for (int t = 0; t < 5; ++t) {
    const int k0 = t * 64;
    __syncthreads();
    // --- stage K (swizzled via pre-swizzled global source) ---
    {
      int row = krow;
      int kr = k0 + row; if (kr > 256) kr = 256;
      gl_lds16(Kb + base + (ll)kr * H_ + ((kc8 ^ (row & 7)) << 3), KsB + tid * 16);
      row = krow + 32;
      kr = k0 + row; if (kr > 256) kr = 256;
      gl_lds16(Kb + base + (ll)kr * H_ + ((kc8 ^ (row & 7)) << 3), KsB + 4096 + tid * 16);
    }
    // --- stage V^T (packed conflict-free writes) ---
    {
      int kk = kkp * 2;
      int kr0 = k0 + kk;     if (kr0 > 256) kr0 = 256;
      int kr1 = k0 + kk + 1; if (kr1 > 256) kr1 = 256;
      bf16x8 v0 = *(const bf16x8*)(Vb + base + (ll)kr0 * H_ + vd0);
      bf16x8 v1 = *(const bf16x8*)(Vb + base + (ll)kr1 * H_ + vd0);
      unsigned int* vtu = (unsigned int*)VTB;
#pragma unroll
      for (int j = 0; j < 8; ++j)
        vtu[(vd0 + j) * 36 + kkp] =
            (unsigned int)(unsigned short)v0[j] | ((unsigned int)(unsigned short)v1[j] << 16);
    }
    __syncthreads();

    if (qvalid) {
      // --- S = Q K^T ---
      fx4 sa[2][4];
#pragma unroll
      for (int mf = 0; mf < 2; ++mf)
#pragma unroll
        for (int nf = 0; nf < 4; ++nf) sa[mf][nf] = fx4{0.f, 0.f, 0.f, 0.f};
#pragma unroll
      for (int nf = 0; nf < 4; ++nf) {
        int key = nf * 16 + (lane & 15);
#pragma unroll
        for (int ks = 0; ks < 2; ++ks) {
          int c16 = ks * 4 + (lane >> 4);
          bf16x8 kf = *(const bf16x8*)(KsB + key * 128 + ((c16 ^ (key & 7)) << 4));
          sa[0][nf] = __builtin_amdgcn_mfma_f32_16x16x32_bf16(qf[0][ks], kf, sa[0][nf], 0, 0, 0);
          sa[1][nf] = __builtin_amdgcn_mfma_f32_16x16x32_bf16(qf[1][ks], kf, sa[1][nf], 0, 0, 0);
        }
      }
      // --- scale + mask ---
#pragma unroll
      for (int nf = 0; nf < 4; ++nf) {
        bool bad = (k0 + nf * 16 + (lane & 15)) > 256;
#pragma unroll
        for (int mf = 0; mf < 2; ++mf) {
          if (bad) sa[mf][nf] = fx4{-3e38f, -3e38f, -3e38f, -3e38f};
          else     sa[mf][nf] *= SCALE;
        }
      }
      // --- online softmax ---
#pragma unroll
      for (int mf = 0; mf < 2; ++mf) {
        float rowsum[4];
#pragma unroll
        for (int r = 0; r < 4; ++r) {
          float mr = fmaxf(fmaxf(sa[mf][0][r], sa[mf][1][r]), fmaxf(sa[mf][2][r], sa[mf][3][r]));
          mr = fmaxf(mr, __shfl_xor(mr, 1));
          mr = fmaxf(mr, __shfl_xor(mr, 2));
          mr = fmaxf(mr, __shfl_xor(mr, 4));
          mr = fmaxf(mr, __shfl_xor(mr, 8));
          float mo = m_[mf][r];
          float mn = fmaxf(mo, mr);
          float sf = __expf(mo - mn);
          m_[mf][r] = mn;
          l_[mf][r] *= sf;
#pragma unroll
          for (int df = 0; df < 4; ++df) of[mf][df][r] *= sf;
          rowsum[r] = 0.f;
        }
#pragma unroll
        for (int nf = 0; nf < 4; ++nf)
#pragma unroll
          for (int r = 0; r < 4; ++r) {
            float p = __expf(sa[mf][nf][r] - m_[mf][r]);
            sa[mf][nf][r] = p;
            rowsum[r] += p;
          }
#pragma unroll
        for (int r = 0; r < 4; ++r) {
          float rs = rowsum[r];
          rs += __shfl_xor(rs, 1);
          rs += __shfl_xor(rs, 2);
          rs += __shfl_xor(rs, 4);
          rs += __shfl_xor(rs, 8);
          l_[mf][r] += rs;
        }
      }
      // --- write P to per-wave swizzled LDS ---
      // FIX(r2): shuffle FIXED register indices across the lane pair; the old
      // code shuffled sa[r_own] with lane-dependent r_own, swapping rows {0,1}
      // and {2,3} between columns.
#pragma unroll
      for (int mf = 0; mf < 2; ++mf)
#pragma unroll
        for (int nf = 0; nf < 4; ++nf)
#pragma unroll
          for (int rp = 0; rp < 2; ++rp) {
            float v0 = sa[mf][nf][rp];        // row rp, own col
            float v2 = sa[mf][nf][rp + 2];    // row rp+2, own col
            float o0 = __shfl_xor(v0, 1);     // row rp, partner col
            float o2 = __shfl_xor(v2, 1);     // row rp+2, partner col
            const bool odd = (lane & 1);
            float lo = odd ? o2 : v0;         // even col value of the row we write
            float hi = odd ? v2 : o0;         // odd col value
            unsigned int pk = (unsigned int)f2bfu(lo) | ((unsigned int)f2bfu(hi) << 16);
            int row = mf * 16 + ((lane >> 4) << 2) + (odd ? rp + 2 : rp);
            int col2 = nf * 16 + (lane & 14);
            *(unsigned int*)(PB + row * 128 + ((col2 * 2) ^ ((row & 7) << 4))) = pk;
          }
      // --- O += P V ---
#pragma unroll
      for (int kks = 0; kks < 2; ++kks) {
        bf16x8 pa[2];
#pragma unroll
        for (int mf = 0; mf < 2; ++mf) {
          int prow = mf * 16 + (lane & 15);
          int c16 = kks * 4 + (lane >> 4);
          pa[mf] = *(const bf16x8*)(PB + prow * 128 + ((c16 ^ (prow & 7)) << 4));
        }
#pragma unroll
        for (int df = 0; df < 4; ++df) {
          bf16x8 vf = *(const bf16x8*)(VTB + (df * 16 + (lane & 15)) * 144 + kks * 64 + ((lane >> 4) << 4));
          of[0][df] = __builtin_amdgcn_mfma_f32_16x16x32_bf16(pa[0], vf, of[0][df], 0, 0, 0);
          of[1][df] = __builtin_amdgcn_mfma_f32_16x16x32_bf16(pa[1], vf, of[1][df], 0, 0, 0);
        }
      }
    }
  }

  if (qvalid) {
#pragma unroll
    for (int mf = 0; mf < 2; ++mf)
#pragma unroll
      for (int r = 0; r < 4; ++r) {
        int q = q0 + mf * 16 + ((lane >> 4) << 2) + r;
        if (q > 256) continue;
        float inv = 1.f / l_[mf][r];
        ll rowoff = ((ll)b * L_ + 1 + (ll)s * T_ + q) * H_ + h * 64;
#pragma unroll
        for (int df = 0; df < 4; ++df) {
          int d = df * 16 + (lane & 15);
          float v = of[mf][df][r] * inv;
          so[rowoff + d] = v;
          sob[rowoff + d] = __float2bfloat16(v);
        }
      }
  }
}

// ---------------- small fp32 VALU GEMM (lord path, M tiny) ----------------
template<typename CT>
__global__ __launch_bounds__(256) void gemm_bt(
    const float* __restrict__ Xb, ll xzs, int xT, ll xbs, ll xrs,
    const float* __restrict__ Wb, ll wzs,
    const float* __restrict__ bias,
    CT* __restrict__ Cb, ll czs, int cT, ll cbs, ll crs,
    const float* __restrict__ res,
    int M, int K)
{
  const float* X = Xb + (ll)blockIdx.z * xzs;
  const float* W = Wb + (ll)blockIdx.z * wzs;
  CT* C = Cb + (ll)blockIdx.z * czs;

  const int tid = threadIdx.x;
  const int m0 = blockIdx.y * 64;
  const int n0 = blockIdx.x * 64;

  __shared__ float Xt[16][68];
  __shared__ float Wt[16][68];

  const int lr = tid >> 2;
  const int lc = (tid & 3) << 2;
  const int mload = m0 + lr;
  const bool mok = (mload < M);
  const ll xoff = mok ? ((ll)(mload / xT) * xbs + (ll)(mload % xT) * xrs) : 0;
  const ll woff = (ll)(n0 + lr) * K;

  const int tr = tid >> 4;
  const int tc = tid & 15;

  float acc[4][4];
#pragma unroll
  for (int i = 0; i < 4; ++i)
#pragma unroll
    for (int j = 0; j < 4; ++j) acc[i][j] = 0.f;

  for (int k0 = 0; k0 < K; k0 += 16) {
    float4 xv = make_float4(0.f, 0.f, 0.f, 0.f);
    if (mok) xv = *(const float4*)(X + xoff + k0 + lc);
    float4 wv = *(const float4*)(W + woff + k0 + lc);
    __syncthreads();
    Xt[lc + 0][lr] = xv.x; Xt[lc + 1][lr] = xv.y; Xt[lc + 2][lr] = xv.z; Xt[lc + 3][lr] = xv.w;
    Wt[lc + 0][lr] = wv.x; Wt[lc + 1][lr] = wv.y; Wt[lc + 2][lr] = wv.z; Wt[lc + 3][lr] = wv.w;
    __syncthreads();
#pragma unroll
    for (int kk = 0; kk < 16; ++kk) {
      float4 xa = *(const float4*)&Xt[kk][tr << 2];
      float4 wb = *(const float4*)&Wt[kk][tc << 2];
      float xa_[4] = {xa.x, xa.y, xa.z, xa.w};
      float wb_[4] = {wb.x, wb.y, wb.z, wb.w};
#pragma unroll
      for (int i = 0; i < 4; ++i)
#pragma unroll
        for (int j = 0; j < 4; ++j)
          acc[i][j] = fmaf(xa_[i], wb_[j], acc[i][j]);
    }
  }

#pragma unroll
  for (int i = 0; i < 4; ++i) {
    int m = m0 + (tr << 2) + i;
    if (m >= M) continue;
    ll co = (ll)(m / cT) * cbs + (ll)(m % cT) * crs;
#pragma unroll
    for (int j = 0; j < 4; ++j) {
      int n = n0 + (tc << 2) + j;
      float v = acc[i][j];
      if (bias) v += bias[n];
      if (res)  v += res[(ll)m * H_ + n];
      store_ct(C + co + n, v);
    }
  }
}

__global__ __launch_bounds__(256) void copy_lords_in(
    const float* __restrict__ so, float* __restrict__ lin)
{
  int b = blockIdx.x / SEG_, s = blockIdx.x % SEG_;
  int i = threadIdx.x * 4;
  *(float4*)(lin + ((ll)(b * 17 + 1 + s)) * H_ + i) =
      *(const float4*)(so + ((ll)b * L_ + 1 + (ll)s * T_) * H_ + i);
}

__global__ __launch_bounds__(320) void lord_attn(
    const float* __restrict__ lq, const float* __restrict__ lk,
    const float* __restrict__ lv, float* __restrict__ so,
    __hip_bfloat16* __restrict__ sob)
{
  int b = blockIdx.x;
  int tid = threadIdx.x;
  if (tid >= NH_ * 17) return;
  int h = tid / 17, qi = tid % 17;
  const float* qp = lq + ((ll)(b * 17 + qi)) * H_ + h * 64;
  float q[64];
#pragma unroll
  for (int d = 0; d < 64; ++d) q[d] = qp[d];
  float sc[17];
#pragma unroll
  for (int k = 0; k < 17; ++k) {
    const float* kp = lk + ((ll)(b * 17 + k)) * H_ + h * 64;
    float s_ = 0.f;
#pragma unroll
    for (int d = 0; d < 64; ++d) s_ = fmaf(q[d], kp[d], s_);
    sc[k] = s_ * SCALE;
  }
  float mx = sc[0];
#pragma unroll
  for (int k = 1; k < 17; ++k) mx = fmaxf(mx, sc[k]);
  float l = 0.f;
#pragma unroll
  for (int k = 0; k < 17; ++k) { sc[k] = __expf(sc[k] - mx); l += sc[k]; }
  float invl = 1.f / l;
  float out[64];
#pragma unroll
  for (int d = 0; d < 64; ++d) out[d] = 0.f;
#pragma unroll
  for (int k = 0; k < 17; ++k) {
    const float* vp = lv + ((ll)(b * 17 + k)) * H_ + h * 64;
    float p = sc[k];
#pragma unroll
    for (int d = 0; d < 64; ++d) out[d] = fmaf(p, vp[d], out[d]);
  }
  ll row = (qi == 0) ? (ll)b * L_ : ((ll)b * L_ + 1 + (ll)(qi - 1) * T_);
#pragma unroll
  for (int d = 0; d < 64; ++d) {
    float v = out[d] * invl;
    so[row * H_ + h * 64 + d] = v;
    sob[row * H_ + h * 64 + d] = __float2bfloat16(v);
  }
}

__global__ __launch_bounds__(256) void ln_inplace(
    float* __restrict__ hbuf, const float* __restrict__ w, const float* __restrict__ bgain)
{
  const ll row = blockIdx.x;
  const int tid = threadIdx.x;
  float4 x = *(float4*)(hbuf + row * H_ + tid * 4);
  float s = x.x + x.y + x.z + x.w;
  float s2 = x.x * x.x + x.y * x.y + x.z * x.z + x.w * x.w;
#pragma unroll
  for (int off = 32; off >= 1; off >>= 1) {
    s  += __shfl_down(s, off, 64);
    s2 += __shfl_down(s2, off, 64);
  }
  __shared__ float red[2][4];
  int wid = tid >> 6;
  if ((tid & 63) == 0) { red[0][wid] = s; red[1][wid] = s2; }
  __syncthreads();
  s  = red[0][0] + red[0][1] + red[0][2] + red[0][3];
  s2 = red[1][0] + red[1][1] + red[1][2] + red[1][3];
  const float mean = s * (1.f / H_);
  float var = s2 * (1.f / H_) - mean * mean;
  var = fmaxf(var, 0.f);
  const float inv = rsqrtf(var + 1e-12f);
  float4 g = *(const float4*)(w + tid * 4);
  float4 bb = *(const float4*)(bgain + tid * 4);
  float4 y;
  y.x = (x.x - mean) * inv * g.x + bb.x;
  y.y = (x.y - mean) * inv * g.y + bb.y;
  y.z = (x.z - mean) * inv * g.z + bb.z;
  y.w = (x.w - mean) * inv * g.w + bb.w;
  *(float4*)(hbuf + row * H_ + tid * 4) = y;
}

extern "C" void kernel_launch(void* const* d_in, const int* in_sizes, int n_in,
                              void* d_out, int out_size, void* d_ws, size_t ws_size,
                              hipStream_t stream)
{
  const float* hidden  = (const float*)d_in[0];
  const float* Blord_w = (const float*)d_in[1];
  const float* Blord_b = (const float*)d_in[2];
  const float* seg_qw  = (const float*)d_in[3];
  const float* seg_kw  = (const float*)d_in[4];
  const float* seg_vw  = (const float*)d_in[5];
  const float* lord_qw = (const float*)d_in[6];
  const float* lord_kw = (const float*)d_in[7];
  const float* lord_vw = (const float*)d_in[8];
  const float* out_w   = (const float*)d_in[9];
  const float* out_b   = (const float*)d_in[10];
  const float* ln_w    = (const float*)d_in[11];
  const float* ln_b    = (const float*)d_in[12];

  float* attn_out = (float*)d_out;                          // output 0 [B,L,H]
  float* self_out = (float*)d_out + (ll)B_ * L_ * H_;       // output 1 [B,L,H]

  const ll QKV = (ll)B_ * SEG_ * T_ * H_;                   // 33,685,504 elems
  // qb + kb live in the attn_out region (free until the out-dense write)
  __hip_bfloat16* qb = (__hip_bfloat16*)attn_out;
  __hip_bfloat16* kb = qb + QKV;
  // workspace
  __hip_bfloat16* vb   = (__hip_bfloat16*)d_ws;
  __hip_bfloat16* hbf  = vb + QKV;                          // aliased: so_bf after attention
  __hip_bfloat16* sob  = hbf;
  __hip_bfloat16* wslot = hbf + (ll)B_ * L_ * H_;           // one weight set
  __hip_bfloat16* outw_bf = wslot + (ll)SEG_ * H_ * H_;
  float* lords_in = (float*)(outw_bf + (ll)H_ * H_);
  float* lqw_ = lords_in + 136 * 1024;
  float* lkw_ = lqw_ + 136 * 1024;
  float* lvw_ = lkw_ + 136 * 1024;

  dim3 blk(256);
  const int HID8 = (B_ * L_ * H_) / 8;
  const int W8   = (SEG_ * H_ * H_) / 8;

  // 0. convert hidden to bf16
  f2bf<<<dim3(2048), blk, 0, stream>>>(hidden, hbf, HID8);

  // 1. segment QKV projections (bf16 MFMA), weights converted through one slot
  dim3 gq(8, 17, 16);
  f2bf<<<dim3(2048), blk, 0, stream>>>(seg_qw, wslot, W8);
  gemm_mfma<__hip_bfloat16, 257><<<gq, blk, 0, stream>>>(
      hbf + H_, (ll)T_ * H_, (ll)L_ * H_, (ll)H_,
      wslot, (ll)H_ * H_, nullptr,
      qb, (ll)T_ * H_, (ll)SEG_ * T_ * H_, (ll)H_, nullptr, B_ * T_);
  f2bf<<<dim3(2048), blk, 0, stream>>>(seg_kw, wslot, W8);
  gemm_mfma<__hip_bfloat16, 257><<<gq, blk, 0, stream>>>(
      hbf + H_, (ll)T_ * H_, (ll)L_ * H_, (ll)H_,
      wslot, (ll)H_ * H_, nullptr,
      kb, (ll)T_ * H_, (ll)SEG_ * T_ * H_, (ll)H_, nullptr, B_ * T_);
  f2bf<<<dim3(2048), blk, 0, stream>>>(seg_vw, wslot, W8);
  gemm_mfma<__hip_bfloat16, 257><<<gq, blk, 0, stream>>>(
      hbf + H_, (ll)T_ * H_, (ll)L_ * H_, (ll)H_,
      wslot, (ll)H_ * H_, nullptr,
      vb, (ll)T_ * H_, (ll)SEG_ * T_ * H_, (ll)H_, nullptr, B_ * T_);

  // 2. Blord projection (fp32, M=8)
  gemm_bt<float><<<dim3(16, 1, 1), blk, 0, stream>>>(
      hidden, 0, 1, (ll)L_ * H_, 0,
      Blord_w, 0, Blord_b,
      lords_in, 0, 1, (ll)17 * H_, 0,
      nullptr, B_, H_);

  // 3. segment attention (MFMA flash) -> self_out fp32 + sob bf16
  seg_attn_mfma<<<dim3(3, NH_, B_ * SEG_), blk, 0, stream>>>(qb, kb, vb, self_out, sob);

  // 4. gather lord inputs
  copy_lords_in<<<dim3(B_ * SEG_), blk, 0, stream>>>(self_out, lords_in);

  // 5. lord q/k/v projections (fp32, M=136)
  gemm_bt<float><<<dim3(16, 3, 1), blk, 0, stream>>>(
      lords_in, 0, 136, 0, (ll)H_, lord_qw, 0, nullptr,
      lqw_, 0, 136, 0, (ll)H_, nullptr, 136, H_);
  gemm_bt<float><<<dim3(16, 3, 1), blk, 0, stream>>>(
      lords_in, 0, 136, 0, (ll)H_, lord_kw, 0, nullptr,
      lkw_, 0, 136, 0, (ll)H_, nullptr, 136, H_);
  gemm_bt<float><<<dim3(16, 3, 1), blk, 0, stream>>>(
      lords_in, 0, 136, 0, (ll)H_, lord_vw, 0, nullptr,
      lvw_, 0, 136, 0, (ll)H_, nullptr, 136, H_);

  // 6. lord attention -> lord rows of self_out (fp32 + bf16 mirror)
  lord_attn<<<dim3(B_), dim3(272), 0, stream>>>(lqw_, lkw_, lvw_, self_out, sob);

  // 7. output dense + bias + residual (bf16 MFMA) -> attn_out (overwrites qb/kb)
  f2bf<<<dim3(2048), blk, 0, stream>>>(out_w, outw_bf, (H_ * H_) / 8);
  gemm_mfma<float, 0><<<dim3(8, 258, 1), blk, 0, stream>>>(
      sob, 0, 0, 0,
      outw_bf, 0, out_b,
      attn_out, 0, 0, 0, hidden, B_ * L_);

  // 8. LayerNorm in place
  ln_inplace<<<dim3(B_ * L_), blk, 0, stream>>>(attn_out, ln_w, ln_b);
}

// Round 4
// 1530.747 us; speedup vs baseline: 4.9472x; 1.1187x over previous
//
#include <hip/hip_runtime.h>
#include <hip/hip_bf16.h>

typedef long long ll;
typedef __attribute__((ext_vector_type(8))) short bf16x8;
typedef __attribute__((ext_vector_type(4))) float fx4;

#define B_ 8
#define SEG_ 16
#define T_ 257
#define H_ 1024
#define NH_ 16
#define L_ 4113
#define SCALE 0.125f

__device__ __forceinline__ float bf2f(unsigned short u) {
  union { unsigned int i; float f; } w; w.i = ((unsigned int)u) << 16; return w.f;
}
__device__ __forceinline__ unsigned short f2bfu(float x) {
  __hip_bfloat16 h = __float2bfloat16(x);
  return *(unsigned short*)&h;
}
__device__ __forceinline__ void store_ct(float* p, float v) { *p = v; }
__device__ __forceinline__ void store_ct(__hip_bfloat16* p, float v) { *p = __float2bfloat16(v); }

__device__ __forceinline__ void gl_lds16(const void* g, void* l) {
  __builtin_amdgcn_global_load_lds((const __attribute__((address_space(1))) void*)g,
                                   (__attribute__((address_space(3))) void*)l, 16, 0, 0);
}

// ---------------- fp32 -> bf16 convert (n multiple of 8) ----------------
__global__ __launch_bounds__(256) void f2bf(const float* __restrict__ src,
                                            __hip_bfloat16* __restrict__ dst, int n8) {
  for (int i = blockIdx.x * 256 + threadIdx.x; i < n8; i += gridDim.x * 256) {
    float4 a = ((const float4*)src)[i * 2];
    float4 b = ((const float4*)src)[i * 2 + 1];
    union { bf16x8 v; unsigned short u[8]; } o;
    o.u[0] = f2bfu(a.x); o.u[1] = f2bfu(a.y); o.u[2] = f2bfu(a.z); o.u[3] = f2bfu(a.w);
    o.u[4] = f2bfu(b.x); o.u[5] = f2bfu(b.y); o.u[6] = f2bfu(b.z); o.u[7] = f2bfu(b.w);
    ((bf16x8*)dst)[i] = o.v;
  }
}

// ---------------- bf16 MFMA GEMM: C[m,n] = sum_k A[m,k]*W[n,k] ----------------
// 2-phase double-buffered pipeline (T3 minimum recipe) + bijective XCD swizzle (T1).
// Grid total blocks MUST be a multiple of 8.
template<typename CT, int XT>
__global__ __launch_bounds__(256) void gemm_mfma(
    const __hip_bfloat16* __restrict__ Ab, ll axz, ll axb, ll axr,
    const __hip_bfloat16* __restrict__ Bb, ll bwz,
    const float* __restrict__ bias,
    CT* __restrict__ Cb, ll czs, ll cbs, ll crs,
    const float* __restrict__ res,
    int M)
{
  // --- XCD-aware block swizzle: contiguous work chunks per XCD ---
  const int gx = gridDim.x, gy = gridDim.y;
  const int nwg = gx * gy * gridDim.z;
  const int orig = blockIdx.x + gx * (blockIdx.y + gy * blockIdx.z);
  const int swz = (orig & 7) * (nwg >> 3) + (orig >> 3);
  const int bx = swz % gx;
  const int t2 = swz / gx;
  const int by = t2 % gy;
  const int bz = t2 / gy;

  const __hip_bfloat16* A = Ab + (ll)bz * axz;
  const __hip_bfloat16* W = Bb + (ll)bz * bwz;
  CT* C = Cb + (ll)bz * czs;

  __shared__ __hip_bfloat16 At[2][128 * 32];
  __shared__ __hip_bfloat16 Bt[2][128 * 32];

  const int tid = threadIdx.x;
  const int lane = tid & 63;
  const int wid = tid >> 6;
  const int m0 = by * 128;
  const int n0 = bx * 128;
  const int wm = (wid >> 1) * 64;
  const int wn = (wid & 1) * 64;

  const int r0 = tid >> 2;            // staging row within 64-row half
  const int kc = (tid & 3) * 8;       // staging k-col (elements)
  int am0 = m0 + r0;      if (am0 > M - 1) am0 = M - 1;
  int am1 = m0 + 64 + r0; if (am1 > M - 1) am1 = M - 1;
  ll aoff0, aoff1;
  if (XT) {
    aoff0 = (ll)(am0 / XT) * axb + (ll)(am0 % XT) * axr;
    aoff1 = (ll)(am1 / XT) * axb + (ll)(am1 % XT) * axr;
  } else {
    aoff0 = (ll)am0 * 1024; aoff1 = (ll)am1 * 1024;
  }
  const ll boff0 = (ll)(n0 + r0) * 1024;
  const ll boff1 = (ll)(n0 + 64 + r0) * 1024;

  fx4 acc[4][4];
#pragma unroll
  for (int i = 0; i < 4; ++i)
#pragma unroll
    for (int j = 0; j < 4; ++j) acc[i][j] = fx4{0.f, 0.f, 0.f, 0.f};

  const int fragA = (wm + (lane & 15)) * 32 + ((lane >> 4) << 3);
  const int fragB = (wn + (lane & 15)) * 32 + ((lane >> 4) << 3);
  const int stA0 = r0 * 32 + kc;

  // prologue: stage k0=0 into buffer 0
  gl_lds16(A + aoff0 + kc, (void*)(&At[0][0] + stA0));
  gl_lds16(A + aoff1 + kc, (void*)(&At[0][0] + 2048 + stA0));
  gl_lds16(W + boff0 + kc, (void*)(&Bt[0][0] + stA0));
  gl_lds16(W + boff1 + kc, (void*)(&Bt[0][0] + 2048 + stA0));
  __syncthreads();   // drains vmcnt(0)

  int cur = 0;
  for (int k0 = 0; k0 < 1024; k0 += 32) {
    // issue next K-tile loads into the other buffer (hidden under MFMA below)
    if (k0 + 32 < 1024) {
      const int kn = k0 + 32;
      const int nxt = cur ^ 1;
      gl_lds16(A + aoff0 + kn + kc, (void*)(&At[nxt][0] + stA0));
      gl_lds16(A + aoff1 + kn + kc, (void*)(&At[nxt][0] + 2048 + stA0));
      gl_lds16(W + boff0 + kn + kc, (void*)(&Bt[nxt][0] + stA0));
      gl_lds16(W + boff1 + kn + kc, (void*)(&Bt[nxt][0] + 2048 + stA0));
    }

    const __hip_bfloat16* ap = &At[cur][0] + fragA;
    const __hip_bfloat16* bp = &Bt[cur][0] + fragB;
    bf16x8 af[4], bfr[4];
#pragma unroll
    for (int f = 0; f < 4; ++f) {
      af[f]  = *(const bf16x8*)(ap + f * 16 * 32);
      bfr[f] = *(const bf16x8*)(bp + f * 16 * 32);
    }
#pragma unroll
    for (int mf = 0; mf < 4; ++mf)
#pragma unroll
      for (int nf = 0; nf < 4; ++nf)
        acc[mf][nf] = __builtin_amdgcn_mfma_f32_16x16x32_bf16(af[mf], bfr[nf], acc[mf][nf], 0, 0, 0);

    __syncthreads();   // vmcnt(0)+lgkmcnt(0) drain: next buffer ready
    cur ^= 1;
  }

  const int cn = n0 + wn + (lane & 15);
#pragma unroll
  for (int mf = 0; mf < 4; ++mf) {
    int mloc = m0 + wm + mf * 16 + ((lane >> 4) << 2);
#pragma unroll
    for (int r = 0; r < 4; ++r) {
      int m = mloc + r;
      if (m >= M) continue;
      ll co;
      if (XT) co = (ll)(m / XT) * cbs + (ll)(m % XT) * crs;
      else    co = (ll)m * 1024;
#pragma unroll
      for (int nf = 0; nf < 4; ++nf) {
        int n = cn + nf * 16;
        float v = acc[mf][nf][r];
        if (bias) v += bias[n];
        if (res)  v += res[(ll)m * 1024 + n];
        store_ct(C + co + n, v);
      }
    }
  }
}

// ---------------- MFMA flash attention over one segment ----------------
__global__ __launch_bounds__(256) void seg_attn_mfma(
    const __hip_bfloat16* __restrict__ Qb,
    const __hip_bfloat16* __restrict__ Kb,
    const __hip_bfloat16* __restrict__ Vb,
    float* __restrict__ so, __hip_bfloat16* __restrict__ sob)
{
  __shared__ __align__(16) char smem[8192 + 9216 + 4 * 4096];
  char* KsB = smem;                 // K tile [64][64] bf16, XOR-swizzled 16B slots
  char* VTB = smem + 8192;          // V^T [64 d][72 kk] bf16 (uint-packed writes)
  const int tid = threadIdx.x, lane = tid & 63, wid = tid >> 6;
  char* PB = smem + 8192 + 9216 + wid * 4096;  // per-wave P [32][64] bf16, swizzled

  const int h = blockIdx.y, bs = blockIdx.z;
  const int b = bs >> 4, s = bs & 15;
  const int q0 = blockIdx.x * 128 + wid * 32;
  const bool qvalid = (q0 <= 256);
  const ll base = (ll)bs * (T_ * H_) + h * 64;

  // Q fragments (rows clamped)
  bf16x8 qf[2][2];
#pragma unroll
  for (int mf = 0; mf < 2; ++mf) {
    int qr = q0 + mf * 16 + (lane & 15); if (qr > 256) qr = 256;
#pragma unroll
    for (int ks = 0; ks < 2; ++ks)
      qf[mf][ks] = *(const bf16x8*)(Qb + base + (ll)qr * H_ + ks * 32 + ((lane >> 4) << 3));
  }

  float m_[2][4], l_[2][4];
  fx4 of[2][4];
#pragma unroll
  for (int mf = 0; mf < 2; ++mf) {
#pragma unroll
    for (int r = 0; r < 4; ++r) { m_[mf][r] = -1e30f; l_[mf][r] = 0.f; }
#pragma unroll
    for (int df = 0; df < 4; ++df) of[mf][df] = fx4{0.f, 0.f, 0.f, 0.f};
  }

  const int krow = tid >> 3;          // K staging row (issue 0), +32 for issue 1
  const int kc8 = tid & 7;            // 16B slot within row
  const int kkp = tid & 31;           // VT: kk pair index
  const int vd0 = (tid >> 5) * 8;     // VT: d block

  for (int t = 0; t < 5; ++t) {
    const int k0 = t * 64;
    __syncthreads();
    // --- stage K (swizzled via pre-swizzled global source) ---
    {
      int row = krow;
      int kr = k0 + row; if (kr > 256) kr = 256;
      gl_lds16(Kb + base + (ll)kr * H_ + ((kc8 ^ (row & 7)) << 3), KsB + tid * 16);
      row = krow + 32;
      kr = k0 + row; if (kr > 256) kr = 256;
      gl_lds16(Kb + base + (ll)kr * H_ + ((kc8 ^ (row & 7)) << 3), KsB + 4096 + tid * 16);
    }
    // --- stage V^T (packed conflict-free writes) ---
    {
      int kk = kkp * 2;
      int kr0 = k0 + kk;     if (kr0 > 256) kr0 = 256;
      int kr1 = k0 + kk + 1; if (kr1 > 256) kr1 = 256;
      bf16x8 v0 = *(const bf16x8*)(Vb + base + (ll)kr0 * H_ + vd0);
      bf16x8 v1 = *(const bf16x8*)(Vb + base + (ll)kr1 * H_ + vd0);
      unsigned int* vtu = (unsigned int*)VTB;
#pragma unroll
      for (int j = 0; j < 8; ++j)
        vtu[(vd0 + j) * 36 + kkp] =
            (unsigned int)(unsigned short)v0[j] | ((unsigned int)(unsigned short)v1[j] << 16);
    }
    __syncthreads();

    if (qvalid) {
      // --- S = Q K^T ---
      fx4 sa[2][4];
#pragma unroll
      for (int mf = 0; mf < 2; ++mf)
#pragma unroll
        for (int nf = 0; nf < 4; ++nf) sa[mf][nf] = fx4{0.f, 0.f, 0.f, 0.f};
#pragma unroll
      for (int nf = 0; nf < 4; ++nf) {
        int key = nf * 16 + (lane & 15);
#pragma unroll
        for (int ks = 0; ks < 2; ++ks) {
          int c16 = ks * 4 + (lane >> 4);
          bf16x8 kf = *(const bf16x8*)(KsB + key * 128 + ((c16 ^ (key & 7)) << 4));
          sa[0][nf] = __builtin_amdgcn_mfma_f32_16x16x32_bf16(qf[0][ks], kf, sa[0][nf], 0, 0, 0);
          sa[1][nf] = __builtin_amdgcn_mfma_f32_16x16x32_bf16(qf[1][ks], kf, sa[1][nf], 0, 0, 0);
        }
      }
      // --- scale + mask ---
#pragma unroll
      for (int nf = 0; nf < 4; ++nf) {
        bool bad = (k0 + nf * 16 + (lane & 15)) > 256;
#pragma unroll
        for (int mf = 0; mf < 2; ++mf) {
          if (bad) sa[mf][nf] = fx4{-3e38f, -3e38f, -3e38f, -3e38f};
          else     sa[mf][nf] *= SCALE;
        }
      }
      // --- online softmax ---
#pragma unroll
      for (int mf = 0; mf < 2; ++mf) {
        float rowsum[4];
#pragma unroll
        for (int r = 0; r < 4; ++r) {
          float mr = fmaxf(fmaxf(sa[mf][0][r], sa[mf][1][r]), fmaxf(sa[mf][2][r], sa[mf][3][r]));
          mr = fmaxf(mr, __shfl_xor(mr, 1));
          mr = fmaxf(mr, __shfl_xor(mr, 2));
          mr = fmaxf(mr, __shfl_xor(mr, 4));
          mr = fmaxf(mr, __shfl_xor(mr, 8));
          float mo = m_[mf][r];
          float mn = fmaxf(mo, mr);
          float sf = __expf(mo - mn);
          m_[mf][r] = mn;
          l_[mf][r] *= sf;
#pragma unroll
          for (int df = 0; df < 4; ++df) of[mf][df][r] *= sf;
          rowsum[r] = 0.f;
        }
#pragma unroll
        for (int nf = 0; nf < 4; ++nf)
#pragma unroll
          for (int r = 0; r < 4; ++r) {
            float p = __expf(sa[mf][nf][r] - m_[mf][r]);
            sa[mf][nf][r] = p;
            rowsum[r] += p;
          }
#pragma unroll
        for (int r = 0; r < 4; ++r) {
          float rs = rowsum[r];
          rs += __shfl_xor(rs, 1);
          rs += __shfl_xor(rs, 2);
          rs += __shfl_xor(rs, 4);
          rs += __shfl_xor(rs, 8);
          l_[mf][r] += rs;
        }
      }
      // --- write P to per-wave swizzled LDS (fixed-register pair shuffle) ---
#pragma unroll
      for (int mf = 0; mf < 2; ++mf)
#pragma unroll
        for (int nf = 0; nf < 4; ++nf)
#pragma unroll
          for (int rp = 0; rp < 2; ++rp) {
            float v0 = sa[mf][nf][rp];        // row rp, own col
            float v2 = sa[mf][nf][rp + 2];    // row rp+2, own col
            float o0 = __shfl_xor(v0, 1);     // row rp, partner col
            float o2 = __shfl_xor(v2, 1);     // row rp+2, partner col
            const bool odd = (lane & 1);
            float lo = odd ? o2 : v0;         // even col value of the row we write
            float hi = odd ? v2 : o0;         // odd col value
            unsigned int pk = (unsigned int)f2bfu(lo) | ((unsigned int)f2bfu(hi) << 16);
            int row = mf * 16 + ((lane >> 4) << 2) + (odd ? rp + 2 : rp);
            int col2 = nf * 16 + (lane & 14);
            *(unsigned int*)(PB + row * 128 + ((col2 * 2) ^ ((row & 7) << 4))) = pk;
          }
      // --- O += P V ---
#pragma unroll
      for (int kks = 0; kks < 2; ++kks) {
        bf16x8 pa[2];
#pragma unroll
        for (int mf = 0; mf < 2; ++mf) {
          int prow = mf * 16 + (lane & 15);
          int c16 = kks * 4 + (lane >> 4);
          pa[mf] = *(const bf16x8*)(PB + prow * 128 + ((c16 ^ (prow & 7)) << 4));
        }
#pragma unroll
        for (int df = 0; df < 4; ++df) {
          bf16x8 vf = *(const bf16x8*)(VTB + (df * 16 + (lane & 15)) * 144 + kks * 64 + ((lane >> 4) << 4));
          of[0][df] = __builtin_amdgcn_mfma_f32_16x16x32_bf16(pa[0], vf, of[0][df], 0, 0, 0);
          of[1][df] = __builtin_amdgcn_mfma_f32_16x16x32_bf16(pa[1], vf, of[1][df], 0, 0, 0);
        }
      }
    }
  }

  if (qvalid) {
#pragma unroll
    for (int mf = 0; mf < 2; ++mf)
#pragma unroll
      for (int r = 0; r < 4; ++r) {
        int q = q0 + mf * 16 + ((lane >> 4) << 2) + r;
        if (q > 256) continue;
        float inv = 1.f / l_[mf][r];
        ll rowoff = ((ll)b * L_ + 1 + (ll)s * T_ + q) * H_ + h * 64;
#pragma unroll
        for (int df = 0; df < 4; ++df) {
          int d = df * 16 + (lane & 15);
          float v = of[mf][df][r] * inv;
          so[rowoff + d] = v;
          sob[rowoff + d] = __float2bfloat16(v);
        }
      }
  }
}

// ---------------- small fp32 VALU GEMM (lord path, M tiny) ----------------
template<typename CT>
__global__ __launch_bounds__(256) void gemm_bt(
    const float* __restrict__ Xb, ll xzs, int xT, ll xbs, ll xrs,
    const float* __restrict__ Wb, ll wzs,
    const float* __restrict__ bias,
    CT* __restrict__ Cb, ll czs, int cT, ll cbs, ll crs,
    const float* __restrict__ res,
    int M, int K)
{
  const float* X = Xb + (ll)blockIdx.z * xzs;
  const float* W = Wb + (ll)blockIdx.z * wzs;
  CT* C = Cb + (ll)blockIdx.z * czs;

  const int tid = threadIdx.x;
  const int m0 = blockIdx.y * 64;
  const int n0 = blockIdx.x * 64;

  __shared__ float Xt[16][68];
  __shared__ float Wt[16][68];

  const int lr = tid >> 2;
  const int lc = (tid & 3) << 2;
  const int mload = m0 + lr;
  const bool mok = (mload < M);
  const ll xoff = mok ? ((ll)(mload / xT) * xbs + (ll)(mload % xT) * xrs) : 0;
  const ll woff = (ll)(n0 + lr) * K;

  const int tr = tid >> 4;
  const int tc = tid & 15;

  float acc[4][4];
#pragma unroll
  for (int i = 0; i < 4; ++i)
#pragma unroll
    for (int j = 0; j < 4; ++j) acc[i][j] = 0.f;

  for (int k0 = 0; k0 < K; k0 += 16) {
    float4 xv = make_float4(0.f, 0.f, 0.f, 0.f);
    if (mok) xv = *(const float4*)(X + xoff + k0 + lc);
    float4 wv = *(const float4*)(W + woff + k0 + lc);
    __syncthreads();
    Xt[lc + 0][lr] = xv.x; Xt[lc + 1][lr] = xv.y; Xt[lc + 2][lr] = xv.z; Xt[lc + 3][lr] = xv.w;
    Wt[lc + 0][lr] = wv.x; Wt[lc + 1][lr] = wv.y; Wt[lc + 2][lr] = wv.z; Wt[lc + 3][lr] = wv.w;
    __syncthreads();
#pragma unroll
    for (int kk = 0; kk < 16; ++kk) {
      float4 xa = *(const float4*)&Xt[kk][tr << 2];
      float4 wb = *(const float4*)&Wt[kk][tc << 2];
      float xa_[4] = {xa.x, xa.y, xa.z, xa.w};
      float wb_[4] = {wb.x, wb.y, wb.z, wb.w};
#pragma unroll
      for (int i = 0; i < 4; ++i)
#pragma unroll
        for (int j = 0; j < 4; ++j)
          acc[i][j] = fmaf(xa_[i], wb_[j], acc[i][j]);
    }
  }

#pragma unroll
  for (int i = 0; i < 4; ++i) {
    int m = m0 + (tr << 2) + i;
    if (m >= M) continue;
    ll co = (ll)(m / cT) * cbs + (ll)(m % cT) * crs;
#pragma unroll
    for (int j = 0; j < 4; ++j) {
      int n = n0 + (tc << 2) + j;
      float v = acc[i][j];
      if (bias) v += bias[n];
      if (res)  v += res[(ll)m * H_ + n];
      store_ct(C + co + n, v);
    }
  }
}

__global__ __launch_bounds__(256) void copy_lords_in(
    const float* __restrict__ so, float* __restrict__ lin)
{
  int b = blockIdx.x / SEG_, s = blockIdx.x % SEG_;
  int i = threadIdx.x * 4;
  *(float4*)(lin + ((ll)(b * 17 + 1 + s)) * H_ + i) =
      *(const float4*)(so + ((ll)b * L_ + 1 + (ll)s * T_) * H_ + i);
}

__global__ __launch_bounds__(320) void lord_attn(
    const float* __restrict__ lq, const float* __restrict__ lk,
    const float* __restrict__ lv, float* __restrict__ so,
    __hip_bfloat16* __restrict__ sob)
{
  int b = blockIdx.x;
  int tid = threadIdx.x;
  if (tid >= NH_ * 17) return;
  int h = tid / 17, qi = tid % 17;
  const float* qp = lq + ((ll)(b * 17 + qi)) * H_ + h * 64;
  float q[64];
#pragma unroll
  for (int d = 0; d < 64; ++d) q[d] = qp[d];
  float sc[17];
#pragma unroll
  for (int k = 0; k < 17; ++k) {
    const float* kp = lk + ((ll)(b * 17 + k)) * H_ + h * 64;
    float s_ = 0.f;
#pragma unroll
    for (int d = 0; d < 64; ++d) s_ = fmaf(q[d], kp[d], s_);
    sc[k] = s_ * SCALE;
  }
  float mx = sc[0];
#pragma unroll
  for (int k = 1; k < 17; ++k) mx = fmaxf(mx, sc[k]);
  float l = 0.f;
#pragma unroll
  for (int k = 0; k < 17; ++k) { sc[k] = __expf(sc[k] - mx); l += sc[k]; }
  float invl = 1.f / l;
  float out[64];
#pragma unroll
  for (int d = 0; d < 64; ++d) out[d] = 0.f;
#pragma unroll
  for (int k = 0; k < 17; ++k) {
    const float* vp = lv + ((ll)(b * 17 + k)) * H_ + h * 64;
    float p = sc[k];
#pragma unroll
    for (int d = 0; d < 64; ++d) out[d] = fmaf(p, vp[d], out[d]);
  }
  ll row = (qi == 0) ? (ll)b * L_ : ((ll)b * L_ + 1 + (ll)(qi - 1) * T_);
#pragma unroll
  for (int d = 0; d < 64; ++d) {
    float v = out[d] * invl;
    so[row * H_ + h * 64 + d] = v;
    sob[row * H_ + h * 64 + d] = __float2bfloat16(v);
  }
}

__global__ __launch_bounds__(256) void ln_inplace(
    float* __restrict__ hbuf, const float* __restrict__ w, const float* __restrict__ bgain)
{
  const ll row = blockIdx.x;
  const int tid = threadIdx.x;
  float4 x = *(float4*)(hbuf + row * H_ + tid * 4);
  float s = x.x + x.y + x.z + x.w;
  float s2 = x.x * x.x + x.y * x.y + x.z * x.z + x.w * x.w;
#pragma unroll
  for (int off = 32; off >= 1; off >>= 1) {
    s  += __shfl_down(s, off, 64);
    s2 += __shfl_down(s2, off, 64);
  }
  __shared__ float red[2][4];
  int wid = tid >> 6;
  if ((tid & 63) == 0) { red[0][wid] = s; red[1][wid] = s2; }
  __syncthreads();
  s  = red[0][0] + red[0][1] + red[0][2] + red[0][3];
  s2 = red[1][0] + red[1][1] + red[1][2] + red[1][3];
  const float mean = s * (1.f / H_);
  float var = s2 * (1.f / H_) - mean * mean;
  var = fmaxf(var, 0.f);
  const float inv = rsqrtf(var + 1e-12f);
  float4 g = *(const float4*)(w + tid * 4);
  float4 bb = *(const float4*)(bgain + tid * 4);
  float4 y;
  y.x = (x.x - mean) * inv * g.x + bb.x;
  y.y = (x.y - mean) * inv * g.y + bb.y;
  y.z = (x.z - mean) * inv * g.z + bb.z;
  y.w = (x.w - mean) * inv * g.w + bb.w;
  *(float4*)(hbuf + row * H_ + tid * 4) = y;
}

extern "C" void kernel_launch(void* const* d_in, const int* in_sizes, int n_in,
                              void* d_out, int out_size, void* d_ws, size_t ws_size,
                              hipStream_t stream)
{
  const float* hidden  = (const float*)d_in[0];
  const float* Blord_w = (const float*)d_in[1];
  const float* Blord_b = (const float*)d_in[2];
  const float* seg_qw  = (const float*)d_in[3];
  const float* seg_kw  = (const float*)d_in[4];
  const float* seg_vw  = (const float*)d_in[5];
  const float* lord_qw = (const float*)d_in[6];
  const float* lord_kw = (const float*)d_in[7];
  const float* lord_vw = (const float*)d_in[8];
  const float* out_w   = (const float*)d_in[9];
  const float* out_b   = (const float*)d_in[10];
  const float* ln_w    = (const float*)d_in[11];
  const float* ln_b    = (const float*)d_in[12];

  float* attn_out = (float*)d_out;                          // output 0 [B,L,H]
  float* self_out = (float*)d_out + (ll)B_ * L_ * H_;       // output 1 [B,L,H]

  const ll QKV = (ll)B_ * SEG_ * T_ * H_;                   // 33,685,504 elems
  // qb + kb live in the attn_out region (free until the out-dense write)
  __hip_bfloat16* qb = (__hip_bfloat16*)attn_out;
  __hip_bfloat16* kb = qb + QKV;
  // workspace
  __hip_bfloat16* vb   = (__hip_bfloat16*)d_ws;
  __hip_bfloat16* hbf  = vb + QKV;                          // aliased: so_bf after attention
  __hip_bfloat16* sob  = hbf;
  __hip_bfloat16* wslot = hbf + (ll)B_ * L_ * H_;           // one weight set
  __hip_bfloat16* outw_bf = wslot + (ll)SEG_ * H_ * H_;
  float* lords_in = (float*)(outw_bf + (ll)H_ * H_);
  float* lqw_ = lords_in + 136 * 1024;
  float* lkw_ = lqw_ + 136 * 1024;
  float* lvw_ = lkw_ + 136 * 1024;

  dim3 blk(256);
  const int HID8 = (B_ * L_ * H_) / 8;
  const int W8   = (SEG_ * H_ * H_) / 8;

  // 0. convert hidden to bf16
  f2bf<<<dim3(2048), blk, 0, stream>>>(hidden, hbf, HID8);

  // 1. segment QKV projections (bf16 MFMA), weights converted through one slot
  dim3 gq(8, 17, 16);   // 2176 blocks, %8==0 (XCD swizzle requirement)
  f2bf<<<dim3(2048), blk, 0, stream>>>(seg_qw, wslot, W8);
  gemm_mfma<__hip_bfloat16, 257><<<gq, blk, 0, stream>>>(
      hbf + H_, (ll)T_ * H_, (ll)L_ * H_, (ll)H_,
      wslot, (ll)H_ * H_, nullptr,
      qb, (ll)T_ * H_, (ll)SEG_ * T_ * H_, (ll)H_, nullptr, B_ * T_);
  f2bf<<<dim3(2048), blk, 0, stream>>>(seg_kw, wslot, W8);
  gemm_mfma<__hip_bfloat16, 257><<<gq, blk, 0, stream>>>(
      hbf + H_, (ll)T_ * H_, (ll)L_ * H_, (ll)H_,
      wslot, (ll)H_ * H_, nullptr,
      kb, (ll)T_ * H_, (ll)SEG_ * T_ * H_, (ll)H_, nullptr, B_ * T_);
  f2bf<<<dim3(2048), blk, 0, stream>>>(seg_vw, wslot, W8);
  gemm_mfma<__hip_bfloat16, 257><<<gq, blk, 0, stream>>>(
      hbf + H_, (ll)T_ * H_, (ll)L_ * H_, (ll)H_,
      wslot, (ll)H_ * H_, nullptr,
      vb, (ll)T_ * H_, (ll)SEG_ * T_ * H_, (ll)H_, nullptr, B_ * T_);

  // 2. Blord projection (fp32, M=8)
  gemm_bt<float><<<dim3(16, 1, 1), blk, 0, stream>>>(
      hidden, 0, 1, (ll)L_ * H_, 0,
      Blord_w, 0, Blord_b,
      lords_in, 0, 1, (ll)17 * H_, 0,
      nullptr, B_, H_);

  // 3. segment attention (MFMA flash) -> self_out fp32 + sob bf16
  seg_attn_mfma<<<dim3(3, NH_, B_ * SEG_), blk, 0, stream>>>(qb, kb, vb, self_out, sob);

  // 4. gather lord inputs
  copy_lords_in<<<dim3(B_ * SEG_), blk, 0, stream>>>(self_out, lords_in);

  // 5. lord q/k/v projections (fp32, M=136)
  gemm_bt<float><<<dim3(16, 3, 1), blk, 0, stream>>>(
      lords_in, 0, 136, 0, (ll)H_, lord_qw, 0, nullptr,
      lqw_, 0, 136, 0, (ll)H_, nullptr, 136, H_);
  gemm_bt<float><<<dim3(16, 3, 1), blk, 0, stream>>>(
      lords_in, 0, 136, 0, (ll)H_, lord_kw, 0, nullptr,
      lkw_, 0, 136, 0, (ll)H_, nullptr, 136, H_);
  gemm_bt<float><<<dim3(16, 3, 1), blk, 0, stream>>>(
      lords_in, 0, 136, 0, (ll)H_, lord_vw, 0, nullptr,
      lvw_, 0, 136, 0, (ll)H_, nullptr, 136, H_);

  // 6. lord attention -> lord rows of self_out (fp32 + bf16 mirror)
  lord_attn<<<dim3(B_), dim3(272), 0, stream>>>(lqw_, lkw_, lvw_, self_out, sob);

  // 7. output dense + bias + residual (bf16 MFMA) -> attn_out (overwrites qb/kb)
  f2bf<<<dim3(2048), blk, 0, stream>>>(out_w, outw_bf, (H_ * H_) / 8);
  gemm_mfma<float, 0><<<dim3(8, 258, 1), blk, 0, stream>>>(   // 2064 blocks, %8==0
      sob, 0, 0, 0,
      outw_bf, 0, out_b,
      attn_out, 0, 0, 0, hidden, B_ * L_);

  // 8. LayerNorm in place
  ln_inplace<<<dim3(B_ * L_), blk, 0, stream>>>(attn_out, ln_w, ln_b);
}

// Round 5
// 1088.155 us; speedup vs baseline: 6.9594x; 1.4067x over previous
//
#include <hip/hip_runtime.h>
#include <hip/hip_bf16.h>

typedef long long ll;
typedef __attribute__((ext_vector_type(8))) short bf16x8;
typedef __attribute__((ext_vector_type(4))) float fx4;

#define B_ 8
#define SEG_ 16
#define T_ 257
#define H_ 1024
#define NH_ 16
#define L_ 4113
#define SCALE 0.125f

__device__ __forceinline__ float bf2f(unsigned short u) {
  union { unsigned int i; float f; } w; w.i = ((unsigned int)u) << 16; return w.f;
}
__device__ __forceinline__ unsigned short f2bfu(float x) {
  __hip_bfloat16 h = __float2bfloat16(x);
  return *(unsigned short*)&h;
}
__device__ __forceinline__ void store_ct(float* p, float v) { *p = v; }
__device__ __forceinline__ void store_ct(__hip_bfloat16* p, float v) { *p = __float2bfloat16(v); }

__device__ __forceinline__ void gl_lds16(const void* g, void* l) {
  __builtin_amdgcn_global_load_lds((const __attribute__((address_space(1))) void*)g,
                                   (__attribute__((address_space(3))) void*)l, 16, 0, 0);
}

// ---------------- fp32 -> bf16 convert (n multiple of 8) ----------------
__global__ __launch_bounds__(256) void f2bf(const float* __restrict__ src,
                                            __hip_bfloat16* __restrict__ dst, int n8) {
  for (int i = blockIdx.x * 256 + threadIdx.x; i < n8; i += gridDim.x * 256) {
    float4 a = ((const float4*)src)[i * 2];
    float4 b = ((const float4*)src)[i * 2 + 1];
    union { bf16x8 v; unsigned short u[8]; } o;
    o.u[0] = f2bfu(a.x); o.u[1] = f2bfu(a.y); o.u[2] = f2bfu(a.z); o.u[3] = f2bfu(a.w);
    o.u[4] = f2bfu(b.x); o.u[5] = f2bfu(b.y); o.u[6] = f2bfu(b.z); o.u[7] = f2bfu(b.w);
    ((bf16x8*)dst)[i] = o.v;
  }
}

// ---------------- bf16 MFMA GEMM: C[m,n] = sum_k A[m,k]*W[n,k] ----------------
// 2-phase double-buffered pipeline + bijective XCD swizzle. Grid blocks %8==0.
template<typename CT, int XT>
__global__ __launch_bounds__(256) void gemm_mfma(
    const __hip_bfloat16* __restrict__ Ab, ll axz, ll axb, ll axr,
    const __hip_bfloat16* __restrict__ Bb, ll bwz,
    const float* __restrict__ bias,
    CT* __restrict__ Cb, ll czs, ll cbs, ll crs,
    const float* __restrict__ res,
    int M)
{
  const int gx = gridDim.x, gy = gridDim.y;
  const int nwg = gx * gy * gridDim.z;
  const int orig = blockIdx.x + gx * (blockIdx.y + gy * blockIdx.z);
  const int swz = (orig & 7) * (nwg >> 3) + (orig >> 3);
  const int bx = swz % gx;
  const int t2 = swz / gx;
  const int by = t2 % gy;
  const int bz = t2 / gy;

  const __hip_bfloat16* A = Ab + (ll)bz * axz;
  const __hip_bfloat16* W = Bb + (ll)bz * bwz;
  CT* C = Cb + (ll)bz * czs;

  __shared__ __hip_bfloat16 At[2][128 * 32];
  __shared__ __hip_bfloat16 Bt[2][128 * 32];

  const int tid = threadIdx.x;
  const int lane = tid & 63;
  const int wid = tid >> 6;
  const int m0 = by * 128;
  const int n0 = bx * 128;
  const int wm = (wid >> 1) * 64;
  const int wn = (wid & 1) * 64;

  const int r0 = tid >> 2;
  const int kc = (tid & 3) * 8;
  int am0 = m0 + r0;      if (am0 > M - 1) am0 = M - 1;
  int am1 = m0 + 64 + r0; if (am1 > M - 1) am1 = M - 1;
  ll aoff0, aoff1;
  if (XT) {
    aoff0 = (ll)(am0 / XT) * axb + (ll)(am0 % XT) * axr;
    aoff1 = (ll)(am1 / XT) * axb + (ll)(am1 % XT) * axr;
  } else {
    aoff0 = (ll)am0 * 1024; aoff1 = (ll)am1 * 1024;
  }
  const ll boff0 = (ll)(n0 + r0) * 1024;
  const ll boff1 = (ll)(n0 + 64 + r0) * 1024;

  fx4 acc[4][4];
#pragma unroll
  for (int i = 0; i < 4; ++i)
#pragma unroll
    for (int j = 0; j < 4; ++j) acc[i][j] = fx4{0.f, 0.f, 0.f, 0.f};

  const int fragA = (wm + (lane & 15)) * 32 + ((lane >> 4) << 3);
  const int fragB = (wn + (lane & 15)) * 32 + ((lane >> 4) << 3);
  const int stA0 = r0 * 32 + kc;

  gl_lds16(A + aoff0 + kc, (void*)(&At[0][0] + stA0));
  gl_lds16(A + aoff1 + kc, (void*)(&At[0][0] + 2048 + stA0));
  gl_lds16(W + boff0 + kc, (void*)(&Bt[0][0] + stA0));
  gl_lds16(W + boff1 + kc, (void*)(&Bt[0][0] + 2048 + stA0));
  __syncthreads();

  int cur = 0;
  for (int k0 = 0; k0 < 1024; k0 += 32) {
    if (k0 + 32 < 1024) {
      const int kn = k0 + 32;
      const int nxt = cur ^ 1;
      gl_lds16(A + aoff0 + kn + kc, (void*)(&At[nxt][0] + stA0));
      gl_lds16(A + aoff1 + kn + kc, (void*)(&At[nxt][0] + 2048 + stA0));
      gl_lds16(W + boff0 + kn + kc, (void*)(&Bt[nxt][0] + stA0));
      gl_lds16(W + boff1 + kn + kc, (void*)(&Bt[nxt][0] + 2048 + stA0));
    }

    const __hip_bfloat16* ap = &At[cur][0] + fragA;
    const __hip_bfloat16* bp = &Bt[cur][0] + fragB;
    bf16x8 af[4], bfr[4];
#pragma unroll
    for (int f = 0; f < 4; ++f) {
      af[f]  = *(const bf16x8*)(ap + f * 16 * 32);
      bfr[f] = *(const bf16x8*)(bp + f * 16 * 32);
    }
#pragma unroll
    for (int mf = 0; mf < 4; ++mf)
#pragma unroll
      for (int nf = 0; nf < 4; ++nf)
        acc[mf][nf] = __builtin_amdgcn_mfma_f32_16x16x32_bf16(af[mf], bfr[nf], acc[mf][nf], 0, 0, 0);

    __syncthreads();
    cur ^= 1;
  }

  const int cn = n0 + wn + (lane & 15);
#pragma unroll
  for (int mf = 0; mf < 4; ++mf) {
    int mloc = m0 + wm + mf * 16 + ((lane >> 4) << 2);
#pragma unroll
    for (int r = 0; r < 4; ++r) {
      int m = mloc + r;
      if (m >= M) continue;
      ll co;
      if (XT) co = (ll)(m / XT) * cbs + (ll)(m % XT) * crs;
      else    co = (ll)m * 1024;
#pragma unroll
      for (int nf = 0; nf < 4; ++nf) {
        int n = cn + nf * 16;
        float v = acc[mf][nf][r];
        if (bias) v += bias[n];
        if (res)  v += res[(ll)m * 1024 + n];
        store_ct(C + co + n, v);
      }
    }
  }
}

// ---------------- MFMA flash attention over one segment ----------------
__global__ __launch_bounds__(256) void seg_attn_mfma(
    const __hip_bfloat16* __restrict__ Qb,
    const __hip_bfloat16* __restrict__ Kb,
    const __hip_bfloat16* __restrict__ Vb,
    float* __restrict__ so, __hip_bfloat16* __restrict__ sob)
{
  __shared__ __align__(16) char smem[8192 + 9216 + 4 * 4096];
  char* KsB = smem;
  char* VTB = smem + 8192;
  const int tid = threadIdx.x, lane = tid & 63, wid = tid >> 6;
  char* PB = smem + 8192 + 9216 + wid * 4096;

  const int h = blockIdx.y, bs = blockIdx.z;
  const int b = bs >> 4, s = bs & 15;
  const int q0 = blockIdx.x * 128 + wid * 32;
  const bool qvalid = (q0 <= 256);
  const ll base = (ll)bs * (T_ * H_) + h * 64;

  bf16x8 qf[2][2];
#pragma unroll
  for (int mf = 0; mf < 2; ++mf) {
    int qr = q0 + mf * 16 + (lane & 15); if (qr > 256) qr = 256;
#pragma unroll
    for (int ks = 0; ks < 2; ++ks)
      qf[mf][ks] = *(const bf16x8*)(Qb + base + (ll)qr * H_ + ks * 32 + ((lane >> 4) << 3));
  }

  float m_[2][4], l_[2][4];
  fx4 of[2][4];
#pragma unroll
  for (int mf = 0; mf < 2; ++mf) {
#pragma unroll
    for (int r = 0; r < 4; ++r) { m_[mf][r] = -1e30f; l_[mf][r] = 0.f; }
#pragma unroll
    for (int df = 0; df < 4; ++df) of[mf][df] = fx4{0.f, 0.f, 0.f, 0.f};
  }

  const int krow = tid >> 3;
  const int kc8 = tid & 7;
  const int kkp = tid & 31;
  const int vd0 = (tid >> 5) * 8;

  for (int t = 0; t < 5; ++t) {
    const int k0 = t * 64;
    __syncthreads();
    {
      int row = krow;
      int kr = k0 + row; if (kr > 256) kr = 256;
      gl_lds16(Kb + base + (ll)kr * H_ + ((kc8 ^ (row & 7)) << 3), KsB + tid * 16);
      row = krow + 32;
      kr = k0 + row; if (kr > 256) kr = 256;
      gl_lds16(Kb + base + (ll)kr * H_ + ((kc8 ^ (row & 7)) << 3), KsB + 4096 + tid * 16);
    }
    {
      int kk = kkp * 2;
      int kr0 = k0 + kk;     if (kr0 > 256) kr0 = 256;
      int kr1 = k0 + kk + 1; if (kr1 > 256) kr1 = 256;
      bf16x8 v0 = *(const bf16x8*)(Vb + base + (ll)kr0 * H_ + vd0);
      bf16x8 v1 = *(const bf16x8*)(Vb + base + (ll)kr1 * H_ + vd0);
      unsigned int* vtu = (unsigned int*)VTB;
#pragma unroll
      for (int j = 0; j < 8; ++j)
        vtu[(vd0 + j) * 36 + kkp] =
            (unsigned int)(unsigned short)v0[j] | ((unsigned int)(unsigned short)v1[j] << 16);
    }
    __syncthreads();

    if (qvalid) {
      fx4 sa[2][4];
#pragma unroll
      for (int mf = 0; mf < 2; ++mf)
#pragma unroll
        for (int nf = 0; nf < 4; ++nf) sa[mf][nf] = fx4{0.f, 0.f, 0.f, 0.f};
#pragma unroll
      for (int nf = 0; nf < 4; ++nf) {
        int key = nf * 16 + (lane & 15);
#pragma unroll
        for (int ks = 0; ks < 2; ++ks) {
          int c16 = ks * 4 + (lane >> 4);
          bf16x8 kf = *(const bf16x8*)(KsB + key * 128 + ((c16 ^ (key & 7)) << 4));
          sa[0][nf] = __builtin_amdgcn_mfma_f32_16x16x32_bf16(qf[0][ks], kf, sa[0][nf], 0, 0, 0);
          sa[1][nf] = __builtin_amdgcn_mfma_f32_16x16x32_bf16(qf[1][ks], kf, sa[1][nf], 0, 0, 0);
        }
      }
#pragma unroll
      for (int nf = 0; nf < 4; ++nf) {
        bool bad = (k0 + nf * 16 + (lane & 15)) > 256;
#pragma unroll
        for (int mf = 0; mf < 2; ++mf) {
          if (bad) sa[mf][nf] = fx4{-3e38f, -3e38f, -3e38f, -3e38f};
          else     sa[mf][nf] *= SCALE;
        }
      }
#pragma unroll
      for (int mf = 0; mf < 2; ++mf) {
        float rowsum[4];
#pragma unroll
        for (int r = 0; r < 4; ++r) {
          float mr = fmaxf(fmaxf(sa[mf][0][r], sa[mf][1][r]), fmaxf(sa[mf][2][r], sa[mf][3][r]));
          mr = fmaxf(mr, __shfl_xor(mr, 1));
          mr = fmaxf(mr, __shfl_xor(mr, 2));
          mr = fmaxf(mr, __shfl_xor(mr, 4));
          mr = fmaxf(mr, __shfl_xor(mr, 8));
          float mo = m_[mf][r];
          float mn = fmaxf(mo, mr);
          float sf = __expf(mo - mn);
          m_[mf][r] = mn;
          l_[mf][r] *= sf;
#pragma unroll
          for (int df = 0; df < 4; ++df) of[mf][df][r] *= sf;
          rowsum[r] = 0.f;
        }
#pragma unroll
        for (int nf = 0; nf < 4; ++nf)
#pragma unroll
          for (int r = 0; r < 4; ++r) {
            float p = __expf(sa[mf][nf][r] - m_[mf][r]);
            sa[mf][nf][r] = p;
            rowsum[r] += p;
          }
#pragma unroll
        for (int r = 0; r < 4; ++r) {
          float rs = rowsum[r];
          rs += __shfl_xor(rs, 1);
          rs += __shfl_xor(rs, 2);
          rs += __shfl_xor(rs, 4);
          rs += __shfl_xor(rs, 8);
          l_[mf][r] += rs;
        }
      }
#pragma unroll
      for (int mf = 0; mf < 2; ++mf)
#pragma unroll
        for (int nf = 0; nf < 4; ++nf)
#pragma unroll
          for (int rp = 0; rp < 2; ++rp) {
            float v0 = sa[mf][nf][rp];
            float v2 = sa[mf][nf][rp + 2];
            float o0 = __shfl_xor(v0, 1);
            float o2 = __shfl_xor(v2, 1);
            const bool odd = (lane & 1);
            float lo = odd ? o2 : v0;
            float hi = odd ? v2 : o0;
            unsigned int pk = (unsigned int)f2bfu(lo) | ((unsigned int)f2bfu(hi) << 16);
            int row = mf * 16 + ((lane >> 4) << 2) + (odd ? rp + 2 : rp);
            int col2 = nf * 16 + (lane & 14);
            *(unsigned int*)(PB + row * 128 + ((col2 * 2) ^ ((row & 7) << 4))) = pk;
          }
#pragma unroll
      for (int kks = 0; kks < 2; ++kks) {
        bf16x8 pa[2];
#pragma unroll
        for (int mf = 0; mf < 2; ++mf) {
          int prow = mf * 16 + (lane & 15);
          int c16 = kks * 4 + (lane >> 4);
          pa[mf] = *(const bf16x8*)(PB + prow * 128 + ((c16 ^ (prow & 7)) << 4));
        }
#pragma unroll
        for (int df = 0; df < 4; ++df) {
          bf16x8 vf = *(const bf16x8*)(VTB + (df * 16 + (lane & 15)) * 144 + kks * 64 + ((lane >> 4) << 4));
          of[0][df] = __builtin_amdgcn_mfma_f32_16x16x32_bf16(pa[0], vf, of[0][df], 0, 0, 0);
          of[1][df] = __builtin_amdgcn_mfma_f32_16x16x32_bf16(pa[1], vf, of[1][df], 0, 0, 0);
        }
      }
    }
  }

  if (qvalid) {
#pragma unroll
    for (int mf = 0; mf < 2; ++mf)
#pragma unroll
      for (int r = 0; r < 4; ++r) {
        int q = q0 + mf * 16 + ((lane >> 4) << 2) + r;
        if (q > 256) continue;
        float inv = 1.f / l_[mf][r];
        ll rowoff = ((ll)b * L_ + 1 + (ll)s * T_ + q) * H_ + h * 64;
#pragma unroll
        for (int df = 0; df < 4; ++df) {
          int d = df * 16 + (lane & 15);
          float v = of[mf][df][r] * inv;
          so[rowoff + d] = v;
          sob[rowoff + d] = __float2bfloat16(v);
        }
      }
  }
}

// ---------------- small fp32 VALU GEMM (Blord path) ----------------
template<typename CT>
__global__ __launch_bounds__(256) void gemm_bt(
    const float* __restrict__ Xb, ll xzs, int xT, ll xbs, ll xrs,
    const float* __restrict__ Wb, ll wzs,
    const float* __restrict__ bias,
    CT* __restrict__ Cb, ll czs, int cT, ll cbs, ll crs,
    const float* __restrict__ res,
    int M, int K)
{
  const float* X = Xb + (ll)blockIdx.z * xzs;
  const float* W = Wb + (ll)blockIdx.z * wzs;
  CT* C = Cb + (ll)blockIdx.z * czs;

  const int tid = threadIdx.x;
  const int m0 = blockIdx.y * 64;
  const int n0 = blockIdx.x * 64;

  __shared__ float Xt[16][68];
  __shared__ float Wt[16][68];

  const int lr = tid >> 2;
  const int lc = (tid & 3) << 2;
  const int mload = m0 + lr;
  const bool mok = (mload < M);
  const ll xoff = mok ? ((ll)(mload / xT) * xbs + (ll)(mload % xT) * xrs) : 0;
  const ll woff = (ll)(n0 + lr) * K;

  const int tr = tid >> 4;
  const int tc = tid & 15;

  float acc[4][4];
#pragma unroll
  for (int i = 0; i < 4; ++i)
#pragma unroll
    for (int j = 0; j < 4; ++j) acc[i][j] = 0.f;

  for (int k0 = 0; k0 < K; k0 += 16) {
    float4 xv = make_float4(0.f, 0.f, 0.f, 0.f);
    if (mok) xv = *(const float4*)(X + xoff + k0 + lc);
    float4 wv = *(const float4*)(W + woff + k0 + lc);
    __syncthreads();
    Xt[lc + 0][lr] = xv.x; Xt[lc + 1][lr] = xv.y; Xt[lc + 2][lr] = xv.z; Xt[lc + 3][lr] = xv.w;
    Wt[lc + 0][lr] = wv.x; Wt[lc + 1][lr] = wv.y; Wt[lc + 2][lr] = wv.z; Wt[lc + 3][lr] = wv.w;
    __syncthreads();
#pragma unroll
    for (int kk = 0; kk < 16; ++kk) {
      float4 xa = *(const float4*)&Xt[kk][tr << 2];
      float4 wb = *(const float4*)&Wt[kk][tc << 2];
      float xa_[4] = {xa.x, xa.y, xa.z, xa.w};
      float wb_[4] = {wb.x, wb.y, wb.z, wb.w};
#pragma unroll
      for (int i = 0; i < 4; ++i)
#pragma unroll
        for (int j = 0; j < 4; ++j)
          acc[i][j] = fmaf(xa_[i], wb_[j], acc[i][j]);
    }
  }

#pragma unroll
  for (int i = 0; i < 4; ++i) {
    int m = m0 + (tr << 2) + i;
    if (m >= M) continue;
    ll co = (ll)(m / cT) * cbs + (ll)(m % cT) * crs;
#pragma unroll
    for (int j = 0; j < 4; ++j) {
      int n = n0 + (tc << 2) + j;
      float v = acc[i][j];
      if (bias) v += bias[n];
      if (res)  v += res[(ll)m * H_ + n];
      store_ct(C + co + n, v);
    }
  }
}

// ---------------- batched lord q/k/v projections (M=136, fp32) ----------------
// grid (16 n-tiles, 3 m-tiles, 3 which); z selects weight/output.
__global__ __launch_bounds__(256) void lord_proj(
    const float* __restrict__ X,
    const float* __restrict__ Wq, const float* __restrict__ Wk, const float* __restrict__ Wv,
    float* __restrict__ Cq, float* __restrict__ Ck, float* __restrict__ Cv)
{
  const float* W = (blockIdx.z == 0) ? Wq : (blockIdx.z == 1) ? Wk : Wv;
  float* C = (blockIdx.z == 0) ? Cq : (blockIdx.z == 1) ? Ck : Cv;
  const int M = 136, K = 1024;

  const int tid = threadIdx.x;
  const int m0 = blockIdx.y * 64;
  const int n0 = blockIdx.x * 64;

  __shared__ float Xt[16][68];
  __shared__ float Wt[16][68];

  const int lr = tid >> 2;
  const int lc = (tid & 3) << 2;
  const int mload = min(m0 + lr, M - 1);
  const ll xoff = (ll)mload * K;
  const ll woff = (ll)(n0 + lr) * K;

  const int tr = tid >> 4;
  const int tc = tid & 15;

  float acc[4][4];
#pragma unroll
  for (int i = 0; i < 4; ++i)
#pragma unroll
    for (int j = 0; j < 4; ++j) acc[i][j] = 0.f;

  for (int k0 = 0; k0 < K; k0 += 16) {
    float4 xv = *(const float4*)(X + xoff + k0 + lc);
    float4 wv = *(const float4*)(W + woff + k0 + lc);
    __syncthreads();
    Xt[lc + 0][lr] = xv.x; Xt[lc + 1][lr] = xv.y; Xt[lc + 2][lr] = xv.z; Xt[lc + 3][lr] = xv.w;
    Wt[lc + 0][lr] = wv.x; Wt[lc + 1][lr] = wv.y; Wt[lc + 2][lr] = wv.z; Wt[lc + 3][lr] = wv.w;
    __syncthreads();
#pragma unroll
    for (int kk = 0; kk < 16; ++kk) {
      float4 xa = *(const float4*)&Xt[kk][tr << 2];
      float4 wb = *(const float4*)&Wt[kk][tc << 2];
      float xa_[4] = {xa.x, xa.y, xa.z, xa.w};
      float wb_[4] = {wb.x, wb.y, wb.z, wb.w};
#pragma unroll
      for (int i = 0; i < 4; ++i)
#pragma unroll
        for (int j = 0; j < 4; ++j)
          acc[i][j] = fmaf(xa_[i], wb_[j], acc[i][j]);
    }
  }

#pragma unroll
  for (int i = 0; i < 4; ++i) {
    int m = m0 + (tr << 2) + i;
    if (m >= M) continue;
#pragma unroll
    for (int j = 0; j < 4; ++j)
      C[(ll)m * 1024 + n0 + (tc << 2) + j] = acc[i][j];
  }
}

__global__ __launch_bounds__(256) void copy_lords_in(
    const float* __restrict__ so, float* __restrict__ lin)
{
  int b = blockIdx.x / SEG_, s = blockIdx.x % SEG_;
  int i = threadIdx.x * 4;
  *(float4*)(lin + ((ll)(b * 17 + 1 + s)) * H_ + i) =
      *(const float4*)(so + ((ll)b * L_ + 1 + (ll)s * T_) * H_ + i);
}

// ---------------- lord attention v2: LDS-staged, wave-parallel ----------------
// grid (B, NH), 256 threads. Wave wid owns queries q = wid, wid+4, ...
__global__ __launch_bounds__(256) void lord_attn2(
    const float* __restrict__ lq, const float* __restrict__ lk,
    const float* __restrict__ lv, float* __restrict__ so,
    __hip_bfloat16* __restrict__ sob)
{
  const int b = blockIdx.x, h = blockIdx.y;
  const int tid = threadIdx.x, lane = tid & 63, wid = tid >> 6;
  __shared__ float Qs[17][64], Ks[17][64], Vs[17][64];
  for (int t = tid; t < 17 * 64; t += 256) {
    int r = t >> 6, c = t & 63;
    ll g = ((ll)(b * 17 + r)) * H_ + h * 64 + c;
    Qs[r][c] = lq[g];
    Ks[r][c] = lk[g];
    Vs[r][c] = lv[g];
  }
  __syncthreads();
  for (int q = wid; q < 17; q += 4) {
    float qd = Qs[q][lane];
    float sc[17];
#pragma unroll
    for (int k = 0; k < 17; ++k) {
      float p = qd * Ks[k][lane];
      p += __shfl_xor(p, 1);  p += __shfl_xor(p, 2);  p += __shfl_xor(p, 4);
      p += __shfl_xor(p, 8);  p += __shfl_xor(p, 16); p += __shfl_xor(p, 32);
      sc[k] = p * SCALE;
    }
    float mx = sc[0];
#pragma unroll
    for (int k = 1; k < 17; ++k) mx = fmaxf(mx, sc[k]);
    float l = 0.f;
#pragma unroll
    for (int k = 0; k < 17; ++k) { sc[k] = __expf(sc[k] - mx); l += sc[k]; }
    float invl = 1.f / l;
    float o = 0.f;
#pragma unroll
    for (int k = 0; k < 17; ++k) o = fmaf(sc[k], Vs[k][lane], o);
    o *= invl;
    ll row = (q == 0) ? (ll)b * L_ : ((ll)b * L_ + 1 + (ll)(q - 1) * T_);
    so[row * H_ + h * 64 + lane] = o;
    sob[row * H_ + h * 64 + lane] = __float2bfloat16(o);
  }
}

__global__ __launch_bounds__(256) void ln_inplace(
    float* __restrict__ hbuf, const float* __restrict__ w, const float* __restrict__ bgain)
{
  const ll row = blockIdx.x;
  const int tid = threadIdx.x;
  float4 x = *(float4*)(hbuf + row * H_ + tid * 4);
  float s = x.x + x.y + x.z + x.w;
  float s2 = x.x * x.x + x.y * x.y + x.z * x.z + x.w * x.w;
#pragma unroll
  for (int off = 32; off >= 1; off >>= 1) {
    s  += __shfl_down(s, off, 64);
    s2 += __shfl_down(s2, off, 64);
  }
  __shared__ float red[2][4];
  int wid = tid >> 6;
  if ((tid & 63) == 0) { red[0][wid] = s; red[1][wid] = s2; }
  __syncthreads();
  s  = red[0][0] + red[0][1] + red[0][2] + red[0][3];
  s2 = red[1][0] + red[1][1] + red[1][2] + red[1][3];
  const float mean = s * (1.f / H_);
  float var = s2 * (1.f / H_) - mean * mean;
  var = fmaxf(var, 0.f);
  const float inv = rsqrtf(var + 1e-12f);
  float4 g = *(const float4*)(w + tid * 4);
  float4 bb = *(const float4*)(bgain + tid * 4);
  float4 y;
  y.x = (x.x - mean) * inv * g.x + bb.x;
  y.y = (x.y - mean) * inv * g.y + bb.y;
  y.z = (x.z - mean) * inv * g.z + bb.z;
  y.w = (x.w - mean) * inv * g.w + bb.w;
  *(float4*)(hbuf + row * H_ + tid * 4) = y;
}

extern "C" void kernel_launch(void* const* d_in, const int* in_sizes, int n_in,
                              void* d_out, int out_size, void* d_ws, size_t ws_size,
                              hipStream_t stream)
{
  const float* hidden  = (const float*)d_in[0];
  const float* Blord_w = (const float*)d_in[1];
  const float* Blord_b = (const float*)d_in[2];
  const float* seg_qw  = (const float*)d_in[3];
  const float* seg_kw  = (const float*)d_in[4];
  const float* seg_vw  = (const float*)d_in[5];
  const float* lord_qw = (const float*)d_in[6];
  const float* lord_kw = (const float*)d_in[7];
  const float* lord_vw = (const float*)d_in[8];
  const float* out_w   = (const float*)d_in[9];
  const float* out_b   = (const float*)d_in[10];
  const float* ln_w    = (const float*)d_in[11];
  const float* ln_b    = (const float*)d_in[12];

  float* attn_out = (float*)d_out;                          // output 0 [B,L,H]
  float* self_out = (float*)d_out + (ll)B_ * L_ * H_;       // output 1 [B,L,H]

  const ll QKV = (ll)B_ * SEG_ * T_ * H_;
  __hip_bfloat16* qb = (__hip_bfloat16*)attn_out;
  __hip_bfloat16* kb = qb + QKV;
  __hip_bfloat16* vb   = (__hip_bfloat16*)d_ws;
  __hip_bfloat16* hbf  = vb + QKV;
  __hip_bfloat16* sob  = hbf;
  __hip_bfloat16* wslot = hbf + (ll)B_ * L_ * H_;
  __hip_bfloat16* outw_bf = wslot + (ll)SEG_ * H_ * H_;
  float* lords_in = (float*)(outw_bf + (ll)H_ * H_);
  float* lqw_ = lords_in + 136 * 1024;
  float* lkw_ = lqw_ + 136 * 1024;
  float* lvw_ = lkw_ + 136 * 1024;

  dim3 blk(256);
  const int HID8 = (B_ * L_ * H_) / 8;
  const int W8   = (SEG_ * H_ * H_) / 8;

  // 0. convert hidden to bf16
  f2bf<<<dim3(2048), blk, 0, stream>>>(hidden, hbf, HID8);

  // 1. segment QKV projections (bf16 MFMA)
  dim3 gq(8, 17, 16);
  f2bf<<<dim3(2048), blk, 0, stream>>>(seg_qw, wslot, W8);
  gemm_mfma<__hip_bfloat16, 257><<<gq, blk, 0, stream>>>(
      hbf + H_, (ll)T_ * H_, (ll)L_ * H_, (ll)H_,
      wslot, (ll)H_ * H_, nullptr,
      qb, (ll)T_ * H_, (ll)SEG_ * T_ * H_, (ll)H_, nullptr, B_ * T_);
  f2bf<<<dim3(2048), blk, 0, stream>>>(seg_kw, wslot, W8);
  gemm_mfma<__hip_bfloat16, 257><<<gq, blk, 0, stream>>>(
      hbf + H_, (ll)T_ * H_, (ll)L_ * H_, (ll)H_,
      wslot, (ll)H_ * H_, nullptr,
      kb, (ll)T_ * H_, (ll)SEG_ * T_ * H_, (ll)H_, nullptr, B_ * T_);
  f2bf<<<dim3(2048), blk, 0, stream>>>(seg_vw, wslot, W8);
  gemm_mfma<__hip_bfloat16, 257><<<gq, blk, 0, stream>>>(
      hbf + H_, (ll)T_ * H_, (ll)L_ * H_, (ll)H_,
      wslot, (ll)H_ * H_, nullptr,
      vb, (ll)T_ * H_, (ll)SEG_ * T_ * H_, (ll)H_, nullptr, B_ * T_);

  // 2. Blord projection (fp32, M=8)
  gemm_bt<float><<<dim3(16, 1, 1), blk, 0, stream>>>(
      hidden, 0, 1, (ll)L_ * H_, 0,
      Blord_w, 0, Blord_b,
      lords_in, 0, 1, (ll)17 * H_, 0,
      nullptr, B_, H_);

  // 3. segment attention (MFMA flash)
  seg_attn_mfma<<<dim3(3, NH_, B_ * SEG_), blk, 0, stream>>>(qb, kb, vb, self_out, sob);

  // 4. gather lord inputs
  copy_lords_in<<<dim3(B_ * SEG_), blk, 0, stream>>>(self_out, lords_in);

  // 5. lord q/k/v projections — one batched dispatch (144 blocks)
  lord_proj<<<dim3(16, 3, 3), blk, 0, stream>>>(
      lords_in, lord_qw, lord_kw, lord_vw, lqw_, lkw_, lvw_);

  // 6. lord attention v2 -> lord rows of self_out (fp32 + bf16 mirror)
  lord_attn2<<<dim3(B_, NH_), blk, 0, stream>>>(lqw_, lkw_, lvw_, self_out, sob);

  // 7. output dense + bias + residual (bf16 MFMA) -> attn_out
  f2bf<<<dim3(2048), blk, 0, stream>>>(out_w, outw_bf, (H_ * H_) / 8);
  gemm_mfma<float, 0><<<dim3(8, 258, 1), blk, 0, stream>>>(
      sob, 0, 0, 0,
      outw_bf, 0, out_b,
      attn_out, 0, 0, 0, hidden, B_ * L_);

  // 8. LayerNorm in place
  ln_inplace<<<dim3(B_ * L_), blk, 0, stream>>>(attn_out, ln_w, ln_b);
}

// Round 8
// 876.830 us; speedup vs baseline: 8.6366x; 1.2410x over previous
//
#include <hip/hip_runtime.h>
#include <hip/hip_bf16.h>

typedef long long ll;
typedef __attribute__((ext_vector_type(8))) short bf16x8;
typedef __attribute__((ext_vector_type(4))) float fx4;

#define B_ 8
#define SEG_ 16
#define T_ 257
#define H_ 1024
#define NH_ 16
#define L_ 4113
#define SCALE 0.125f

__device__ __forceinline__ unsigned short f2bfu(float x) {
  __hip_bfloat16 h = __float2bfloat16(x);
  return *(unsigned short*)&h;
}

__device__ __forceinline__ void gl_lds16(const void* g, void* l) {
  __builtin_amdgcn_global_load_lds((const __attribute__((address_space(1))) void*)g,
                                   (__attribute__((address_space(3))) void*)l, 16, 0, 0);
}

// ---------------- fused fp32 -> bf16 conversion of all inputs ----------------
#define NU_HID 4211712
#define NU_W   2097152
#define NU_OW  131072
__global__ __launch_bounds__(256) void f2bf_all(
    const float* __restrict__ hid, __hip_bfloat16* __restrict__ hbf,
    const float* __restrict__ wq, const float* __restrict__ wk, const float* __restrict__ wv,
    __hip_bfloat16* __restrict__ w3,
    const float* __restrict__ ow, __hip_bfloat16* __restrict__ owb)
{
  const int NTOT = NU_HID + 3 * NU_W + NU_OW;
  for (int i = blockIdx.x * 256 + threadIdx.x; i < NTOT; i += gridDim.x * 256) {
    const float* src;
    __hip_bfloat16* dst;
    if (i < NU_HID) {
      src = hid + (ll)i * 8;
      dst = hbf + (ll)i * 8;
    } else if (i < NU_HID + 3 * NU_W) {
      int j = i - NU_HID;
      int which = j >> 21;               // NU_W = 2^21
      int off = j & (NU_W - 1);
      const float* ws = (which == 0) ? wq : (which == 1) ? wk : wv;
      src = ws + (ll)off * 8;
      dst = w3 + (ll)j * 8;
    } else {
      int k = i - NU_HID - 3 * NU_W;
      src = ow + (ll)k * 8;
      dst = owb + (ll)k * 8;
    }
    float4 a = ((const float4*)src)[0];
    float4 b = ((const float4*)src)[1];
    union { bf16x8 v; unsigned short u[8]; } o;
    o.u[0] = f2bfu(a.x); o.u[1] = f2bfu(a.y); o.u[2] = f2bfu(a.z); o.u[3] = f2bfu(a.w);
    o.u[4] = f2bfu(b.x); o.u[5] = f2bfu(b.y); o.u[6] = f2bfu(b.z); o.u[7] = f2bfu(b.w);
    *(bf16x8*)dst = o.v;
  }
}

// ---------------- fused QKV GEMM (2-phase __syncthreads dbuf) ----------------
// grid (24,17,16): bx>>3 selects Q/K/V; (bx&7)=n-tile; by=m-tile; bz=segment.
__global__ __launch_bounds__(256) void gemm_qkv(
    const __hip_bfloat16* __restrict__ A,     // hbf + H_
    const __hip_bfloat16* __restrict__ Wall,  // [3][SEG][H][H]
    __hip_bfloat16* __restrict__ Cq,
    __hip_bfloat16* __restrict__ Ck,
    __hip_bfloat16* __restrict__ Cv)
{
  const int nwg = 24 * 17 * 16;
  const int orig = blockIdx.x + 24 * (blockIdx.y + 17 * blockIdx.z);
  const int swz = (orig & 7) * (nwg >> 3) + (orig >> 3);
  const int bx = swz % 24;
  const int t2 = swz / 24;
  const int by = t2 % 17;
  const int bz = t2 / 17;
  const int which = bx >> 3;
  const int n0 = (bx & 7) * 128;
  const int m0 = by * 128;
  const int M = B_ * T_;   // 2056

  const __hip_bfloat16* W = Wall + ((ll)which * SEG_ + bz) * ((ll)H_ * H_);
  __hip_bfloat16* C = (which == 0) ? Cq : (which == 1) ? Ck : Cv;

  __shared__ __hip_bfloat16 At[2][128 * 32];
  __shared__ __hip_bfloat16 Bt[2][128 * 32];

  const int tid = threadIdx.x;
  const int lane = tid & 63;
  const int wid = tid >> 6;
  const int wm = (wid >> 1) * 64;
  const int wn = (wid & 1) * 64;

  const int r0 = tid >> 2;
  const int kc = (tid & 3) * 8;
  const int am0 = min(m0 + r0, M - 1);
  const int am1 = min(m0 + 64 + r0, M - 1);
  // FIX(r7): A row must include the SEGMENT offset bz*T_*H_ (r6/r7 read segment 0
  // for every segment — the 0.25 absmax bug).
  const ll segoff = (ll)bz * ((ll)T_ * H_);
  const ll aoff0 = (ll)(am0 / T_) * ((ll)L_ * H_) + segoff + (ll)(am0 % T_) * H_;
  const ll aoff1 = (ll)(am1 / T_) * ((ll)L_ * H_) + segoff + (ll)(am1 % T_) * H_;
  const ll boff0 = (ll)(n0 + r0) * H_;
  const ll boff1 = (ll)(n0 + 64 + r0) * H_;
  const int stA0 = r0 * 32 + kc;

  fx4 acc[4][4];
#pragma unroll
  for (int i = 0; i < 4; ++i)
#pragma unroll
    for (int j = 0; j < 4; ++j) acc[i][j] = fx4{0.f, 0.f, 0.f, 0.f};

  const int fragA = (wm + (lane & 15)) * 32 + ((lane >> 4) << 3);
  const int fragB = (wn + (lane & 15)) * 32 + ((lane >> 4) << 3);

  gl_lds16(A + aoff0 + kc, (void*)(&At[0][0] + stA0));
  gl_lds16(A + aoff1 + kc, (void*)(&At[0][0] + 2048 + stA0));
  gl_lds16(W + boff0 + kc, (void*)(&Bt[0][0] + stA0));
  gl_lds16(W + boff1 + kc, (void*)(&Bt[0][0] + 2048 + stA0));
  __syncthreads();

  int cur = 0;
  for (int k0 = 0; k0 < 1024; k0 += 32) {
    if (k0 + 32 < 1024) {
      const int kn = k0 + 32;
      const int nxt = cur ^ 1;
      gl_lds16(A + aoff0 + kn + kc, (void*)(&At[nxt][0] + stA0));
      gl_lds16(A + aoff1 + kn + kc, (void*)(&At[nxt][0] + 2048 + stA0));
      gl_lds16(W + boff0 + kn + kc, (void*)(&Bt[nxt][0] + stA0));
      gl_lds16(W + boff1 + kn + kc, (void*)(&Bt[nxt][0] + 2048 + stA0));
    }

    const __hip_bfloat16* ap = &At[cur][0] + fragA;
    const __hip_bfloat16* bp = &Bt[cur][0] + fragB;
    bf16x8 af[4], bfr[4];
#pragma unroll
    for (int f = 0; f < 4; ++f) {
      af[f]  = *(const bf16x8*)(ap + f * 16 * 32);
      bfr[f] = *(const bf16x8*)(bp + f * 16 * 32);
    }
#pragma unroll
    for (int mf = 0; mf < 4; ++mf)
#pragma unroll
      for (int nf = 0; nf < 4; ++nf)
        acc[mf][nf] = __builtin_amdgcn_mfma_f32_16x16x32_bf16(af[mf], bfr[nf], acc[mf][nf], 0, 0, 0);

    __syncthreads();
    cur ^= 1;
  }

  const int cn = n0 + wn + (lane & 15);
#pragma unroll
  for (int mf = 0; mf < 4; ++mf) {
    int mloc = m0 + wm + mf * 16 + ((lane >> 4) << 2);
#pragma unroll
    for (int r = 0; r < 4; ++r) {
      int m = mloc + r;
      if (m >= M) continue;
      ll co = ((ll)(m / T_) * SEG_ + bz) * ((ll)T_ * H_) + (ll)(m % T_) * H_;
#pragma unroll
      for (int nf = 0; nf < 4; ++nf)
        C[co + cn + nf * 16] = __float2bfloat16(acc[mf][nf][r]);
    }
  }
}

// ---------------- output dense GEMM (2-phase dbuf): fp32 + bias + residual ----------------
__global__ __launch_bounds__(256) void gemm_out(
    const __hip_bfloat16* __restrict__ A,   // sob [B*L][H]
    const __hip_bfloat16* __restrict__ W,   // outw_bf [H][H]
    const float* __restrict__ bias,
    float* __restrict__ C,
    const float* __restrict__ res)
{
  const int nwg = 8 * 258;
  const int orig = blockIdx.x + 8 * blockIdx.y;
  const int swz = (orig & 7) * (nwg >> 3) + (orig >> 3);
  const int bx = swz % 8;
  const int by = swz / 8;
  const int M = B_ * L_;   // 32904
  const int m0 = by * 128;
  const int n0 = bx * 128;

  __shared__ __hip_bfloat16 At[2][128 * 32];
  __shared__ __hip_bfloat16 Bt[2][128 * 32];

  const int tid = threadIdx.x;
  const int lane = tid & 63;
  const int wid = tid >> 6;
  const int wm = (wid >> 1) * 64;
  const int wn = (wid & 1) * 64;

  const int r0 = tid >> 2;
  const int kc = (tid & 3) * 8;
  const ll aoff0 = (ll)min(m0 + r0, M - 1) * H_;
  const ll aoff1 = (ll)min(m0 + 64 + r0, M - 1) * H_;
  const ll boff0 = (ll)(n0 + r0) * H_;
  const ll boff1 = (ll)(n0 + 64 + r0) * H_;
  const int stA0 = r0 * 32 + kc;

  fx4 acc[4][4];
#pragma unroll
  for (int i = 0; i < 4; ++i)
#pragma unroll
    for (int j = 0; j < 4; ++j) acc[i][j] = fx4{0.f, 0.f, 0.f, 0.f};

  const int fragA = (wm + (lane & 15)) * 32 + ((lane >> 4) << 3);
  const int fragB = (wn + (lane & 15)) * 32 + ((lane >> 4) << 3);

  gl_lds16(A + aoff0 + kc, (void*)(&At[0][0] + stA0));
  gl_lds16(A + aoff1 + kc, (void*)(&At[0][0] + 2048 + stA0));
  gl_lds16(W + boff0 + kc, (void*)(&Bt[0][0] + stA0));
  gl_lds16(W + boff1 + kc, (void*)(&Bt[0][0] + 2048 + stA0));
  __syncthreads();

  int cur = 0;
  for (int k0 = 0; k0 < 1024; k0 += 32) {
    if (k0 + 32 < 1024) {
      const int kn = k0 + 32;
      const int nxt = cur ^ 1;
      gl_lds16(A + aoff0 + kn + kc, (void*)(&At[nxt][0] + stA0));
      gl_lds16(A + aoff1 + kn + kc, (void*)(&At[nxt][0] + 2048 + stA0));
      gl_lds16(W + boff0 + kn + kc, (void*)(&Bt[nxt][0] + stA0));
      gl_lds16(W + boff1 + kn + kc, (void*)(&Bt[nxt][0] + 2048 + stA0));
    }

    const __hip_bfloat16* ap = &At[cur][0] + fragA;
    const __hip_bfloat16* bp = &Bt[cur][0] + fragB;
    bf16x8 af[4], bfr[4];
#pragma unroll
    for (int f = 0; f < 4; ++f) {
      af[f]  = *(const bf16x8*)(ap + f * 16 * 32);
      bfr[f] = *(const bf16x8*)(bp + f * 16 * 32);
    }
#pragma unroll
    for (int mf = 0; mf < 4; ++mf)
#pragma unroll
      for (int nf = 0; nf < 4; ++nf)
        acc[mf][nf] = __builtin_amdgcn_mfma_f32_16x16x32_bf16(af[mf], bfr[nf], acc[mf][nf], 0, 0, 0);

    __syncthreads();
    cur ^= 1;
  }

  const int cn = n0 + wn + (lane & 15);
#pragma unroll
  for (int mf = 0; mf < 4; ++mf) {
    int mloc = m0 + wm + mf * 16 + ((lane >> 4) << 2);
#pragma unroll
    for (int r = 0; r < 4; ++r) {
      int m = mloc + r;
      if (m >= M) continue;
#pragma unroll
      for (int nf = 0; nf < 4; ++nf) {
        int n = cn + nf * 16;
        C[(ll)m * H_ + n] = acc[mf][nf][r] + bias[n] + res[(ll)m * H_ + n];
      }
    }
  }
}

// ---------------- MFMA flash attention over one segment (no-max softmax) ----------------
__global__ __launch_bounds__(256) void seg_attn_mfma(
    const __hip_bfloat16* __restrict__ Qb,
    const __hip_bfloat16* __restrict__ Kb,
    const __hip_bfloat16* __restrict__ Vb,
    float* __restrict__ so, __hip_bfloat16* __restrict__ sob)
{
  __shared__ __align__(16) char smem[8192 + 9216 + 4 * 4096];
  char* KsB = smem;
  char* VTB = smem + 8192;
  const int tid = threadIdx.x, lane = tid & 63, wid = tid >> 6;
  char* PB = smem + 8192 + 9216 + wid * 4096;

  const int h = blockIdx.y, bs = blockIdx.z;
  const int b = bs >> 4, s = bs & 15;
  const int q0 = blockIdx.x * 128 + wid * 32;
  const bool qvalid = (q0 <= 256);
  const ll base = (ll)bs * (T_ * H_) + h * 64;

  bf16x8 qf[2][2];
#pragma unroll
  for (int mf = 0; mf < 2; ++mf) {
    int qr = q0 + mf * 16 + (lane & 15); if (qr > 256) qr = 256;
#pragma unroll
    for (int ks = 0; ks < 2; ++ks)
      qf[mf][ks] = *(const bf16x8*)(Qb + base + (ll)qr * H_ + ks * 32 + ((lane >> 4) << 3));
  }

  float l_[2][4];
  fx4 of[2][4];
#pragma unroll
  for (int mf = 0; mf < 2; ++mf) {
#pragma unroll
    for (int r = 0; r < 4; ++r) l_[mf][r] = 0.f;
#pragma unroll
    for (int df = 0; df < 4; ++df) of[mf][df] = fx4{0.f, 0.f, 0.f, 0.f};
  }

  const int krow = tid >> 3;
  const int kc8 = tid & 7;
  const int kkp = tid & 31;
  const int vd0 = (tid >> 5) * 8;

  for (int t = 0; t < 5; ++t) {
    const int k0 = t * 64;
    __syncthreads();
    {
      int row = krow;
      int kr = k0 + row; if (kr > 256) kr = 256;
      gl_lds16(Kb + base + (ll)kr * H_ + ((kc8 ^ (row & 7)) << 3), KsB + tid * 16);
      row = krow + 32;
      kr = k0 + row; if (kr > 256) kr = 256;
      gl_lds16(Kb + base + (ll)kr * H_ + ((kc8 ^ (row & 7)) << 3), KsB + 4096 + tid * 16);
    }
    {
      int kk = kkp * 2;
      int kr0 = k0 + kk;     if (kr0 > 256) kr0 = 256;
      int kr1 = k0 + kk + 1; if (kr1 > 256) kr1 = 256;
      bf16x8 v0 = *(const bf16x8*)(Vb + base + (ll)kr0 * H_ + vd0);
      bf16x8 v1 = *(const bf16x8*)(Vb + base + (ll)kr1 * H_ + vd0);
      unsigned int* vtu = (unsigned int*)VTB;
#pragma unroll
      for (int j = 0; j < 8; ++j)
        vtu[(vd0 + j) * 36 + kkp] =
            (unsigned int)(unsigned short)v0[j] | ((unsigned int)(unsigned short)v1[j] << 16);
    }
    __syncthreads();

    if (qvalid) {
      fx4 sa[2][4];
#pragma unroll
      for (int mf = 0; mf < 2; ++mf)
#pragma unroll
        for (int nf = 0; nf < 4; ++nf) sa[mf][nf] = fx4{0.f, 0.f, 0.f, 0.f};
#pragma unroll
      for (int nf = 0; nf < 4; ++nf) {
        int key = nf * 16 + (lane & 15);
#pragma unroll
        for (int ks = 0; ks < 2; ++ks) {
          int c16 = ks * 4 + (lane >> 4);
          bf16x8 kf = *(const bf16x8*)(KsB + key * 128 + ((c16 ^ (key & 7)) << 4));
          sa[0][nf] = __builtin_amdgcn_mfma_f32_16x16x32_bf16(qf[0][ks], kf, sa[0][nf], 0, 0, 0);
          sa[1][nf] = __builtin_amdgcn_mfma_f32_16x16x32_bf16(qf[1][ks], kf, sa[1][nf], 0, 0, 0);
        }
      }
#pragma unroll
      for (int nf = 0; nf < 4; ++nf) {
        bool bad = (k0 + nf * 16 + (lane & 15)) > 256;
#pragma unroll
        for (int mf = 0; mf < 2; ++mf) {
#pragma unroll
          for (int r = 0; r < 4; ++r) {
            float p = bad ? 0.f : __expf(sa[mf][nf][r] * SCALE);
            sa[mf][nf][r] = p;
            l_[mf][r] += p;
          }
        }
      }
#pragma unroll
      for (int mf = 0; mf < 2; ++mf)
#pragma unroll
        for (int nf = 0; nf < 4; ++nf)
#pragma unroll
          for (int rp = 0; rp < 2; ++rp) {
            float v0 = sa[mf][nf][rp];
            float v2 = sa[mf][nf][rp + 2];
            float o0 = __shfl_xor(v0, 1);
            float o2 = __shfl_xor(v2, 1);
            const bool odd = (lane & 1);
            float lo = odd ? o2 : v0;
            float hi = odd ? v2 : o0;
            unsigned int pk = (unsigned int)f2bfu(lo) | ((unsigned int)f2bfu(hi) << 16);
            int row = mf * 16 + ((lane >> 4) << 2) + (odd ? rp + 2 : rp);
            int col2 = nf * 16 + (lane & 14);
            *(unsigned int*)(PB + row * 128 + ((col2 * 2) ^ ((row & 7) << 4))) = pk;
          }
#pragma unroll
      for (int kks = 0; kks < 2; ++kks) {
        bf16x8 pa[2];
#pragma unroll
        for (int mf = 0; mf < 2; ++mf) {
          int prow = mf * 16 + (lane & 15);
          int c16 = kks * 4 + (lane >> 4);
          pa[mf] = *(const bf16x8*)(PB + prow * 128 + ((c16 ^ (prow & 7)) << 4));
        }
#pragma unroll
        for (int df = 0; df < 4; ++df) {
          bf16x8 vf = *(const bf16x8*)(VTB + (df * 16 + (lane & 15)) * 144 + kks * 64 + ((lane >> 4) << 4));
          of[0][df] = __builtin_amdgcn_mfma_f32_16x16x32_bf16(pa[0], vf, of[0][df], 0, 0, 0);
          of[1][df] = __builtin_amdgcn_mfma_f32_16x16x32_bf16(pa[1], vf, of[1][df], 0, 0, 0);
        }
      }
    }
  }

  if (qvalid) {
#pragma unroll
    for (int mf = 0; mf < 2; ++mf)
#pragma unroll
      for (int r = 0; r < 4; ++r) {
        float rs = l_[mf][r];
        rs += __shfl_xor(rs, 1);
        rs += __shfl_xor(rs, 2);
        rs += __shfl_xor(rs, 4);
        rs += __shfl_xor(rs, 8);
        l_[mf][r] = rs;
      }
#pragma unroll
    for (int mf = 0; mf < 2; ++mf)
#pragma unroll
      for (int r = 0; r < 4; ++r) {
        int q = q0 + mf * 16 + ((lane >> 4) << 2) + r;
        if (q > 256) continue;
        float inv = 1.f / l_[mf][r];
        ll rowoff = ((ll)b * L_ + 1 + (ll)s * T_ + q) * H_ + h * 64;
#pragma unroll
        for (int df = 0; df < 4; ++df) {
          int d = df * 16 + (lane & 15);
          float v = of[mf][df][r] * inv;
          so[rowoff + d] = v;
          sob[rowoff + d] = __float2bfloat16(v);
        }
      }
  }
}

// ---------------- small fp32 VALU GEMM (Blord path, M=8) ----------------
__global__ __launch_bounds__(256) void gemm_bt(
    const float* __restrict__ X, ll xbs,
    const float* __restrict__ W,
    const float* __restrict__ bias,
    float* __restrict__ C, ll cbs,
    int M, int K)
{
  const int tid = threadIdx.x;
  const int n0 = blockIdx.x * 64;

  __shared__ float Xt[16][68];
  __shared__ float Wt[16][68];

  const int lr = tid >> 2;
  const int lc = (tid & 3) << 2;
  const int mload = min(lr, M - 1);
  const ll xoff = (ll)mload * xbs;
  const ll woff = (ll)(n0 + lr) * K;

  const int tr = tid >> 4;
  const int tc = tid & 15;

  float acc[4][4];
#pragma unroll
  for (int i = 0; i < 4; ++i)
#pragma unroll
    for (int j = 0; j < 4; ++j) acc[i][j] = 0.f;

  for (int k0 = 0; k0 < K; k0 += 16) {
    float4 xv = *(const float4*)(X + xoff + k0 + lc);
    float4 wv = *(const float4*)(W + woff + k0 + lc);
    __syncthreads();
    Xt[lc + 0][lr] = xv.x; Xt[lc + 1][lr] = xv.y; Xt[lc + 2][lr] = xv.z; Xt[lc + 3][lr] = xv.w;
    Wt[lc + 0][lr] = wv.x; Wt[lc + 1][lr] = wv.y; Wt[lc + 2][lr] = wv.z; Wt[lc + 3][lr] = wv.w;
    __syncthreads();
#pragma unroll
    for (int kk = 0; kk < 16; ++kk) {
      float4 xa = *(const float4*)&Xt[kk][tr << 2];
      float4 wb = *(const float4*)&Wt[kk][tc << 2];
      float xa_[4] = {xa.x, xa.y, xa.z, xa.w};
      float wb_[4] = {wb.x, wb.y, wb.z, wb.w};
#pragma unroll
      for (int i = 0; i < 4; ++i)
#pragma unroll
        for (int j = 0; j < 4; ++j)
          acc[i][j] = fmaf(xa_[i], wb_[j], acc[i][j]);
    }
  }

#pragma unroll
  for (int i = 0; i < 4; ++i) {
    int m = (tr << 2) + i;
    if (m >= M) continue;
#pragma unroll
    for (int j = 0; j < 4; ++j) {
      int n = n0 + (tc << 2) + j;
      C[(ll)m * cbs + n] = acc[i][j] + (bias ? bias[n] : 0.f);
    }
  }
}

// ---------------- batched lord q/k/v projections (M=136, fp32) ----------------
__global__ __launch_bounds__(256) void lord_proj(
    const float* __restrict__ X,
    const float* __restrict__ Wq, const float* __restrict__ Wk, const float* __restrict__ Wv,
    float* __restrict__ Cq, float* __restrict__ Ck, float* __restrict__ Cv)
{
  const float* W = (blockIdx.z == 0) ? Wq : (blockIdx.z == 1) ? Wk : Wv;
  float* C = (blockIdx.z == 0) ? Cq : (blockIdx.z == 1) ? Ck : Cv;
  const int M = 136, K = 1024;

  const int tid = threadIdx.x;
  const int m0 = blockIdx.y * 64;
  const int n0 = blockIdx.x * 64;

  __shared__ float Xt[16][68];
  __shared__ float Wt[16][68];

  const int lr = tid >> 2;
  const int lc = (tid & 3) << 2;
  const int mload = min(m0 + lr, M - 1);
  const ll xoff = (ll)mload * K;
  const ll woff = (ll)(n0 + lr) * K;

  const int tr = tid >> 4;
  const int tc = tid & 15;

  float acc[4][4];
#pragma unroll
  for (int i = 0; i < 4; ++i)
#pragma unroll
    for (int j = 0; j < 4; ++j) acc[i][j] = 0.f;

  for (int k0 = 0; k0 < K; k0 += 16) {
    float4 xv = *(const float4*)(X + xoff + k0 + lc);
    float4 wv = *(const float4*)(W + woff + k0 + lc);
    __syncthreads();
    Xt[lc + 0][lr] = xv.x; Xt[lc + 1][lr] = xv.y; Xt[lc + 2][lr] = xv.z; Xt[lc + 3][lr] = xv.w;
    Wt[lc + 0][lr] = wv.x; Wt[lc + 1][lr] = wv.y; Wt[lc + 2][lr] = wv.z; Wt[lc + 3][lr] = wv.w;
    __syncthreads();
#pragma unroll
    for (int kk = 0; kk < 16; ++kk) {
      float4 xa = *(const float4*)&Xt[kk][tr << 2];
      float4 wb = *(const float4*)&Wt[kk][tc << 2];
      float xa_[4] = {xa.x, xa.y, xa.z, xa.w};
      float wb_[4] = {wb.x, wb.y, wb.z, wb.w};
#pragma unroll
      for (int i = 0; i < 4; ++i)
#pragma unroll
        for (int j = 0; j < 4; ++j)
          acc[i][j] = fmaf(xa_[i], wb_[j], acc[i][j]);
    }
  }

#pragma unroll
  for (int i = 0; i < 4; ++i) {
    int m = m0 + (tr << 2) + i;
    if (m >= M) continue;
#pragma unroll
    for (int j = 0; j < 4; ++j)
      C[(ll)m * 1024 + n0 + (tc << 2) + j] = acc[i][j];
  }
}

__global__ __launch_bounds__(256) void copy_lords_in(
    const float* __restrict__ so, float* __restrict__ lin)
{
  int b = blockIdx.x / SEG_, s = blockIdx.x % SEG_;
  int i = threadIdx.x * 4;
  *(float4*)(lin + ((ll)(b * 17 + 1 + s)) * H_ + i) =
      *(const float4*)(so + ((ll)b * L_ + 1 + (ll)s * T_) * H_ + i);
}

// ---------------- lord attention v2: LDS-staged, wave-parallel ----------------
__global__ __launch_bounds__(256) void lord_attn2(
    const float* __restrict__ lq, const float* __restrict__ lk,
    const float* __restrict__ lv, float* __restrict__ so,
    __hip_bfloat16* __restrict__ sob)
{
  const int b = blockIdx.x, h = blockIdx.y;
  const int tid = threadIdx.x, lane = tid & 63, wid = tid >> 6;
  __shared__ float Qs[17][64], Ks[17][64], Vs[17][64];
  for (int t = tid; t < 17 * 64; t += 256) {
    int r = t >> 6, c = t & 63;
    ll g = ((ll)(b * 17 + r)) * H_ + h * 64 + c;
    Qs[r][c] = lq[g];
    Ks[r][c] = lk[g];
    Vs[r][c] = lv[g];
  }
  __syncthreads();
  for (int q = wid; q < 17; q += 4) {
    float qd = Qs[q][lane];
    float sc[17];
#pragma unroll
    for (int k = 0; k < 17; ++k) {
      float p = qd * Ks[k][lane];
      p += __shfl_xor(p, 1);  p += __shfl_xor(p, 2);  p += __shfl_xor(p, 4);
      p += __shfl_xor(p, 8);  p += __shfl_xor(p, 16); p += __shfl_xor(p, 32);
      sc[k] = p * SCALE;
    }
    float mx = sc[0];
#pragma unroll
    for (int k = 1; k < 17; ++k) mx = fmaxf(mx, sc[k]);
    float l = 0.f;
#pragma unroll
    for (int k = 0; k < 17; ++k) { sc[k] = __expf(sc[k] - mx); l += sc[k]; }
    float invl = 1.f / l;
    float o = 0.f;
#pragma unroll
    for (int k = 0; k < 17; ++k) o = fmaf(sc[k], Vs[k][lane], o);
    o *= invl;
    ll row = (q == 0) ? (ll)b * L_ : ((ll)b * L_ + 1 + (ll)(q - 1) * T_);
    so[row * H_ + h * 64 + lane] = o;
    sob[row * H_ + h * 64 + lane] = __float2bfloat16(o);
  }
}

__global__ __launch_bounds__(256) void ln_inplace(
    float* __restrict__ hbuf, const float* __restrict__ w, const float* __restrict__ bgain)
{
  const ll row = blockIdx.x;
  const int tid = threadIdx.x;
  float4 x = *(float4*)(hbuf + row * H_ + tid * 4);
  float s = x.x + x.y + x.z + x.w;
  float s2 = x.x * x.x + x.y * x.y + x.z * x.z + x.w * x.w;
#pragma unroll
  for (int off = 32; off >= 1; off >>= 1) {
    s  += __shfl_down(s, off, 64);
    s2 += __shfl_down(s2, off, 64);
  }
  __shared__ float red[2][4];
  int wid = tid >> 6;
  if ((tid & 63) == 0) { red[0][wid] = s; red[1][wid] = s2; }
  __syncthreads();
  s  = red[0][0] + red[0][1] + red[0][2] + red[0][3];
  s2 = red[1][0] + red[1][1] + red[1][2] + red[1][3];
  const float mean = s * (1.f / H_);
  float var = s2 * (1.f / H_) - mean * mean;
  var = fmaxf(var, 0.f);
  const float inv = rsqrtf(var + 1e-12f);
  float4 g = *(const float4*)(w + tid * 4);
  float4 bb = *(const float4*)(bgain + tid * 4);
  float4 y;
  y.x = (x.x - mean) * inv * g.x + bb.x;
  y.y = (x.y - mean) * inv * g.y + bb.y;
  y.z = (x.z - mean) * inv * g.z + bb.z;
  y.w = (x.w - mean) * inv * g.w + bb.w;
  *(float4*)(hbuf + row * H_ + tid * 4) = y;
}

extern "C" void kernel_launch(void* const* d_in, const int* in_sizes, int n_in,
                              void* d_out, int out_size, void* d_ws, size_t ws_size,
                              hipStream_t stream)
{
  const float* hidden  = (const float*)d_in[0];
  const float* Blord_w = (const float*)d_in[1];
  const float* Blord_b = (const float*)d_in[2];
  const float* seg_qw  = (const float*)d_in[3];
  const float* seg_kw  = (const float*)d_in[4];
  const float* seg_vw  = (const float*)d_in[5];
  const float* lord_qw = (const float*)d_in[6];
  const float* lord_kw = (const float*)d_in[7];
  const float* lord_vw = (const float*)d_in[8];
  const float* out_w   = (const float*)d_in[9];
  const float* out_b   = (const float*)d_in[10];
  const float* ln_w    = (const float*)d_in[11];
  const float* ln_b    = (const float*)d_in[12];

  float* attn_out = (float*)d_out;                          // output 0 [B,L,H]
  float* self_out = (float*)d_out + (ll)B_ * L_ * H_;       // output 1 [B,L,H]

  const ll QKV = (ll)B_ * SEG_ * T_ * H_;
  const ll SHH = (ll)SEG_ * H_ * H_;
  __hip_bfloat16* qb = (__hip_bfloat16*)attn_out;
  __hip_bfloat16* kb = qb + QKV;
  __hip_bfloat16* hbf = (__hip_bfloat16*)self_out;
  __hip_bfloat16* vb = (__hip_bfloat16*)d_ws;
  __hip_bfloat16* wslot3 = vb + QKV;
  __hip_bfloat16* sob = wslot3;                             // alias (weights dead)
  __hip_bfloat16* outw_bf = wslot3 + 3 * SHH;
  float* lords_in = (float*)(outw_bf + (ll)H_ * H_);
  float* lqw_ = lords_in + 136 * 1024;
  float* lkw_ = lqw_ + 136 * 1024;
  float* lvw_ = lkw_ + 136 * 1024;

  dim3 blk(256);

  // 0. convert hidden + all weights to bf16 (single dispatch)
  f2bf_all<<<dim3(2048), blk, 0, stream>>>(
      hidden, hbf, seg_qw, seg_kw, seg_vw, wslot3, out_w, outw_bf);

  // 1. fused segment QKV projection
  gemm_qkv<<<dim3(24, 17, 16), blk, 0, stream>>>(hbf + H_, wslot3, qb, kb, vb);

  // 2. Blord projection (fp32, M=8)
  gemm_bt<<<dim3(16), blk, 0, stream>>>(
      hidden, (ll)L_ * H_, Blord_w, Blord_b, lords_in, (ll)17 * H_, B_, H_);

  // 3. segment attention (MFMA flash, no-max softmax)
  seg_attn_mfma<<<dim3(3, NH_, B_ * SEG_), blk, 0, stream>>>(qb, kb, vb, self_out, sob);

  // 4. gather lord inputs
  copy_lords_in<<<dim3(B_ * SEG_), blk, 0, stream>>>(self_out, lords_in);

  // 5. lord q/k/v projections
  lord_proj<<<dim3(16, 3, 3), blk, 0, stream>>>(
      lords_in, lord_qw, lord_kw, lord_vw, lqw_, lkw_, lvw_);

  // 6. lord attention
  lord_attn2<<<dim3(B_, NH_), blk, 0, stream>>>(lqw_, lkw_, lvw_, self_out, sob);

  // 7. output dense + bias + residual -> attn_out (overwrites qb/kb)
  gemm_out<<<dim3(8, 258), blk, 0, stream>>>(sob, outw_bf, out_b, attn_out, hidden);

  // 8. LayerNorm in place
  ln_inplace<<<dim3(B_ * L_), blk, 0, stream>>>(attn_out, ln_w, ln_b);
}

// Round 9
// 875.197 us; speedup vs baseline: 8.6527x; 1.0019x over previous
//
#include <hip/hip_runtime.h>
#include <hip/hip_bf16.h>

typedef long long ll;
typedef __attribute__((ext_vector_type(8))) short bf16x8;
typedef __attribute__((ext_vector_type(4))) float fx4;

#define B_ 8
#define SEG_ 16
#define T_ 257
#define H_ 1024
#define NH_ 16
#define L_ 4113
#define SCALE 0.125f

__device__ __forceinline__ unsigned short f2bfu(float x) {
  __hip_bfloat16 h = __float2bfloat16(x);
  return *(unsigned short*)&h;
}

__device__ __forceinline__ void gl_lds16(const void* g, void* l) {
  __builtin_amdgcn_global_load_lds((const __attribute__((address_space(1))) void*)g,
                                   (__attribute__((address_space(3))) void*)l, 16, 0, 0);
}

// ---------------- fused fp32 -> bf16 conversion of all inputs ----------------
#define NU_HID 4211712
#define NU_W   2097152
#define NU_OW  131072
__global__ __launch_bounds__(256) void f2bf_all(
    const float* __restrict__ hid, __hip_bfloat16* __restrict__ hbf,
    const float* __restrict__ wq, const float* __restrict__ wk, const float* __restrict__ wv,
    __hip_bfloat16* __restrict__ w3,
    const float* __restrict__ ow, __hip_bfloat16* __restrict__ owb)
{
  const int NTOT = NU_HID + 3 * NU_W + NU_OW;
  for (int i = blockIdx.x * 256 + threadIdx.x; i < NTOT; i += gridDim.x * 256) {
    const float* src;
    __hip_bfloat16* dst;
    if (i < NU_HID) {
      src = hid + (ll)i * 8;
      dst = hbf + (ll)i * 8;
    } else if (i < NU_HID + 3 * NU_W) {
      int j = i - NU_HID;
      int which = j >> 21;               // NU_W = 2^21
      int off = j & (NU_W - 1);
      const float* ws = (which == 0) ? wq : (which == 1) ? wk : wv;
      src = ws + (ll)off * 8;
      dst = w3 + (ll)j * 8;
    } else {
      int k = i - NU_HID - 3 * NU_W;
      src = ow + (ll)k * 8;
      dst = owb + (ll)k * 8;
    }
    float4 a = ((const float4*)src)[0];
    float4 b = ((const float4*)src)[1];
    union { bf16x8 v; unsigned short u[8]; } o;
    o.u[0] = f2bfu(a.x); o.u[1] = f2bfu(a.y); o.u[2] = f2bfu(a.z); o.u[3] = f2bfu(a.w);
    o.u[4] = f2bfu(b.x); o.u[5] = f2bfu(b.y); o.u[6] = f2bfu(b.z); o.u[7] = f2bfu(b.w);
    *(bf16x8*)dst = o.v;
  }
}

// ---------------- fused QKV GEMM (2-phase __syncthreads dbuf) ----------------
// grid (24,17,16): bx>>3 selects Q/K/V; (bx&7)=n-tile; by=m-tile; bz=segment.
__global__ __launch_bounds__(256) void gemm_qkv(
    const __hip_bfloat16* __restrict__ A,     // hbf + H_
    const __hip_bfloat16* __restrict__ Wall,  // [3][SEG][H][H]
    __hip_bfloat16* __restrict__ Cq,
    __hip_bfloat16* __restrict__ Ck,
    __hip_bfloat16* __restrict__ Cv)
{
  const int nwg = 24 * 17 * 16;
  const int orig = blockIdx.x + 24 * (blockIdx.y + 17 * blockIdx.z);
  const int swz = (orig & 7) * (nwg >> 3) + (orig >> 3);
  const int bx = swz % 24;
  const int t2 = swz / 24;
  const int by = t2 % 17;
  const int bz = t2 / 17;
  const int which = bx >> 3;
  const int n0 = (bx & 7) * 128;
  const int m0 = by * 128;
  const int M = B_ * T_;   // 2056

  const __hip_bfloat16* W = Wall + ((ll)which * SEG_ + bz) * ((ll)H_ * H_);
  __hip_bfloat16* C = (which == 0) ? Cq : (which == 1) ? Ck : Cv;

  __shared__ __hip_bfloat16 At[2][128 * 32];
  __shared__ __hip_bfloat16 Bt[2][128 * 32];

  const int tid = threadIdx.x;
  const int lane = tid & 63;
  const int wid = tid >> 6;
  const int wm = (wid >> 1) * 64;
  const int wn = (wid & 1) * 64;

  const int r0 = tid >> 2;
  const int kc = (tid & 3) * 8;
  const int am0 = min(m0 + r0, M - 1);
  const int am1 = min(m0 + 64 + r0, M - 1);
  // FIX(r7): A row must include the SEGMENT offset bz*T_*H_ (r6/r7 read segment 0
  // for every segment — the 0.25 absmax bug).
  const ll segoff = (ll)bz * ((ll)T_ * H_);
  const ll aoff0 = (ll)(am0 / T_) * ((ll)L_ * H_) + segoff + (ll)(am0 % T_) * H_;
  const ll aoff1 = (ll)(am1 / T_) * ((ll)L_ * H_) + segoff + (ll)(am1 % T_) * H_;
  const ll boff0 = (ll)(n0 + r0) * H_;
  const ll boff1 = (ll)(n0 + 64 + r0) * H_;
  const int stA0 = r0 * 32 + kc;

  fx4 acc[4][4];
#pragma unroll
  for (int i = 0; i < 4; ++i)
#pragma unroll
    for (int j = 0; j < 4; ++j) acc[i][j] = fx4{0.f, 0.f, 0.f, 0.f};

  const int fragA = (wm + (lane & 15)) * 32 + ((lane >> 4) << 3);
  const int fragB = (wn + (lane & 15)) * 32 + ((lane >> 4) << 3);

  gl_lds16(A + aoff0 + kc, (void*)(&At[0][0] + stA0));
  gl_lds16(A + aoff1 + kc, (void*)(&At[0][0] + 2048 + stA0));
  gl_lds16(W + boff0 + kc, (void*)(&Bt[0][0] + stA0));
  gl_lds16(W + boff1 + kc, (void*)(&Bt[0][0] + 2048 + stA0));
  __syncthreads();

  int cur = 0;
  for (int k0 = 0; k0 < 1024; k0 += 32) {
    if (k0 + 32 < 1024) {
      const int kn = k0 + 32;
      const int nxt = cur ^ 1;
      gl_lds16(A + aoff0 + kn + kc, (void*)(&At[nxt][0] + stA0));
      gl_lds16(A + aoff1 + kn + kc, (void*)(&At[nxt][0] + 2048 + stA0));
      gl_lds16(W + boff0 + kn + kc, (void*)(&Bt[nxt][0] + stA0));
      gl_lds16(W + boff1 + kn + kc, (void*)(&Bt[nxt][0] + 2048 + stA0));
    }

    const __hip_bfloat16* ap = &At[cur][0] + fragA;
    const __hip_bfloat16* bp = &Bt[cur][0] + fragB;
    bf16x8 af[4], bfr[4];
#pragma unroll
    for (int f = 0; f < 4; ++f) {
      af[f]  = *(const bf16x8*)(ap + f * 16 * 32);
      bfr[f] = *(const bf16x8*)(bp + f * 16 * 32);
    }
#pragma unroll
    for (int mf = 0; mf < 4; ++mf)
#pragma unroll
      for (int nf = 0; nf < 4; ++nf)
        acc[mf][nf] = __builtin_amdgcn_mfma_f32_16x16x32_bf16(af[mf], bfr[nf], acc[mf][nf], 0, 0, 0);

    __syncthreads();
    cur ^= 1;
  }

  const int cn = n0 + wn + (lane & 15);
#pragma unroll
  for (int mf = 0; mf < 4; ++mf) {
    int mloc = m0 + wm + mf * 16 + ((lane >> 4) << 2);
#pragma unroll
    for (int r = 0; r < 4; ++r) {
      int m = mloc + r;
      if (m >= M) continue;
      ll co = ((ll)(m / T_) * SEG_ + bz) * ((ll)T_ * H_) + (ll)(m % T_) * H_;
#pragma unroll
      for (int nf = 0; nf < 4; ++nf)
        C[co + cn + nf * 16] = __float2bfloat16(acc[mf][nf][r]);
    }
  }
}

// ---------------- output dense GEMM (2-phase dbuf): fp32 + bias + residual ----------------
__global__ __launch_bounds__(256) void gemm_out(
    const __hip_bfloat16* __restrict__ A,   // sob [B*L][H]
    const __hip_bfloat16* __restrict__ W,   // outw_bf [H][H]
    const float* __restrict__ bias,
    float* __restrict__ C,
    const float* __restrict__ res)
{
  const int nwg = 8 * 258;
  const int orig = blockIdx.x + 8 * blockIdx.y;
  const int swz = (orig & 7) * (nwg >> 3) + (orig >> 3);
  const int bx = swz % 8;
  const int by = swz / 8;
  const int M = B_ * L_;   // 32904
  const int m0 = by * 128;
  const int n0 = bx * 128;

  __shared__ __hip_bfloat16 At[2][128 * 32];
  __shared__ __hip_bfloat16 Bt[2][128 * 32];

  const int tid = threadIdx.x;
  const int lane = tid & 63;
  const int wid = tid >> 6;
  const int wm = (wid >> 1) * 64;
  const int wn = (wid & 1) * 64;

  const int r0 = tid >> 2;
  const int kc = (tid & 3) * 8;
  const ll aoff0 = (ll)min(m0 + r0, M - 1) * H_;
  const ll aoff1 = (ll)min(m0 + 64 + r0, M - 1) * H_;
  const ll boff0 = (ll)(n0 + r0) * H_;
  const ll boff1 = (ll)(n0 + 64 + r0) * H_;
  const int stA0 = r0 * 32 + kc;

  fx4 acc[4][4];
#pragma unroll
  for (int i = 0; i < 4; ++i)
#pragma unroll
    for (int j = 0; j < 4; ++j) acc[i][j] = fx4{0.f, 0.f, 0.f, 0.f};

  const int fragA = (wm + (lane & 15)) * 32 + ((lane >> 4) << 3);
  const int fragB = (wn + (lane & 15)) * 32 + ((lane >> 4) << 3);

  gl_lds16(A + aoff0 + kc, (void*)(&At[0][0] + stA0));
  gl_lds16(A + aoff1 + kc, (void*)(&At[0][0] + 2048 + stA0));
  gl_lds16(W + boff0 + kc, (void*)(&Bt[0][0] + stA0));
  gl_lds16(W + boff1 + kc, (void*)(&Bt[0][0] + 2048 + stA0));
  __syncthreads();

  int cur = 0;
  for (int k0 = 0; k0 < 1024; k0 += 32) {
    if (k0 + 32 < 1024) {
      const int kn = k0 + 32;
      const int nxt = cur ^ 1;
      gl_lds16(A + aoff0 + kn + kc, (void*)(&At[nxt][0] + stA0));
      gl_lds16(A + aoff1 + kn + kc, (void*)(&At[nxt][0] + 2048 + stA0));
      gl_lds16(W + boff0 + kn + kc, (void*)(&Bt[nxt][0] + stA0));
      gl_lds16(W + boff1 + kn + kc, (void*)(&Bt[nxt][0] + 2048 + stA0));
    }

    const __hip_bfloat16* ap = &At[cur][0] + fragA;
    const __hip_bfloat16* bp = &Bt[cur][0] + fragB;
    bf16x8 af[4], bfr[4];
#pragma unroll
    for (int f = 0; f < 4; ++f) {
      af[f]  = *(const bf16x8*)(ap + f * 16 * 32);
      bfr[f] = *(const bf16x8*)(bp + f * 16 * 32);
    }
#pragma unroll
    for (int mf = 0; mf < 4; ++mf)
#pragma unroll
      for (int nf = 0; nf < 4; ++nf)
        acc[mf][nf] = __builtin_amdgcn_mfma_f32_16x16x32_bf16(af[mf], bfr[nf], acc[mf][nf], 0, 0, 0);

    __syncthreads();
    cur ^= 1;
  }

  const int cn = n0 + wn + (lane & 15);
#pragma unroll
  for (int mf = 0; mf < 4; ++mf) {
    int mloc = m0 + wm + mf * 16 + ((lane >> 4) << 2);
#pragma unroll
    for (int r = 0; r < 4; ++r) {
      int m = mloc + r;
      if (m >= M) continue;
#pragma unroll
      for (int nf = 0; nf < 4; ++nf) {
        int n = cn + nf * 16;
        C[(ll)m * H_ + n] = acc[mf][nf][r] + bias[n] + res[(ll)m * H_ + n];
      }
    }
  }
}

// ---------------- MFMA flash attention over one segment (no-max softmax) ----------------
__global__ __launch_bounds__(256) void seg_attn_mfma(
    const __hip_bfloat16* __restrict__ Qb,
    const __hip_bfloat16* __restrict__ Kb,
    const __hip_bfloat16* __restrict__ Vb,
    float* __restrict__ so, __hip_bfloat16* __restrict__ sob)
{
  __shared__ __align__(16) char smem[8192 + 9216 + 4 * 4096];
  char* KsB = smem;
  char* VTB = smem + 8192;
  const int tid = threadIdx.x, lane = tid & 63, wid = tid >> 6;
  char* PB = smem + 8192 + 9216 + wid * 4096;

  const int h = blockIdx.y, bs = blockIdx.z;
  const int b = bs >> 4, s = bs & 15;
  const int q0 = blockIdx.x * 128 + wid * 32;
  const bool qvalid = (q0 <= 256);
  const ll base = (ll)bs * (T_ * H_) + h * 64;

  bf16x8 qf[2][2];
#pragma unroll
  for (int mf = 0; mf < 2; ++mf) {
    int qr = q0 + mf * 16 + (lane & 15); if (qr > 256) qr = 256;
#pragma unroll
    for (int ks = 0; ks < 2; ++ks)
      qf[mf][ks] = *(const bf16x8*)(Qb + base + (ll)qr * H_ + ks * 32 + ((lane >> 4) << 3));
  }

  float l_[2][4];
  fx4 of[2][4];
#pragma unroll
  for (int mf = 0; mf < 2; ++mf) {
#pragma unroll
    for (int r = 0; r < 4; ++r) l_[mf][r] = 0.f;
#pragma unroll
    for (int df = 0; df < 4; ++df) of[mf][df] = fx4{0.f, 0.f, 0.f, 0.f};
  }

  const int krow = tid >> 3;
  const int kc8 = tid & 7;
  const int kkp = tid & 31;
  const int vd0 = (tid >> 5) * 8;

  for (int t = 0; t < 5; ++t) {
    const int k0 = t * 64;
    __syncthreads();
    {
      int row = krow;
      int kr = k0 + row; if (kr > 256) kr = 256;
      gl_lds16(Kb + base + (ll)kr * H_ + ((kc8 ^ (row & 7)) << 3), KsB + tid * 16);
      row = krow + 32;
      kr = k0 + row; if (kr > 256) kr = 256;
      gl_lds16(Kb + base + (ll)kr * H_ + ((kc8 ^ (row & 7)) << 3), KsB + 4096 + tid * 16);
    }
    {
      int kk = kkp * 2;
      int kr0 = k0 + kk;     if (kr0 > 256) kr0 = 256;
      int kr1 = k0 + kk + 1; if (kr1 > 256) kr1 = 256;
      bf16x8 v0 = *(const bf16x8*)(Vb + base + (ll)kr0 * H_ + vd0);
      bf16x8 v1 = *(const bf16x8*)(Vb + base + (ll)kr1 * H_ + vd0);
      unsigned int* vtu = (unsigned int*)VTB;
#pragma unroll
      for (int j = 0; j < 8; ++j)
        vtu[(vd0 + j) * 36 + kkp] =
            (unsigned int)(unsigned short)v0[j] | ((unsigned int)(unsigned short)v1[j] << 16);
    }
    __syncthreads();

    if (qvalid) {
      fx4 sa[2][4];
#pragma unroll
      for (int mf = 0; mf < 2; ++mf)
#pragma unroll
        for (int nf = 0; nf < 4; ++nf) sa[mf][nf] = fx4{0.f, 0.f, 0.f, 0.f};
#pragma unroll
      for (int nf = 0; nf < 4; ++nf) {
        int key = nf * 16 + (lane & 15);
#pragma unroll
        for (int ks = 0; ks < 2; ++ks) {
          int c16 = ks * 4 + (lane >> 4);
          bf16x8 kf = *(const bf16x8*)(KsB + key * 128 + ((c16 ^ (key & 7)) << 4));
          sa[0][nf] = __builtin_amdgcn_mfma_f32_16x16x32_bf16(qf[0][ks], kf, sa[0][nf], 0, 0, 0);
          sa[1][nf] = __builtin_amdgcn_mfma_f32_16x16x32_bf16(qf[1][ks], kf, sa[1][nf], 0, 0, 0);
        }
      }
#pragma unroll
      for (int nf = 0; nf < 4; ++nf) {
        bool bad = (k0 + nf * 16 + (lane & 15)) > 256;
#pragma unroll
        for (int mf = 0; mf < 2; ++mf) {
#pragma unroll
          for (int r = 0; r < 4; ++r) {
            float p = bad ? 0.f : __expf(sa[mf][nf][r] * SCALE);
            sa[mf][nf][r] = p;
            l_[mf][r] += p;
          }
        }
      }
#pragma unroll
      for (int mf = 0; mf < 2; ++mf)
#pragma unroll
        for (int nf = 0; nf < 4; ++nf)
#pragma unroll
          for (int rp = 0; rp < 2; ++rp) {
            float v0 = sa[mf][nf][rp];
            float v2 = sa[mf][nf][rp + 2];
            float o0 = __shfl_xor(v0, 1);
            float o2 = __shfl_xor(v2, 1);
            const bool odd = (lane & 1);
            float lo = odd ? o2 : v0;
            float hi = odd ? v2 : o0;
            unsigned int pk = (unsigned int)f2bfu(lo) | ((unsigned int)f2bfu(hi) << 16);
            int row = mf * 16 + ((lane >> 4) << 2) + (odd ? rp + 2 : rp);
            int col2 = nf * 16 + (lane & 14);
            *(unsigned int*)(PB + row * 128 + ((col2 * 2) ^ ((row & 7) << 4))) = pk;
          }
#pragma unroll
      for (int kks = 0; kks < 2; ++kks) {
        bf16x8 pa[2];
#pragma unroll
        for (int mf = 0; mf < 2; ++mf) {
          int prow = mf * 16 + (lane & 15);
          int c16 = kks * 4 + (lane >> 4);
          pa[mf] = *(const bf16x8*)(PB + prow * 128 + ((c16 ^ (prow & 7)) << 4));
        }
#pragma unroll
        for (int df = 0; df < 4; ++df) {
          bf16x8 vf = *(const bf16x8*)(VTB + (df * 16 + (lane & 15)) * 144 + kks * 64 + ((lane >> 4) << 4));
          of[0][df] = __builtin_amdgcn_mfma_f32_16x16x32_bf16(pa[0], vf, of[0][df], 0, 0, 0);
          of[1][df] = __builtin_amdgcn_mfma_f32_16x16x32_bf16(pa[1], vf, of[1][df], 0, 0, 0);
        }
      }
    }
  }

  if (qvalid) {
#pragma unroll
    for (int mf = 0; mf < 2; ++mf)
#pragma unroll
      for (int r = 0; r < 4; ++r) {
        float rs = l_[mf][r];
        rs += __shfl_xor(rs, 1);
        rs += __shfl_xor(rs, 2);
        rs += __shfl_xor(rs, 4);
        rs += __shfl_xor(rs, 8);
        l_[mf][r] = rs;
      }
#pragma unroll
    for (int mf = 0; mf < 2; ++mf)
#pragma unroll
      for (int r = 0; r < 4; ++r) {
        int q = q0 + mf * 16 + ((lane >> 4) << 2) + r;
        if (q > 256) continue;
        float inv = 1.f / l_[mf][r];
        ll rowoff = ((ll)b * L_ + 1 + (ll)s * T_ + q) * H_ + h * 64;
#pragma unroll
        for (int df = 0; df < 4; ++df) {
          int d = df * 16 + (lane & 15);
          float v = of[mf][df][r] * inv;
          so[rowoff + d] = v;
          sob[rowoff + d] = __float2bfloat16(v);
        }
      }
  }
}

// ---------------- small fp32 VALU GEMM (Blord path, M=8) ----------------
__global__ __launch_bounds__(256) void gemm_bt(
    const float* __restrict__ X, ll xbs,
    const float* __restrict__ W,
    const float* __restrict__ bias,
    float* __restrict__ C, ll cbs,
    int M, int K)
{
  const int tid = threadIdx.x;
  const int n0 = blockIdx.x * 64;

  __shared__ float Xt[16][68];
  __shared__ float Wt[16][68];

  const int lr = tid >> 2;
  const int lc = (tid & 3) << 2;
  const int mload = min(lr, M - 1);
  const ll xoff = (ll)mload * xbs;
  const ll woff = (ll)(n0 + lr) * K;

  const int tr = tid >> 4;
  const int tc = tid & 15;

  float acc[4][4];
#pragma unroll
  for (int i = 0; i < 4; ++i)
#pragma unroll
    for (int j = 0; j < 4; ++j) acc[i][j] = 0.f;

  for (int k0 = 0; k0 < K; k0 += 16) {
    float4 xv = *(const float4*)(X + xoff + k0 + lc);
    float4 wv = *(const float4*)(W + woff + k0 + lc);
    __syncthreads();
    Xt[lc + 0][lr] = xv.x; Xt[lc + 1][lr] = xv.y; Xt[lc + 2][lr] = xv.z; Xt[lc + 3][lr] = xv.w;
    Wt[lc + 0][lr] = wv.x; Wt[lc + 1][lr] = wv.y; Wt[lc + 2][lr] = wv.z; Wt[lc + 3][lr] = wv.w;
    __syncthreads();
#pragma unroll
    for (int kk = 0; kk < 16; ++kk) {
      float4 xa = *(const float4*)&Xt[kk][tr << 2];
      float4 wb = *(const float4*)&Wt[kk][tc << 2];
      float xa_[4] = {xa.x, xa.y, xa.z, xa.w};
      float wb_[4] = {wb.x, wb.y, wb.z, wb.w};
#pragma unroll
      for (int i = 0; i < 4; ++i)
#pragma unroll
        for (int j = 0; j < 4; ++j)
          acc[i][j] = fmaf(xa_[i], wb_[j], acc[i][j]);
    }
  }

#pragma unroll
  for (int i = 0; i < 4; ++i) {
    int m = (tr << 2) + i;
    if (m >= M) continue;
#pragma unroll
    for (int j = 0; j < 4; ++j) {
      int n = n0 + (tc << 2) + j;
      C[(ll)m * cbs + n] = acc[i][j] + (bias ? bias[n] : 0.f);
    }
  }
}

// ---------------- batched lord q/k/v projections (M=136, fp32) ----------------
__global__ __launch_bounds__(256) void lord_proj(
    const float* __restrict__ X,
    const float* __restrict__ Wq, const float* __restrict__ Wk, const float* __restrict__ Wv,
    float* __restrict__ Cq, float* __restrict__ Ck, float* __restrict__ Cv)
{
  const float* W = (blockIdx.z == 0) ? Wq : (blockIdx.z == 1) ? Wk : Wv;
  float* C = (blockIdx.z == 0) ? Cq : (blockIdx.z == 1) ? Ck : Cv;
  const int M = 136, K = 1024;

  const int tid = threadIdx.x;
  const int m0 = blockIdx.y * 64;
  const int n0 = blockIdx.x * 64;

  __shared__ float Xt[16][68];
  __shared__ float Wt[16][68];

  const int lr = tid >> 2;
  const int lc = (tid & 3) << 2;
  const int mload = min(m0 + lr, M - 1);
  const ll xoff = (ll)mload * K;
  const ll woff = (ll)(n0 + lr) * K;

  const int tr = tid >> 4;
  const int tc = tid & 15;

  float acc[4][4];
#pragma unroll
  for (int i = 0; i < 4; ++i)
#pragma unroll
    for (int j = 0; j < 4; ++j) acc[i][j] = 0.f;

  for (int k0 = 0; k0 < K; k0 += 16) {
    float4 xv = *(const float4*)(X + xoff + k0 + lc);
    float4 wv = *(const float4*)(W + woff + k0 + lc);
    __syncthreads();
    Xt[lc + 0][lr] = xv.x; Xt[lc + 1][lr] = xv.y; Xt[lc + 2][lr] = xv.z; Xt[lc + 3][lr] = xv.w;
    Wt[lc + 0][lr] = wv.x; Wt[lc + 1][lr] = wv.y; Wt[lc + 2][lr] = wv.z; Wt[lc + 3][lr] = wv.w;
    __syncthreads();
#pragma unroll
    for (int kk = 0; kk < 16; ++kk) {
      float4 xa = *(const float4*)&Xt[kk][tr << 2];
      float4 wb = *(const float4*)&Wt[kk][tc << 2];
      float xa_[4] = {xa.x, xa.y, xa.z, xa.w};
      float wb_[4] = {wb.x, wb.y, wb.z, wb.w};
#pragma unroll
      for (int i = 0; i < 4; ++i)
#pragma unroll
        for (int j = 0; j < 4; ++j)
          acc[i][j] = fmaf(xa_[i], wb_[j], acc[i][j]);
    }
  }

#pragma unroll
  for (int i = 0; i < 4; ++i) {
    int m = m0 + (tr << 2) + i;
    if (m >= M) continue;
#pragma unroll
    for (int j = 0; j < 4; ++j)
      C[(ll)m * 1024 + n0 + (tc << 2) + j] = acc[i][j];
  }
}

__global__ __launch_bounds__(256) void copy_lords_in(
    const float* __restrict__ so, float* __restrict__ lin)
{
  int b = blockIdx.x / SEG_, s = blockIdx.x % SEG_;
  int i = threadIdx.x * 4;
  *(float4*)(lin + ((ll)(b * 17 + 1 + s)) * H_ + i) =
      *(const float4*)(so + ((ll)b * L_ + 1 + (ll)s * T_) * H_ + i);
}

// ---------------- lord attention v2: LDS-staged, wave-parallel ----------------
__global__ __launch_bounds__(256) void lord_attn2(
    const float* __restrict__ lq, const float* __restrict__ lk,
    const float* __restrict__ lv, float* __restrict__ so,
    __hip_bfloat16* __restrict__ sob)
{
  const int b = blockIdx.x, h = blockIdx.y;
  const int tid = threadIdx.x, lane = tid & 63, wid = tid >> 6;
  __shared__ float Qs[17][64], Ks[17][64], Vs[17][64];
  for (int t = tid; t < 17 * 64; t += 256) {
    int r = t >> 6, c = t & 63;
    ll g = ((ll)(b * 17 + r)) * H_ + h * 64 + c;
    Qs[r][c] = lq[g];
    Ks[r][c] = lk[g];
    Vs[r][c] = lv[g];
  }
  __syncthreads();
  for (int q = wid; q < 17; q += 4) {
    float qd = Qs[q][lane];
    float sc[17];
#pragma unroll
    for (int k = 0; k < 17; ++k) {
      float p = qd * Ks[k][lane];
      p += __shfl_xor(p, 1);  p += __shfl_xor(p, 2);  p += __shfl_xor(p, 4);
      p += __shfl_xor(p, 8);  p += __shfl_xor(p, 16); p += __shfl_xor(p, 32);
      sc[k] = p * SCALE;
    }
    float mx = sc[0];
#pragma unroll
    for (int k = 1; k < 17; ++k) mx = fmaxf(mx, sc[k]);
    float l = 0.f;
#pragma unroll
    for (int k = 0; k < 17; ++k) { sc[k] = __expf(sc[k] - mx); l += sc[k]; }
    float invl = 1.f / l;
    float o = 0.f;
#pragma unroll
    for (int k = 0; k < 17; ++k) o = fmaf(sc[k], Vs[k][lane], o);
    o *= invl;
    ll row = (q == 0) ? (ll)b * L_ : ((ll)b * L_ + 1 + (ll)(q - 1) * T_);
    so[row * H_ + h * 64 + lane] = o;
    sob[row * H_ + h * 64 + lane] = __float2bfloat16(o);
  }
}

__global__ __launch_bounds__(256) void ln_inplace(
    float* __restrict__ hbuf, const float* __restrict__ w, const float* __restrict__ bgain)
{
  const ll row = blockIdx.x;
  const int tid = threadIdx.x;
  float4 x = *(float4*)(hbuf + row * H_ + tid * 4);
  float s = x.x + x.y + x.z + x.w;
  float s2 = x.x * x.x + x.y * x.y + x.z * x.z + x.w * x.w;
#pragma unroll
  for (int off = 32; off >= 1; off >>= 1) {
    s  += __shfl_down(s, off, 64);
    s2 += __shfl_down(s2, off, 64);
  }
  __shared__ float red[2][4];
  int wid = tid >> 6;
  if ((tid & 63) == 0) { red[0][wid] = s; red[1][wid] = s2; }
  __syncthreads();
  s  = red[0][0] + red[0][1] + red[0][2] + red[0][3];
  s2 = red[1][0] + red[1][1] + red[1][2] + red[1][3];
  const float mean = s * (1.f / H_);
  float var = s2 * (1.f / H_) - mean * mean;
  var = fmaxf(var, 0.f);
  const float inv = rsqrtf(var + 1e-12f);
  float4 g = *(const float4*)(w + tid * 4);
  float4 bb = *(const float4*)(bgain + tid * 4);
  float4 y;
  y.x = (x.x - mean) * inv * g.x + bb.x;
  y.y = (x.y - mean) * inv * g.y + bb.y;
  y.z = (x.z - mean) * inv * g.z + bb.z;
  y.w = (x.w - mean) * inv * g.w + bb.w;
  *(float4*)(hbuf + row * H_ + tid * 4) = y;
}

extern "C" void kernel_launch(void* const* d_in, const int* in_sizes, int n_in,
                              void* d_out, int out_size, void* d_ws, size_t ws_size,
                              hipStream_t stream)
{
  const float* hidden  = (const float*)d_in[0];
  const float* Blord_w = (const float*)d_in[1];
  const float* Blord_b = (const float*)d_in[2];
  const float* seg_qw  = (const float*)d_in[3];
  const float* seg_kw  = (const float*)d_in[4];
  const float* seg_vw  = (const float*)d_in[5];
  const float* lord_qw = (const float*)d_in[6];
  const float* lord_kw = (const float*)d_in[7];
  const float* lord_vw = (const float*)d_in[8];
  const float* out_w   = (const float*)d_in[9];
  const float* out_b   = (const float*)d_in[10];
  const float* ln_w    = (const float*)d_in[11];
  const float* ln_b    = (const float*)d_in[12];

  float* attn_out = (float*)d_out;                          // output 0 [B,L,H]
  float* self_out = (float*)d_out + (ll)B_ * L_ * H_;       // output 1 [B,L,H]

  const ll QKV = (ll)B_ * SEG_ * T_ * H_;
  const ll SHH = (ll)SEG_ * H_ * H_;
  __hip_bfloat16* qb = (__hip_bfloat16*)attn_out;
  __hip_bfloat16* kb = qb + QKV;
  __hip_bfloat16* hbf = (__hip_bfloat16*)self_out;
  __hip_bfloat16* vb = (__hip_bfloat16*)d_ws;
  __hip_bfloat16* wslot3 = vb + QKV;
  __hip_bfloat16* sob = wslot3;                             // alias (weights dead)
  __hip_bfloat16* outw_bf = wslot3 + 3 * SHH;
  float* lords_in = (float*)(outw_bf + (ll)H_ * H_);
  float* lqw_ = lords_in + 136 * 1024;
  float* lkw_ = lqw_ + 136 * 1024;
  float* lvw_ = lkw_ + 136 * 1024;

  dim3 blk(256);

  // 0. convert hidden + all weights to bf16 (single dispatch)
  f2bf_all<<<dim3(2048), blk, 0, stream>>>(
      hidden, hbf, seg_qw, seg_kw, seg_vw, wslot3, out_w, outw_bf);

  // 1. fused segment QKV projection
  gemm_qkv<<<dim3(24, 17, 16), blk, 0, stream>>>(hbf + H_, wslot3, qb, kb, vb);

  // 2. Blord projection (fp32, M=8)
  gemm_bt<<<dim3(16), blk, 0, stream>>>(
      hidden, (ll)L_ * H_, Blord_w, Blord_b, lords_in, (ll)17 * H_, B_, H_);

  // 3. segment attention (MFMA flash, no-max softmax)
  seg_attn_mfma<<<dim3(3, NH_, B_ * SEG_), blk, 0, stream>>>(qb, kb, vb, self_out, sob);

  // 4. gather lord inputs
  copy_lords_in<<<dim3(B_ * SEG_), blk, 0, stream>>>(self_out, lords_in);

  // 5. lord q/k/v projections
  lord_proj<<<dim3(16, 3, 3), blk, 0, stream>>>(
      lords_in, lord_qw, lord_kw, lord_vw, lqw_, lkw_, lvw_);

  // 6. lord attention
  lord_attn2<<<dim3(B_, NH_), blk, 0, stream>>>(lqw_, lkw_, lvw_, self_out, sob);

  // 7. output dense + bias + residual -> attn_out (overwrites qb/kb)
  gemm_out<<<dim3(8, 258), blk, 0, stream>>>(sob, outw_bf, out_b, attn_out, hidden);

  // 8. LayerNorm in place
  ln_inplace<<<dim3(B_ * L_), blk, 0, stream>>>(attn_out, ln_w, ln_b);
}

// Round 10
// 851.063 us; speedup vs baseline: 8.8981x; 1.0284x over previous
//
#include <hip/hip_runtime.h>
#include <hip/hip_bf16.h>

typedef long long ll;
typedef __attribute__((ext_vector_type(8))) short bf16x8;
typedef __attribute__((ext_vector_type(4))) float fx4;

#define B_ 8
#define SEG_ 16
#define T_ 257
#define H_ 1024
#define NH_ 16
#define L_ 4113
#define SCALE 0.125f

__device__ __forceinline__ unsigned short f2bfu(float x) {
  __hip_bfloat16 h = __float2bfloat16(x);
  return *(unsigned short*)&h;
}

__device__ __forceinline__ void gl_lds16(const void* g, void* l) {
  __builtin_amdgcn_global_load_lds((const __attribute__((address_space(1))) void*)g,
                                   (__attribute__((address_space(3))) void*)l, 16, 0, 0);
}

// ---------------- fused fp32 -> bf16 conversion of all inputs ----------------
#define NU_HID 4211712
#define NU_W   2097152
#define NU_OW  131072
__global__ __launch_bounds__(256) void f2bf_all(
    const float* __restrict__ hid, __hip_bfloat16* __restrict__ hbf,
    const float* __restrict__ wq, const float* __restrict__ wk, const float* __restrict__ wv,
    __hip_bfloat16* __restrict__ w3,
    const float* __restrict__ ow, __hip_bfloat16* __restrict__ owb)
{
  const int NTOT = NU_HID + 3 * NU_W + NU_OW;
  for (int i = blockIdx.x * 256 + threadIdx.x; i < NTOT; i += gridDim.x * 256) {
    const float* src;
    __hip_bfloat16* dst;
    if (i < NU_HID) {
      src = hid + (ll)i * 8;
      dst = hbf + (ll)i * 8;
    } else if (i < NU_HID + 3 * NU_W) {
      int j = i - NU_HID;
      int which = j >> 21;
      int off = j & (NU_W - 1);
      const float* ws = (which == 0) ? wq : (which == 1) ? wk : wv;
      src = ws + (ll)off * 8;
      dst = w3 + (ll)j * 8;
    } else {
      int k = i - NU_HID - 3 * NU_W;
      src = ow + (ll)k * 8;
      dst = owb + (ll)k * 8;
    }
    float4 a = ((const float4*)src)[0];
    float4 b = ((const float4*)src)[1];
    union { bf16x8 v; unsigned short u[8]; } o;
    o.u[0] = f2bfu(a.x); o.u[1] = f2bfu(a.y); o.u[2] = f2bfu(a.z); o.u[3] = f2bfu(a.w);
    o.u[4] = f2bfu(b.x); o.u[5] = f2bfu(b.y); o.u[6] = f2bfu(b.z); o.u[7] = f2bfu(b.w);
    *(bf16x8*)dst = o.v;
  }
}

// ---------------- fused QKV GEMM: counted-vmcnt 2-deep pipeline + LDS slot swizzle ----
// grid (24,17,16): bx>>3 selects Q/K/V; (bx&7)=n-tile; by=m-tile; bz=segment.
// Swizzle (rule #21): LDS dest linear (tid*16B); GLOBAL source column XORed by
// (row>>1)&3; fragment reads apply the same XOR. Conflicts 8-way -> ~2-way.
__global__ __launch_bounds__(256) void gemm_qkv(
    const __hip_bfloat16* __restrict__ A,     // hbf + H_
    const __hip_bfloat16* __restrict__ Wall,  // [3][SEG][H][H]
    __hip_bfloat16* __restrict__ Cq,
    __hip_bfloat16* __restrict__ Ck,
    __hip_bfloat16* __restrict__ Cv)
{
  const int nwg = 24 * 17 * 16;
  const int orig = blockIdx.x + 24 * (blockIdx.y + 17 * blockIdx.z);
  const int swz = (orig & 7) * (nwg >> 3) + (orig >> 3);
  const int bx = swz % 24;
  const int t2 = swz / 24;
  const int by = t2 % 17;
  const int bz = t2 / 17;
  const int which = bx >> 3;
  const int n0 = (bx & 7) * 128;
  const int m0 = by * 128;
  const int M = B_ * T_;   // 2056

  const __hip_bfloat16* W = Wall + ((ll)which * SEG_ + bz) * ((ll)H_ * H_);
  __hip_bfloat16* C = (which == 0) ? Cq : (which == 1) ? Ck : Cv;

  __shared__ __hip_bfloat16 At[3][128 * 32];
  __shared__ __hip_bfloat16 Bt[3][128 * 32];

  const int tid = threadIdx.x;
  const int lane = tid & 63;
  const int wid = tid >> 6;
  const int wm = (wid >> 1) * 64;
  const int wn = (wid & 1) * 64;

  const int r0 = tid >> 2;
  const int p = tid & 3;
  const int kc  = p * 8;                          // linear LDS slot (dest)
  const int kcs = (p ^ ((r0 >> 1) & 3)) * 8;      // pre-swizzled global source col
  const int am0 = min(m0 + r0, M - 1);
  const int am1 = min(m0 + 64 + r0, M - 1);
  // segment offset on A (r8 fix)
  const ll segoff = (ll)bz * ((ll)T_ * H_);
  const ll aoff0 = (ll)(am0 / T_) * ((ll)L_ * H_) + segoff + (ll)(am0 % T_) * H_;
  const ll aoff1 = (ll)(am1 / T_) * ((ll)L_ * H_) + segoff + (ll)(am1 % T_) * H_;
  const ll boff0 = (ll)(n0 + r0) * H_;
  const ll boff1 = (ll)(n0 + 64 + r0) * H_;
  const int stA0 = r0 * 32 + kc;

  fx4 acc[4][4];
#pragma unroll
  for (int i = 0; i < 4; ++i)
#pragma unroll
    for (int j = 0; j < 4; ++j) acc[i][j] = fx4{0.f, 0.f, 0.f, 0.f};

  // fragment read offsets with matching swizzle (f*16 row steps preserve (row>>1)&3)
  const int sw = ((lane & 15) >> 1) & 3;
  const int fragA = (wm + (lane & 15)) * 32 + (((lane >> 4) ^ sw) << 3);
  const int fragB = (wn + (lane & 15)) * 32 + (((lane >> 4) ^ sw) << 3);

#define STAGE_QKV(buf, kt) do { const int kk = (kt) * 32; \
    gl_lds16(A + aoff0 + kk + kcs, (void*)(&At[buf][0] + stA0)); \
    gl_lds16(A + aoff1 + kk + kcs, (void*)(&At[buf][0] + 2048 + stA0)); \
    gl_lds16(W + boff0 + kk + kcs, (void*)(&Bt[buf][0] + stA0)); \
    gl_lds16(W + boff1 + kk + kcs, (void*)(&Bt[buf][0] + 2048 + stA0)); } while (0)

  STAGE_QKV(0, 0);
  STAGE_QKV(1, 1);
  for (int t = 0; t < 32; ++t) {
    __builtin_amdgcn_s_barrier();            // all waves done reading buf[(t+2)%3]
    asm volatile("" ::: "memory");
    if (t + 2 < 32) { const int b3 = (t + 2) % 3; STAGE_QKV(b3, t + 2); }
    if (t < 30)       asm volatile("s_waitcnt vmcnt(8)" ::: "memory");
    else if (t == 30) asm volatile("s_waitcnt vmcnt(4)" ::: "memory");
    else              asm volatile("s_waitcnt vmcnt(0)" ::: "memory");
    __builtin_amdgcn_s_barrier();            // stage t visible to all waves
    asm volatile("" ::: "memory");

    const int cb = t % 3;
    const __hip_bfloat16* ap = &At[cb][0] + fragA;
    const __hip_bfloat16* bp = &Bt[cb][0] + fragB;
    bf16x8 af[4], bfr[4];
#pragma unroll
    for (int f = 0; f < 4; ++f) {
      af[f]  = *(const bf16x8*)(ap + f * 16 * 32);
      bfr[f] = *(const bf16x8*)(bp + f * 16 * 32);
    }
#pragma unroll
    for (int mf = 0; mf < 4; ++mf)
#pragma unroll
      for (int nf = 0; nf < 4; ++nf)
        acc[mf][nf] = __builtin_amdgcn_mfma_f32_16x16x32_bf16(af[mf], bfr[nf], acc[mf][nf], 0, 0, 0);
  }
#undef STAGE_QKV

  const int cn = n0 + wn + (lane & 15);
#pragma unroll
  for (int mf = 0; mf < 4; ++mf) {
    int mloc = m0 + wm + mf * 16 + ((lane >> 4) << 2);
#pragma unroll
    for (int r = 0; r < 4; ++r) {
      int m = mloc + r;
      if (m >= M) continue;
      ll co = ((ll)(m / T_) * SEG_ + bz) * ((ll)T_ * H_) + (ll)(m % T_) * H_;
#pragma unroll
      for (int nf = 0; nf < 4; ++nf)
        C[co + cn + nf * 16] = __float2bfloat16(acc[mf][nf][r]);
    }
  }
}

// ---------------- output dense GEMM: same pipeline + swizzle; fp32 + bias + residual ----
__global__ __launch_bounds__(256) void gemm_out(
    const __hip_bfloat16* __restrict__ A,   // sob [B*L][H]
    const __hip_bfloat16* __restrict__ W,   // outw_bf [H][H]
    const float* __restrict__ bias,
    float* __restrict__ C,
    const float* __restrict__ res)
{
  const int nwg = 8 * 258;
  const int orig = blockIdx.x + 8 * blockIdx.y;
  const int swz = (orig & 7) * (nwg >> 3) + (orig >> 3);
  const int bx = swz % 8;
  const int by = swz / 8;
  const int M = B_ * L_;   // 32904
  const int m0 = by * 128;
  const int n0 = bx * 128;

  __shared__ __hip_bfloat16 At[3][128 * 32];
  __shared__ __hip_bfloat16 Bt[3][128 * 32];

  const int tid = threadIdx.x;
  const int lane = tid & 63;
  const int wid = tid >> 6;
  const int wm = (wid >> 1) * 64;
  const int wn = (wid & 1) * 64;

  const int r0 = tid >> 2;
  const int p = tid & 3;
  const int kc  = p * 8;
  const int kcs = (p ^ ((r0 >> 1) & 3)) * 8;
  const ll aoff0 = (ll)min(m0 + r0, M - 1) * H_;
  const ll aoff1 = (ll)min(m0 + 64 + r0, M - 1) * H_;
  const ll boff0 = (ll)(n0 + r0) * H_;
  const ll boff1 = (ll)(n0 + 64 + r0) * H_;
  const int stA0 = r0 * 32 + kc;

  fx4 acc[4][4];
#pragma unroll
  for (int i = 0; i < 4; ++i)
#pragma unroll
    for (int j = 0; j < 4; ++j) acc[i][j] = fx4{0.f, 0.f, 0.f, 0.f};

  const int sw = ((lane & 15) >> 1) & 3;
  const int fragA = (wm + (lane & 15)) * 32 + (((lane >> 4) ^ sw) << 3);
  const int fragB = (wn + (lane & 15)) * 32 + (((lane >> 4) ^ sw) << 3);

#define STAGE_O(buf, kt) do { const int kk = (kt) * 32; \
    gl_lds16(A + aoff0 + kk + kcs, (void*)(&At[buf][0] + stA0)); \
    gl_lds16(A + aoff1 + kk + kcs, (void*)(&At[buf][0] + 2048 + stA0)); \
    gl_lds16(W + boff0 + kk + kcs, (void*)(&Bt[buf][0] + stA0)); \
    gl_lds16(W + boff1 + kk + kcs, (void*)(&Bt[buf][0] + 2048 + stA0)); } while (0)

  STAGE_O(0, 0);
  STAGE_O(1, 1);
  for (int t = 0; t < 32; ++t) {
    __builtin_amdgcn_s_barrier();
    asm volatile("" ::: "memory");
    if (t + 2 < 32) { const int b3 = (t + 2) % 3; STAGE_O(b3, t + 2); }
    if (t < 30)       asm volatile("s_waitcnt vmcnt(8)" ::: "memory");
    else if (t == 30) asm volatile("s_waitcnt vmcnt(4)" ::: "memory");
    else              asm volatile("s_waitcnt vmcnt(0)" ::: "memory");
    __builtin_amdgcn_s_barrier();
    asm volatile("" ::: "memory");

    const int cb = t % 3;
    const __hip_bfloat16* ap = &At[cb][0] + fragA;
    const __hip_bfloat16* bp = &Bt[cb][0] + fragB;
    bf16x8 af[4], bfr[4];
#pragma unroll
    for (int f = 0; f < 4; ++f) {
      af[f]  = *(const bf16x8*)(ap + f * 16 * 32);
      bfr[f] = *(const bf16x8*)(bp + f * 16 * 32);
    }
#pragma unroll
    for (int mf = 0; mf < 4; ++mf)
#pragma unroll
      for (int nf = 0; nf < 4; ++nf)
        acc[mf][nf] = __builtin_amdgcn_mfma_f32_16x16x32_bf16(af[mf], bfr[nf], acc[mf][nf], 0, 0, 0);
  }
#undef STAGE_O

  const int cn = n0 + wn + (lane & 15);
#pragma unroll
  for (int mf = 0; mf < 4; ++mf) {
    int mloc = m0 + wm + mf * 16 + ((lane >> 4) << 2);
#pragma unroll
    for (int r = 0; r < 4; ++r) {
      int m = mloc + r;
      if (m >= M) continue;
#pragma unroll
      for (int nf = 0; nf < 4; ++nf) {
        int n = cn + nf * 16;
        C[(ll)m * H_ + n] = acc[mf][nf][r] + bias[n] + res[(ll)m * H_ + n];
      }
    }
  }
}

// ---------------- MFMA flash attention over one segment (no-max softmax) ----------------
__global__ __launch_bounds__(256) void seg_attn_mfma(
    const __hip_bfloat16* __restrict__ Qb,
    const __hip_bfloat16* __restrict__ Kb,
    const __hip_bfloat16* __restrict__ Vb,
    float* __restrict__ so, __hip_bfloat16* __restrict__ sob)
{
  __shared__ __align__(16) char smem[8192 + 9216 + 4 * 4096];
  char* KsB = smem;
  char* VTB = smem + 8192;
  const int tid = threadIdx.x, lane = tid & 63, wid = tid >> 6;
  char* PB = smem + 8192 + 9216 + wid * 4096;

  const int h = blockIdx.y, bs = blockIdx.z;
  const int b = bs >> 4, s = bs & 15;
  const int q0 = blockIdx.x * 128 + wid * 32;
  const bool qvalid = (q0 <= 256);
  const ll base = (ll)bs * (T_ * H_) + h * 64;

  bf16x8 qf[2][2];
#pragma unroll
  for (int mf = 0; mf < 2; ++mf) {
    int qr = q0 + mf * 16 + (lane & 15); if (qr > 256) qr = 256;
#pragma unroll
    for (int ks = 0; ks < 2; ++ks)
      qf[mf][ks] = *(const bf16x8*)(Qb + base + (ll)qr * H_ + ks * 32 + ((lane >> 4) << 3));
  }

  float l_[2][4];
  fx4 of[2][4];
#pragma unroll
  for (int mf = 0; mf < 2; ++mf) {
#pragma unroll
    for (int r = 0; r < 4; ++r) l_[mf][r] = 0.f;
#pragma unroll
    for (int df = 0; df < 4; ++df) of[mf][df] = fx4{0.f, 0.f, 0.f, 0.f};
  }

  const int krow = tid >> 3;
  const int kc8 = tid & 7;
  const int kkp = tid & 31;
  const int vd0 = (tid >> 5) * 8;

  for (int t = 0; t < 5; ++t) {
    const int k0 = t * 64;
    __syncthreads();
    {
      int row = krow;
      int kr = k0 + row; if (kr > 256) kr = 256;
      gl_lds16(Kb + base + (ll)kr * H_ + ((kc8 ^ (row & 7)) << 3), KsB + tid * 16);
      row = krow + 32;
      kr = k0 + row; if (kr > 256) kr = 256;
      gl_lds16(Kb + base + (ll)kr * H_ + ((kc8 ^ (row & 7)) << 3), KsB + 4096 + tid * 16);
    }
    {
      int kk = kkp * 2;
      int kr0 = k0 + kk;     if (kr0 > 256) kr0 = 256;
      int kr1 = k0 + kk + 1; if (kr1 > 256) kr1 = 256;
      bf16x8 v0 = *(const bf16x8*)(Vb + base + (ll)kr0 * H_ + vd0);
      bf16x8 v1 = *(const bf16x8*)(Vb + base + (ll)kr1 * H_ + vd0);
      unsigned int* vtu = (unsigned int*)VTB;
#pragma unroll
      for (int j = 0; j < 8; ++j)
        vtu[(vd0 + j) * 36 + kkp] =
            (unsigned int)(unsigned short)v0[j] | ((unsigned int)(unsigned short)v1[j] << 16);
    }
    __syncthreads();

    if (qvalid) {
      fx4 sa[2][4];
#pragma unroll
      for (int mf = 0; mf < 2; ++mf)
#pragma unroll
        for (int nf = 0; nf < 4; ++nf) sa[mf][nf] = fx4{0.f, 0.f, 0.f, 0.f};
#pragma unroll
      for (int nf = 0; nf < 4; ++nf) {
        int key = nf * 16 + (lane & 15);
#pragma unroll
        for (int ks = 0; ks < 2; ++ks) {
          int c16 = ks * 4 + (lane >> 4);
          bf16x8 kf = *(const bf16x8*)(KsB + key * 128 + ((c16 ^ (key & 7)) << 4));
          sa[0][nf] = __builtin_amdgcn_mfma_f32_16x16x32_bf16(qf[0][ks], kf, sa[0][nf], 0, 0, 0);
          sa[1][nf] = __builtin_amdgcn_mfma_f32_16x16x32_bf16(qf[1][ks], kf, sa[1][nf], 0, 0, 0);
        }
      }
#pragma unroll
      for (int nf = 0; nf < 4; ++nf) {
        bool bad = (k0 + nf * 16 + (lane & 15)) > 256;
#pragma unroll
        for (int mf = 0; mf < 2; ++mf) {
#pragma unroll
          for (int r = 0; r < 4; ++r) {
            float pexp = bad ? 0.f : __expf(sa[mf][nf][r] * SCALE);
            sa[mf][nf][r] = pexp;
            l_[mf][r] += pexp;
          }
        }
      }
#pragma unroll
      for (int mf = 0; mf < 2; ++mf)
#pragma unroll
        for (int nf = 0; nf < 4; ++nf)
#pragma unroll
          for (int rp = 0; rp < 2; ++rp) {
            float v0 = sa[mf][nf][rp];
            float v2 = sa[mf][nf][rp + 2];
            float o0 = __shfl_xor(v0, 1);
            float o2 = __shfl_xor(v2, 1);
            const bool odd = (lane & 1);
            float lo = odd ? o2 : v0;
            float hi = odd ? v2 : o0;
            unsigned int pk = (unsigned int)f2bfu(lo) | ((unsigned int)f2bfu(hi) << 16);
            int row = mf * 16 + ((lane >> 4) << 2) + (odd ? rp + 2 : rp);
            int col2 = nf * 16 + (lane & 14);
            *(unsigned int*)(PB + row * 128 + ((col2 * 2) ^ ((row & 7) << 4))) = pk;
          }
#pragma unroll
      for (int kks = 0; kks < 2; ++kks) {
        bf16x8 pa[2];
#pragma unroll
        for (int mf = 0; mf < 2; ++mf) {
          int prow = mf * 16 + (lane & 15);
          int c16 = kks * 4 + (lane >> 4);
          pa[mf] = *(const bf16x8*)(PB + prow * 128 + ((c16 ^ (prow & 7)) << 4));
        }
#pragma unroll
        for (int df = 0; df < 4; ++df) {
          bf16x8 vf = *(const bf16x8*)(VTB + (df * 16 + (lane & 15)) * 144 + kks * 64 + ((lane >> 4) << 4));
          of[0][df] = __builtin_amdgcn_mfma_f32_16x16x32_bf16(pa[0], vf, of[0][df], 0, 0, 0);
          of[1][df] = __builtin_amdgcn_mfma_f32_16x16x32_bf16(pa[1], vf, of[1][df], 0, 0, 0);
        }
      }
    }
  }

  if (qvalid) {
#pragma unroll
    for (int mf = 0; mf < 2; ++mf)
#pragma unroll
      for (int r = 0; r < 4; ++r) {
        float rs = l_[mf][r];
        rs += __shfl_xor(rs, 1);
        rs += __shfl_xor(rs, 2);
        rs += __shfl_xor(rs, 4);
        rs += __shfl_xor(rs, 8);
        l_[mf][r] = rs;
      }
#pragma unroll
    for (int mf = 0; mf < 2; ++mf)
#pragma unroll
      for (int r = 0; r < 4; ++r) {
        int q = q0 + mf * 16 + ((lane >> 4) << 2) + r;
        if (q > 256) continue;
        float inv = 1.f / l_[mf][r];
        ll rowoff = ((ll)b * L_ + 1 + (ll)s * T_ + q) * H_ + h * 64;
#pragma unroll
        for (int df = 0; df < 4; ++df) {
          int d = df * 16 + (lane & 15);
          float v = of[mf][df][r] * inv;
          so[rowoff + d] = v;
          sob[rowoff + d] = __float2bfloat16(v);
        }
      }
  }
}

// ---------------- small fp32 VALU GEMM (Blord path, M=8) ----------------
__global__ __launch_bounds__(256) void gemm_bt(
    const float* __restrict__ X, ll xbs,
    const float* __restrict__ W,
    const float* __restrict__ bias,
    float* __restrict__ C, ll cbs,
    int M, int K)
{
  const int tid = threadIdx.x;
  const int n0 = blockIdx.x * 64;

  __shared__ float Xt[16][68];
  __shared__ float Wt[16][68];

  const int lr = tid >> 2;
  const int lc = (tid & 3) << 2;
  const int mload = min(lr, M - 1);
  const ll xoff = (ll)mload * xbs;
  const ll woff = (ll)(n0 + lr) * K;

  const int tr = tid >> 4;
  const int tc = tid & 15;

  float acc[4][4];
#pragma unroll
  for (int i = 0; i < 4; ++i)
#pragma unroll
    for (int j = 0; j < 4; ++j) acc[i][j] = 0.f;

  for (int k0 = 0; k0 < K; k0 += 16) {
    float4 xv = *(const float4*)(X + xoff + k0 + lc);
    float4 wv = *(const float4*)(W + woff + k0 + lc);
    __syncthreads();
    Xt[lc + 0][lr] = xv.x; Xt[lc + 1][lr] = xv.y; Xt[lc + 2][lr] = xv.z; Xt[lc + 3][lr] = xv.w;
    Wt[lc + 0][lr] = wv.x; Wt[lc + 1][lr] = wv.y; Wt[lc + 2][lr] = wv.z; Wt[lc + 3][lr] = wv.w;
    __syncthreads();
#pragma unroll
    for (int kk = 0; kk < 16; ++kk) {
      float4 xa = *(const float4*)&Xt[kk][tr << 2];
      float4 wb = *(const float4*)&Wt[kk][tc << 2];
      float xa_[4] = {xa.x, xa.y, xa.z, xa.w};
      float wb_[4] = {wb.x, wb.y, wb.z, wb.w};
#pragma unroll
      for (int i = 0; i < 4; ++i)
#pragma unroll
        for (int j = 0; j < 4; ++j)
          acc[i][j] = fmaf(xa_[i], wb_[j], acc[i][j]);
    }
  }

#pragma unroll
  for (int i = 0; i < 4; ++i) {
    int m = (tr << 2) + i;
    if (m >= M) continue;
#pragma unroll
    for (int j = 0; j < 4; ++j) {
      int n = n0 + (tc << 2) + j;
      C[(ll)m * cbs + n] = acc[i][j] + (bias ? bias[n] : 0.f);
    }
  }
}

// ---------------- batched lord q/k/v projections (M=136, fp32) ----------------
__global__ __launch_bounds__(256) void lord_proj(
    const float* __restrict__ X,
    const float* __restrict__ Wq, const float* __restrict__ Wk, const float* __restrict__ Wv,
    float* __restrict__ Cq, float* __restrict__ Ck, float* __restrict__ Cv)
{
  const float* W = (blockIdx.z == 0) ? Wq : (blockIdx.z == 1) ? Wk : Wv;
  float* C = (blockIdx.z == 0) ? Cq : (blockIdx.z == 1) ? Ck : Cv;
  const int M = 136, K = 1024;

  const int tid = threadIdx.x;
  const int m0 = blockIdx.y * 64;
  const int n0 = blockIdx.x * 64;

  __shared__ float Xt[16][68];
  __shared__ float Wt[16][68];

  const int lr = tid >> 2;
  const int lc = (tid & 3) << 2;
  const int mload = min(m0 + lr, M - 1);
  const ll xoff = (ll)mload * K;
  const ll woff = (ll)(n0 + lr) * K;

  const int tr = tid >> 4;
  const int tc = tid & 15;

  float acc[4][4];
#pragma unroll
  for (int i = 0; i < 4; ++i)
#pragma unroll
    for (int j = 0; j < 4; ++j) acc[i][j] = 0.f;

  for (int k0 = 0; k0 < K; k0 += 16) {
    float4 xv = *(const float4*)(X + xoff + k0 + lc);
    float4 wv = *(const float4*)(W + woff + k0 + lc);
    __syncthreads();
    Xt[lc + 0][lr] = xv.x; Xt[lc + 1][lr] = xv.y; Xt[lc + 2][lr] = xv.z; Xt[lc + 3][lr] = xv.w;
    Wt[lc + 0][lr] = wv.x; Wt[lc + 1][lr] = wv.y; Wt[lc + 2][lr] = wv.z; Wt[lc + 3][lr] = wv.w;
    __syncthreads();
#pragma unroll
    for (int kk = 0; kk < 16; ++kk) {
      float4 xa = *(const float4*)&Xt[kk][tr << 2];
      float4 wb = *(const float4*)&Wt[kk][tc << 2];
      float xa_[4] = {xa.x, xa.y, xa.z, xa.w};
      float wb_[4] = {wb.x, wb.y, wb.z, wb.w};
#pragma unroll
      for (int i = 0; i < 4; ++i)
#pragma unroll
        for (int j = 0; j < 4; ++j)
          acc[i][j] = fmaf(xa_[i], wb_[j], acc[i][j]);
    }
  }

#pragma unroll
  for (int i = 0; i < 4; ++i) {
    int m = m0 + (tr << 2) + i;
    if (m >= M) continue;
#pragma unroll
    for (int j = 0; j < 4; ++j)
      C[(ll)m * 1024 + n0 + (tc << 2) + j] = acc[i][j];
  }
}

__global__ __launch_bounds__(256) void copy_lords_in(
    const float* __restrict__ so, float* __restrict__ lin)
{
  int b = blockIdx.x / SEG_, s = blockIdx.x % SEG_;
  int i = threadIdx.x * 4;
  *(float4*)(lin + ((ll)(b * 17 + 1 + s)) * H_ + i) =
      *(const float4*)(so + ((ll)b * L_ + 1 + (ll)s * T_) * H_ + i);
}

// ---------------- lord attention v2: LDS-staged, wave-parallel ----------------
__global__ __launch_bounds__(256) void lord_attn2(
    const float* __restrict__ lq, const float* __restrict__ lk,
    const float* __restrict__ lv, float* __restrict__ so,
    __hip_bfloat16* __restrict__ sob)
{
  const int b = blockIdx.x, h = blockIdx.y;
  const int tid = threadIdx.x, lane = tid & 63, wid = tid >> 6;
  __shared__ float Qs[17][64], Ks[17][64], Vs[17][64];
  for (int t = tid; t < 17 * 64; t += 256) {
    int r = t >> 6, c = t & 63;
    ll g = ((ll)(b * 17 + r)) * H_ + h * 64 + c;
    Qs[r][c] = lq[g];
    Ks[r][c] = lk[g];
    Vs[r][c] = lv[g];
  }
  __syncthreads();
  for (int q = wid; q < 17; q += 4) {
    float qd = Qs[q][lane];
    float sc[17];
#pragma unroll
    for (int k = 0; k < 17; ++k) {
      float p = qd * Ks[k][lane];
      p += __shfl_xor(p, 1);  p += __shfl_xor(p, 2);  p += __shfl_xor(p, 4);
      p += __shfl_xor(p, 8);  p += __shfl_xor(p, 16); p += __shfl_xor(p, 32);
      sc[k] = p * SCALE;
    }
    float mx = sc[0];
#pragma unroll
    for (int k = 1; k < 17; ++k) mx = fmaxf(mx, sc[k]);
    float l = 0.f;
#pragma unroll
    for (int k = 0; k < 17; ++k) { sc[k] = __expf(sc[k] - mx); l += sc[k]; }
    float invl = 1.f / l;
    float o = 0.f;
#pragma unroll
    for (int k = 0; k < 17; ++k) o = fmaf(sc[k], Vs[k][lane], o);
    o *= invl;
    ll row = (q == 0) ? (ll)b * L_ : ((ll)b * L_ + 1 + (ll)(q - 1) * T_);
    so[row * H_ + h * 64 + lane] = o;
    sob[row * H_ + h * 64 + lane] = __float2bfloat16(o);
  }
}

__global__ __launch_bounds__(256) void ln_inplace(
    float* __restrict__ hbuf, const float* __restrict__ w, const float* __restrict__ bgain)
{
  const ll row = blockIdx.x;
  const int tid = threadIdx.x;
  float4 x = *(float4*)(hbuf + row * H_ + tid * 4);
  float s = x.x + x.y + x.z + x.w;
  float s2 = x.x * x.x + x.y * x.y + x.z * x.z + x.w * x.w;
#pragma unroll
  for (int off = 32; off >= 1; off >>= 1) {
    s  += __shfl_down(s, off, 64);
    s2 += __shfl_down(s2, off, 64);
  }
  __shared__ float red[2][4];
  int wid = tid >> 6;
  if ((tid & 63) == 0) { red[0][wid] = s; red[1][wid] = s2; }
  __syncthreads();
  s  = red[0][0] + red[0][1] + red[0][2] + red[0][3];
  s2 = red[1][0] + red[1][1] + red[1][2] + red[1][3];
  const float mean = s * (1.f / H_);
  float var = s2 * (1.f / H_) - mean * mean;
  var = fmaxf(var, 0.f);
  const float inv = rsqrtf(var + 1e-12f);
  float4 g = *(const float4*)(w + tid * 4);
  float4 bb = *(const float4*)(bgain + tid * 4);
  float4 y;
  y.x = (x.x - mean) * inv * g.x + bb.x;
  y.y = (x.y - mean) * inv * g.y + bb.y;
  y.z = (x.z - mean) * inv * g.z + bb.z;
  y.w = (x.w - mean) * inv * g.w + bb.w;
  *(float4*)(hbuf + row * H_ + tid * 4) = y;
}

extern "C" void kernel_launch(void* const* d_in, const int* in_sizes, int n_in,
                              void* d_out, int out_size, void* d_ws, size_t ws_size,
                              hipStream_t stream)
{
  const float* hidden  = (const float*)d_in[0];
  const float* Blord_w = (const float*)d_in[1];
  const float* Blord_b = (const float*)d_in[2];
  const float* seg_qw  = (const float*)d_in[3];
  const float* seg_kw  = (const float*)d_in[4];
  const float* seg_vw  = (const float*)d_in[5];
  const float* lord_qw = (const float*)d_in[6];
  const float* lord_kw = (const float*)d_in[7];
  const float* lord_vw = (const float*)d_in[8];
  const float* out_w   = (const float*)d_in[9];
  const float* out_b   = (const float*)d_in[10];
  const float* ln_w    = (const float*)d_in[11];
  const float* ln_b    = (const float*)d_in[12];

  float* attn_out = (float*)d_out;                          // output 0 [B,L,H]
  float* self_out = (float*)d_out + (ll)B_ * L_ * H_;       // output 1 [B,L,H]

  const ll QKV = (ll)B_ * SEG_ * T_ * H_;
  const ll SHH = (ll)SEG_ * H_ * H_;
  __hip_bfloat16* qb = (__hip_bfloat16*)attn_out;
  __hip_bfloat16* kb = qb + QKV;
  __hip_bfloat16* hbf = (__hip_bfloat16*)self_out;
  __hip_bfloat16* vb = (__hip_bfloat16*)d_ws;
  __hip_bfloat16* wslot3 = vb + QKV;
  __hip_bfloat16* sob = wslot3;                             // alias (weights dead)
  __hip_bfloat16* outw_bf = wslot3 + 3 * SHH;
  float* lords_in = (float*)(outw_bf + (ll)H_ * H_);
  float* lqw_ = lords_in + 136 * 1024;
  float* lkw_ = lqw_ + 136 * 1024;
  float* lvw_ = lkw_ + 136 * 1024;

  dim3 blk(256);

  // 0. convert hidden + all weights to bf16 (single dispatch)
  f2bf_all<<<dim3(2048), blk, 0, stream>>>(
      hidden, hbf, seg_qw, seg_kw, seg_vw, wslot3, out_w, outw_bf);

  // 1. fused segment QKV projection (counted-vmcnt pipeline + swizzle)
  gemm_qkv<<<dim3(24, 17, 16), blk, 0, stream>>>(hbf + H_, wslot3, qb, kb, vb);

  // 2. Blord projection (fp32, M=8)
  gemm_bt<<<dim3(16), blk, 0, stream>>>(
      hidden, (ll)L_ * H_, Blord_w, Blord_b, lords_in, (ll)17 * H_, B_, H_);

  // 3. segment attention (MFMA flash, no-max softmax)
  seg_attn_mfma<<<dim3(3, NH_, B_ * SEG_), blk, 0, stream>>>(qb, kb, vb, self_out, sob);

  // 4. gather lord inputs
  copy_lords_in<<<dim3(B_ * SEG_), blk, 0, stream>>>(self_out, lords_in);

  // 5. lord q/k/v projections
  lord_proj<<<dim3(16, 3, 3), blk, 0, stream>>>(
      lords_in, lord_qw, lord_kw, lord_vw, lqw_, lkw_, lvw_);

  // 6. lord attention
  lord_attn2<<<dim3(B_, NH_), blk, 0, stream>>>(lqw_, lkw_, lvw_, self_out, sob);

  // 7. output dense + bias + residual -> attn_out (overwrites qb/kb)
  gemm_out<<<dim3(8, 258), blk, 0, stream>>>(sob, outw_bf, out_b, attn_out, hidden);

  // 8. LayerNorm in place
  ln_inplace<<<dim3(B_ * L_), blk, 0, stream>>>(attn_out, ln_w, ln_b);
}